// Round 13
// baseline (1066.316 us; speedup 1.0000x reference)
//
#include <hip/hip_runtime.h>
#include <hip/hip_bf16.h>
#include <math.h>

// ---- problem constants ----
#define HIDN 7168
#define NHEAD 128
#define QLRANK 1536
#define KVLRANK 512
#define QKD 128
#define VHD 128
#define RHD 64
#define SEQ 1024
#define RMS_EPS 1.1920929e-07f

typedef unsigned short u16;
typedef __attribute__((ext_vector_type(8))) short bf16x8;
typedef __attribute__((ext_vector_type(4))) float f32x4;
typedef __attribute__((ext_vector_type(8))) unsigned short u16x8;

__device__ __forceinline__ u16 f2bf(float f) {
    unsigned int u = __float_as_uint(f);
    unsigned int r = (u + 0x7FFFu + ((u >> 16) & 1u)) >> 16;
    return (u16)r;
}
__device__ __forceinline__ float bf2f(u16 v) {
    return __uint_as_float(((unsigned int)v) << 16);
}

// async global->LDS, 16B per lane. LDS dest is wave-uniform base + lane*16.
__device__ __forceinline__ void gld_lds16(const u16* g, u16* l) {
    __builtin_amdgcn_global_load_lds(
        (const __attribute__((address_space(1))) unsigned int*)g,
        (__attribute__((address_space(3))) unsigned int*)l,
        16, 0, 0);
}

// ---------------- fp32 -> bf16 conversion (x8 vectorized) ----------------
__global__ __launch_bounds__(256) void f32_to_bf16(const float* __restrict__ in,
                                                   u16* __restrict__ out, long n) {
    long i = ((long)blockIdx.x * blockDim.x + threadIdx.x) * 8;
    long stride = (long)gridDim.x * blockDim.x * 8;
    for (; i < n; i += stride) {
        float4 a = *(const float4*)(in + i);
        float4 b = *(const float4*)(in + i + 4);
        u16x8 o;
        o[0] = f2bf(a.x); o[1] = f2bf(a.y); o[2] = f2bf(a.z); o[3] = f2bf(a.w);
        o[4] = f2bf(b.x); o[5] = f2bf(b.y); o[6] = f2bf(b.z); o[7] = f2bf(b.w);
        *(u16x8*)(out + i) = o;
    }
}

// ---------------- generic GEMM: C[m][n] = sum_k A[m][k]*B[n][k] ----------------
// T4-counted pipeline at UNCHANGED occupancy (the r8/r11 lesson): BK=32 makes
// each buffer 8 KiB, so a 4-buffer ring is still 64 KiB total -> 2 WG/CU x
// 8 waves = 4 waves/SIMD (same TLP as r10), while loads now get ~2 K-steps of
// latency cover and the per-step wait is counted vmcnt(4) (tiles t+1,t+2 stay
// in flight; never drains). 128x128 tile, 8 waves (2M x 4N), 16 MFMA/wave/step.
// Ring safety: stage(t+3) overwrites buf (t-1)&3 whose readers all passed
// barrier t (ds_reads complete before MFMA issue); per-wave vmcnt(4) before
// barrier t guarantees its tile-t loads landed (m135 issue-order semantics).
// LDS swizzle: phys chunk = logical ^ ((row>>1)&3) on both stage-source and
// read side -> exactly 2-way banking on ds_read_b128 (free, m136).
// Split-K via blockIdx.z: fp32 partials at Cv + z*M*N (OUT_BF16=0 only).
template <int OUT_BF16>
__global__ __launch_bounds__(512) void gemm_bt(const u16* __restrict__ A,
                                               const u16* __restrict__ B,
                                               void* __restrict__ Cv,
                                               int M, int N, int Kslice, long ldk) {
    __shared__ u16 As[4][128 * 32];   // 4 bufs x 8 KiB
    __shared__ u16 Bs[4][128 * 32];
    const int tid = threadIdx.x;
    const int lane = tid & 63;
    const int w = tid >> 6;            // 0..7
    const int wr = w >> 2, wc = w & 3; // wave grid 2M x 4N
    const int l15 = lane & 15, lg = lane >> 4;
    const int n0 = blockIdx.x * 128;
    const int m0 = blockIdx.y * 128;
    const long kbase = (long)blockIdx.z * Kslice;

    // staging: thread -> row r=tid>>2 (0..127), phys 16B chunk p=tid&3 of the
    // 64B row; global chunk g = p ^ ((r>>1)&3). LDS linear index = tid*16B,
    // so each wave's dest base &buf[w*512] is wave-uniform (lane*16 auto).
    // 4 threads per row read a permuted-but-contiguous 64B segment: coalesced.
    const int r = tid >> 2;
    const int p = tid & 3;
    const int g = p ^ ((r >> 1) & 3);
    const u16* asrc = A + (long)(m0 + r) * ldk + kbase + g * 8;
    int brow = n0 + r; if (brow >= N) brow = N - 1;
    const u16* bsrc = B + (long)brow * ldk + kbase + g * 8;

    f32x4 acc[4][2];
    const f32x4 z = {0.f, 0.f, 0.f, 0.f};
#pragma unroll
    for (int i = 0; i < 4; ++i)
#pragma unroll
        for (int j = 0; j < 2; ++j) acc[i][j] = z;

    auto stage = [&](int t) {
        const int b4 = t & 3;
        const long ko = (long)t * 32;
        gld_lds16(asrc + ko, &As[b4][w * 512]);
        gld_lds16(bsrc + ko, &Bs[b4][w * 512]);
    };

    const int T = Kslice >> 5;
    stage(0);
    if (1 < T) stage(1);
    if (2 < T) stage(2);

    for (int t = 0; t < T; ++t) {
        if (t + 2 < T)      asm volatile("s_waitcnt vmcnt(4)" ::: "memory");
        else if (t + 1 < T) asm volatile("s_waitcnt vmcnt(2)" ::: "memory");
        else                asm volatile("s_waitcnt vmcnt(0)" ::: "memory");
        __builtin_amdgcn_s_barrier();
        __builtin_amdgcn_sched_barrier(0);
        if (t + 3 < T) stage(t + 3);
        const u16* Ab = As[t & 3];
        const u16* Bb = Bs[t & 3];
        bf16x8 a[4], b[2];
#pragma unroll
        for (int i = 0; i < 4; ++i) {
            int row = wr * 64 + i * 16 + l15;
            a[i] = *(const bf16x8*)&Ab[row * 32 + (lg ^ ((row >> 1) & 3)) * 8];
        }
#pragma unroll
        for (int j = 0; j < 2; ++j) {
            int row = wc * 32 + j * 16 + l15;
            b[j] = *(const bf16x8*)&Bb[row * 32 + (lg ^ ((row >> 1) & 3)) * 8];
        }
#pragma unroll
        for (int i = 0; i < 4; ++i)
#pragma unroll
            for (int j = 0; j < 2; ++j)
                acc[i][j] = __builtin_amdgcn_mfma_f32_16x16x32_bf16(a[i], b[j], acc[i][j], 0, 0, 0);
    }

#pragma unroll
    for (int i = 0; i < 4; ++i)
#pragma unroll
        for (int j = 0; j < 2; ++j)
#pragma unroll
            for (int rr = 0; rr < 4; ++rr) {
                int m = m0 + wr * 64 + i * 16 + lg * 4 + rr;
                int n = n0 + wc * 32 + j * 16 + l15;
                if (n < N) {
                    if (OUT_BF16)
                        ((u16*)Cv)[(long)m * N + n] = f2bf(acc[i][j][rr]);
                    else
                        ((float*)Cv)[(long)blockIdx.z * M * N + (long)m * N + n] = acc[i][j][rr];
                }
            }
}

// ---------------- sum split-K partials (fp32), x4 vectorized ----------------
__global__ __launch_bounds__(256) void reduce_parts(const float* __restrict__ parts,
                                                    float* __restrict__ out,
                                                    int nparts, long mn) {
    long i = ((long)blockIdx.x * 256 + threadIdx.x) * 4;
    long stride = (long)gridDim.x * 256 * 4;
    for (; i < mn; i += stride) {
        float4 s = *(const float4*)(parts + i);
        for (int p = 1; p < nparts; ++p) {
            float4 v = *(const float4*)(parts + (long)p * mn + i);
            s.x += v.x; s.y += v.y; s.z += v.z; s.w += v.w;
        }
        *(float4*)(out + i) = s;
    }
}

// ---------------- RMSNorm (row-wise): y = x * rsqrt(mean(x^2)+eps) * w ----------------
__global__ __launch_bounds__(256) void rmsnorm_kernel(const float* __restrict__ x,
                                                      const float* __restrict__ w,
                                                      u16* __restrict__ y,
                                                      int stride, int norm_len) {
    const int row = blockIdx.x;
    const float* xr = x + (long)row * stride;
    float ss = 0.f;
    for (int i = threadIdx.x; i < norm_len; i += 256) {
        float v = xr[i];
        ss += v * v;
    }
#pragma unroll
    for (int off = 32; off > 0; off >>= 1) ss += __shfl_down(ss, off);
    __shared__ float partial[4];
    if ((threadIdx.x & 63) == 0) partial[threadIdx.x >> 6] = ss;
    __syncthreads();
    float tot = partial[0] + partial[1] + partial[2] + partial[3];
    float rs = 1.0f / sqrtf(tot / (float)norm_len + RMS_EPS);
    u16* yr = y + (long)row * norm_len;
    for (int i = threadIdx.x; i < norm_len; i += 256) yr[i] = f2bf(xr[i] * rs * w[i]);
}

// ---------------- RoPE tables (fp32): cos/sin[s][i], i<32 ----------------
__global__ void rope_tables(float* __restrict__ cos_t, float* __restrict__ sin_t) {
    int s = blockIdx.x;
    int i = threadIdx.x;  // 32 threads
    float invf = powf(10000.0f, -((float)(2 * i) / 64.0f));
    float ang = (float)s * invf;
    cos_t[s * 32 + i] = cosf(ang);
    sin_t[s * 32 + i] = sinf(ang);
}

// ---------------- RoPE on q_r, in-place on q_cr (bf16) ----------------
__global__ void rope_q(u16* __restrict__ q_cr, const float* __restrict__ cos_t,
                       const float* __restrict__ sin_t) {
    int s = blockIdx.x;
    int h = blockIdx.y * 2 + (threadIdx.x >> 5);
    int i = threadIdx.x & 31;
    u16* base = q_cr + (s * (NHEAD * 192) + h * 192 + QKD);
    float x1 = bf2f(base[i]);
    float x2 = bf2f(base[i + 32]);
    float c = cos_t[s * 32 + i], sn = sin_t[s * 32 + i];
    base[i]      = f2bf(x1 * c - x2 * sn);
    base[i + 32] = f2bf(x2 * c + x1 * sn);
}

// ---------------- RoPE on k_r (from fp32 ckv_kr cols 512..576) -> bf16 kr ----------------
__global__ void rope_k(const float* __restrict__ ckv_kr, const float* __restrict__ cos_t,
                       const float* __restrict__ sin_t, u16* __restrict__ kr) {
    int s = blockIdx.x;
    int i = threadIdx.x;  // 64 threads; first 32 active
    if (i < 32) {
        const float* base = ckv_kr + (s * 576 + 512);
        float x1 = base[i], x2 = base[i + 32];
        float c = cos_t[s * 32 + i], sn = sin_t[s * 32 + i];
        kr[s * 64 + i]      = f2bf(x1 * c - x2 * sn);
        kr[s * 64 + i + 32] = f2bf(x2 * c + x1 * sn);
    }
}

// ---------------- build vT[h][dv][s] from kv[s][h*256+128+dv] ----------------
__global__ __launch_bounds__(256) void build_vt(const u16* __restrict__ kv,
                                                u16* __restrict__ vT) {
    __shared__ u16 vtile[64][136];  // 272B row stride (16B aligned)
    const int h = blockIdx.x, sb = blockIdx.y, s0 = sb * 64;
    const int tid = threadIdx.x;
#pragma unroll
    for (int it = 0; it < 4; ++it) {
        int c = it * 256 + tid;
        int row = c >> 4;
        int off8 = (c & 15) * 8;
        *(u16x8*)&vtile[row][off8] =
            *(const u16x8*)&kv[(s0 + row) * 32768 + h * 256 + 128 + off8];
    }
    __syncthreads();
    const int sl = tid & 63;
    const int dvb = tid >> 6;  // 0..3
#pragma unroll
    for (int it = 0; it < 32; ++it) {
        int dv = dvb + it * 4;
        vT[(h * 128 + dv) * 1024 + s0 + sl] = vtile[sl][dv];
    }
}

// ---------------- flash attention: 1 block = 128 queries x 1 head, 8 waves ----------------
// T14 async-STAGE (reg prefetch of next tile under compute) + T5 setprio
// around MFMA clusters. p_lds is wave-private -> no barrier after P-write.
__global__ __launch_bounds__(512) void mla_attn(const u16* __restrict__ q_cr,
                                                const u16* __restrict__ kv,
                                                const u16* __restrict__ kr,
                                                const u16* __restrict__ vT,
                                                u16* __restrict__ o_g) {
    __shared__ u16 ks[64][200];        // 64 keys x 192 dims (+pad)
    __shared__ u16 vts[128][72];       // 128 dv x 64 k (+pad)
    __shared__ u16 p_lds[8][16][72];   // per wave: 16 q x 64 k (+pad)
    const int qb = blockIdx.x, h = blockIdx.y;
    const int s0q = qb * 128;
    const int tid = threadIdx.x, lane = tid & 63, w = tid >> 6;
    const int l15 = lane & 15, lg = lane >> 4;
    const float scale = 0.07216878364870323f;  // 1/sqrt(192)

    // Q in registers, A-fragment layout (row = l15, k contiguous per lg group)
    bf16x8 qreg[6];
    {
        const int qrow = s0q + w * 16 + l15;
#pragma unroll
        for (int kk = 0; kk < 6; ++kk)
            qreg[kk] = *(const bf16x8*)&q_cr[qrow * (NHEAD * 192) + h * 192 + kk * 32 + lg * 8];
    }

    // staging-index precompute (512 threads cover: K 2x, kr 1x, V 2x u16x8 each)
    const int krow0 = tid >> 4,           koff0 = (tid & 15) * 8;
    const int krow1 = (512 + tid) >> 4,   koff1 = ((512 + tid) & 15) * 8;
    const int rrow  = tid >> 3,           roff  = (tid & 7) * 8;
    const int vdv0  = tid >> 3,           voff0 = (tid & 7) * 8;
    const int vdv1  = (512 + tid) >> 3,   voff1 = ((512 + tid) & 7) * 8;
    const u16* kvp = kv + h * 256;
    const u16* vtp = vT + (long)(h * 128) * 1024;

    u16x8 kreg0, kreg1, krreg, vreg0, vreg1;
    auto load_tile = [&](int s0k) {
        kreg0 = *(const u16x8*)&kvp[(long)(s0k + krow0) * 32768 + koff0];
        kreg1 = *(const u16x8*)&kvp[(long)(s0k + krow1) * 32768 + koff1];
        krreg = *(const u16x8*)&kr[(s0k + rrow) * 64 + roff];
        vreg0 = *(const u16x8*)&vtp[(long)vdv0 * 1024 + s0k + voff0];
        vreg1 = *(const u16x8*)&vtp[(long)vdv1 * 1024 + s0k + voff1];
    };

    f32x4 o_acc[8];
    const f32x4 z = {0.f, 0.f, 0.f, 0.f};
#pragma unroll
    for (int d = 0; d < 8; ++d) o_acc[d] = z;
    float m_r[4], l_r[4];
#pragma unroll
    for (int r = 0; r < 4; ++r) { m_r[r] = -1e30f; l_r[r] = 0.f; }

    load_tile(0);

    for (int kt = 0; kt < 16; ++kt) {
        __syncthreads();   // prev tile's readers done
        *(u16x8*)&ks[krow0][koff0]      = kreg0;
        *(u16x8*)&ks[krow1][koff1]      = kreg1;
        *(u16x8*)&ks[rrow][128 + roff]  = krreg;
        *(u16x8*)&vts[vdv0][voff0]      = vreg0;
        *(u16x8*)&vts[vdv1][voff1]      = vreg1;
        __syncthreads();   // tile staged
        if (kt + 1 < 16) load_tile((kt + 1) * 64);   // async: hides under compute

        // QK^T : S-frags (16 q x 64 keys per wave)
        f32x4 sf[4];
#pragma unroll
        for (int j = 0; j < 4; ++j) sf[j] = z;
        __builtin_amdgcn_s_setprio(1);
#pragma unroll
        for (int kk = 0; kk < 6; ++kk) {
            bf16x8 a = qreg[kk];
#pragma unroll
            for (int j = 0; j < 4; ++j) {
                bf16x8 b = *(const bf16x8*)&ks[j * 16 + l15][kk * 32 + lg * 8];
                sf[j] = __builtin_amdgcn_mfma_f32_16x16x32_bf16(a, b, sf[j], 0, 0, 0);
            }
        }
        __builtin_amdgcn_s_setprio(0);

        // online softmax (rows live in C-layout: row=(lg)*4+r, col=j*16+l15)
        float p[4][4];
        float alpha[4];
#pragma unroll
        for (int r = 0; r < 4; ++r) {
            float mx = fmaxf(fmaxf(sf[0][r], sf[1][r]), fmaxf(sf[2][r], sf[3][r]));
#pragma unroll
            for (int off = 1; off < 16; off <<= 1) mx = fmaxf(mx, __shfl_xor(mx, off));
            mx *= scale;
            float mnew = fmaxf(m_r[r], mx);
            alpha[r] = __expf(m_r[r] - mnew);
            float rs = 0.f;
#pragma unroll
            for (int j = 0; j < 4; ++j) {
                float pv = __expf(sf[j][r] * scale - mnew);
                p[j][r] = pv;
                rs += pv;
            }
#pragma unroll
            for (int off = 1; off < 16; off <<= 1) rs += __shfl_xor(rs, off);
            l_r[r] = l_r[r] * alpha[r] + rs;
            m_r[r] = mnew;
        }
#pragma unroll
        for (int d = 0; d < 8; ++d)
#pragma unroll
            for (int r = 0; r < 4; ++r) o_acc[d][r] *= alpha[r];

        // P -> LDS (wave-private; no block barrier needed)
#pragma unroll
        for (int j = 0; j < 4; ++j)
#pragma unroll
            for (int r = 0; r < 4; ++r)
                p_lds[w][lg * 4 + r][j * 16 + l15] = f2bf(p[j][r]);

        // PV: O += P @ V
        __builtin_amdgcn_s_setprio(1);
#pragma unroll
        for (int kk2 = 0; kk2 < 2; ++kk2) {
            bf16x8 a = *(const bf16x8*)&p_lds[w][l15][kk2 * 32 + lg * 8];
#pragma unroll
            for (int d = 0; d < 8; ++d) {
                bf16x8 b = *(const bf16x8*)&vts[d * 16 + l15][kk2 * 32 + lg * 8];
                o_acc[d] = __builtin_amdgcn_mfma_f32_16x16x32_bf16(a, b, o_acc[d], 0, 0, 0);
            }
        }
        __builtin_amdgcn_s_setprio(0);
    }

    // epilogue: divide by l, store bf16 o[s][h*128+dv]
#pragma unroll
    for (int d = 0; d < 8; ++d)
#pragma unroll
        for (int r = 0; r < 4; ++r) {
            int srow = s0q + w * 16 + lg * 4 + r;
            float v = o_acc[d][r] / l_r[r];
            o_g[srow * 16384 + h * 128 + d * 16 + l15] = f2bf(v);
        }
}

// ---------------- host launcher ----------------
extern "C" void kernel_launch(void* const* d_in, const int* in_sizes, int n_in,
                              void* d_out, int out_size, void* d_ws, size_t ws_size,
                              hipStream_t stream) {
    const float* hs        = (const float*)d_in[0];
    const float* w_q_down  = (const float*)d_in[1];
    const float* q_norm_w  = (const float*)d_in[2];
    const float* w_q_up    = (const float*)d_in[3];
    const float* w_kv_down = (const float*)d_in[4];
    const float* kv_norm_w = (const float*)d_in[5];
    const float* w_kv_up   = (const float*)d_in[6];
    const float* w_out     = (const float*)d_in[7];
    float* out = (float*)d_out;
    char* ws = (char*)d_ws;

    // ---- workspace layout (contiguous front region is reused for w_out bf16) ----
    const size_t SZ_HS   = (size_t)SEQ * HIDN * 2;
    const size_t SZ_KV   = (size_t)SEQ * 32768 * 2;
    const size_t SZ_QCR  = (size_t)SEQ * (NHEAD * 192) * 2;
    const size_t SZ_VT   = (size_t)NHEAD * 128 * 1024 * 2;
    const size_t SZ_WB   = (size_t)24576 * 1536 * 2;
    const size_t SZ_CQ   = (size_t)SEQ * QLRANK * 4;
    const size_t SZ_CQN  = (size_t)SEQ * QLRANK * 2;
    const size_t SZ_CKV  = (size_t)SEQ * 576 * 4;
    const size_t SZ_CKVN = (size_t)SEQ * KVLRANK * 2;
    const size_t SZ_KR   = (size_t)SEQ * 64 * 2;
    const size_t SZ_OG   = (size_t)SEQ * 16384 * 2;
    const size_t SZ_TAB  = (size_t)SEQ * 32 * 4;

    size_t off = 0;
    u16* hs_bf  = (u16*)(ws + off); off += SZ_HS;
    u16* kvb    = (u16*)(ws + off); off += SZ_KV;
    u16* q_cr   = (u16*)(ws + off); off += SZ_QCR;
    u16* vT     = (u16*)(ws + off); off += SZ_VT;
    u16* W_BUF  = (u16*)(ws + off); off += SZ_WB;
    // split-K partials for c_q/kv_down alias upper W_BUF region (+32MB; weight
    // there is <32MB while these gemms run).
    float* parts = (float*)((char*)W_BUF + 33554432);
    // w_out bf16 (234,881,024 B) aliases [ws .. 235MB), all dead by then
    u16* wout_bf = (u16*)ws;
    float* c_q    = (float*)(ws + off); off += SZ_CQ;
    u16* cq_n     = (u16*)(ws + off); off += SZ_CQN;
    float* ckv_kr = (float*)(ws + off); off += SZ_CKV;
    u16* ckv_n    = (u16*)(ws + off); off += SZ_CKVN;
    u16* kr       = (u16*)(ws + off); off += SZ_KR;
    u16* o_g      = (u16*)(ws + off); off += SZ_OG;
    float* cos_t  = (float*)(ws + off); off += SZ_TAB;
    float* sin_t  = (float*)(ws + off); off += SZ_TAB;
    (void)in_sizes; (void)n_in; (void)out_size; (void)ws_size;

    rope_tables<<<dim3(SEQ), dim3(32), 0, stream>>>(cos_t, sin_t);
    f32_to_bf16<<<2048, 256, 0, stream>>>(hs, hs_bf, (long)SEQ * HIDN);

    // c_q = hs @ w_q_down^T   (split-K x4: 7168 = 4 x 1792)
    f32_to_bf16<<<2048, 256, 0, stream>>>(w_q_down, W_BUF, (long)QLRANK * HIDN);
    gemm_bt<0><<<dim3(QLRANK / 128, SEQ / 128, 4), 512, 0, stream>>>(hs_bf, W_BUF, parts, SEQ, QLRANK, HIDN / 4, HIDN);
    reduce_parts<<<1024, 256, 0, stream>>>(parts, c_q, 4, (long)SEQ * QLRANK);
    rmsnorm_kernel<<<SEQ, 256, 0, stream>>>(c_q, q_norm_w, cq_n, QLRANK, QLRANK);

    // q_cr = rmsnorm(c_q) @ w_q_up^T
    f32_to_bf16<<<2048, 256, 0, stream>>>(w_q_up, W_BUF, (long)24576 * QLRANK);
    gemm_bt<1><<<dim3(24576 / 128, SEQ / 128), 512, 0, stream>>>(cq_n, W_BUF, q_cr, SEQ, 24576, QLRANK, QLRANK);

    // ckv_kr = hs @ w_kv_down^T   (split-K x8; N=576 ragged)
    f32_to_bf16<<<2048, 256, 0, stream>>>(w_kv_down, W_BUF, (long)576 * HIDN);
    gemm_bt<0><<<dim3(5, SEQ / 128, 8), 512, 0, stream>>>(hs_bf, W_BUF, parts, SEQ, 576, HIDN / 8, HIDN);
    reduce_parts<<<1024, 256, 0, stream>>>(parts, ckv_kr, 8, (long)SEQ * 576);
    rmsnorm_kernel<<<SEQ, 256, 0, stream>>>(ckv_kr, kv_norm_w, ckv_n, 576, KVLRANK);
    rope_k<<<SEQ, 64, 0, stream>>>(ckv_kr, cos_t, sin_t, kr);

    // kv = rmsnorm(c_kv) @ w_kv_up^T
    f32_to_bf16<<<2048, 256, 0, stream>>>(w_kv_up, W_BUF, (long)32768 * KVLRANK);
    gemm_bt<1><<<dim3(32768 / 128, SEQ / 128), 512, 0, stream>>>(ckv_n, W_BUF, kvb, SEQ, 32768, KVLRANK, KVLRANK);

    rope_q<<<dim3(SEQ, NHEAD / 2), 64, 0, stream>>>(q_cr, cos_t, sin_t);
    build_vt<<<dim3(NHEAD, SEQ / 64), 256, 0, stream>>>(kvb, vT);

    mla_attn<<<dim3(SEQ / 128, NHEAD), 512, 0, stream>>>(q_cr, kvb, kr, vT, o_g);

    // out = o @ w_out^T   (natural order keeps B-strip on one XCD's L2)
    f32_to_bf16<<<4096, 256, 0, stream>>>(w_out, wout_bf, (long)HIDN * 16384);
    gemm_bt<0><<<dim3(HIDN / 128, SEQ / 128), 512, 0, stream>>>(o_g, wout_bf, out, SEQ, HIDN, 16384, 16384);
}

// Round 14
// 1012.222 us; speedup vs baseline: 1.0534x; 1.0534x over previous
//
#include <hip/hip_runtime.h>
#include <hip/hip_bf16.h>
#include <math.h>

// ---- problem constants ----
#define HIDN 7168
#define NHEAD 128
#define QLRANK 1536
#define KVLRANK 512
#define QKD 128
#define VHD 128
#define RHD 64
#define SEQ 1024
#define RMS_EPS 1.1920929e-07f

typedef unsigned short u16;
typedef __attribute__((ext_vector_type(8))) short bf16x8;
typedef __attribute__((ext_vector_type(4))) float f32x4;
typedef __attribute__((ext_vector_type(8))) unsigned short u16x8;

__device__ __forceinline__ u16 f2bf(float f) {
    unsigned int u = __float_as_uint(f);
    unsigned int r = (u + 0x7FFFu + ((u >> 16) & 1u)) >> 16;
    return (u16)r;
}
__device__ __forceinline__ float bf2f(u16 v) {
    return __uint_as_float(((unsigned int)v) << 16);
}

// async global->LDS, 16B per lane. LDS dest is wave-uniform base + lane*16.
__device__ __forceinline__ void gld_lds16(const u16* g, u16* l) {
    __builtin_amdgcn_global_load_lds(
        (const __attribute__((address_space(1))) unsigned int*)g,
        (__attribute__((address_space(3))) unsigned int*)l,
        16, 0, 0);
}

// ---------------- fp32 -> bf16 conversion (x8 vectorized) ----------------
__global__ __launch_bounds__(256) void f32_to_bf16(const float* __restrict__ in,
                                                   u16* __restrict__ out, long n) {
    long i = ((long)blockIdx.x * blockDim.x + threadIdx.x) * 8;
    long stride = (long)gridDim.x * blockDim.x * 8;
    for (; i < n; i += stride) {
        float4 a = *(const float4*)(in + i);
        float4 b = *(const float4*)(in + i + 4);
        u16x8 o;
        o[0] = f2bf(a.x); o[1] = f2bf(a.y); o[2] = f2bf(a.z); o[3] = f2bf(a.w);
        o[4] = f2bf(b.x); o[5] = f2bf(b.y); o[6] = f2bf(b.z); o[7] = f2bf(b.w);
        *(u16x8*)(out + i) = o;
    }
}

// ---------------- generic GEMM: C[m][n] = sum_k A[m][k]*B[n][k] ----------------
// Max-occupancy 2-phase (r10 schedule, thinner steps): 128x128 tile, BK=32,
// 8 waves (2M x 4N, 64x32 out/wave, 8 MFMA/wave/step), LDS 32 KiB dbuf
// (2 x 8 KiB per matrix) -> LDS cap 5 WG/CU, HW wave cap 32 -> 4 WG/CU =
// 8 waves/SIMD, 2x r10's TLP. The per-step vmcnt(0) drain is hidden by
// co-resident waves (m114); the schedule itself is the proven 2-phase.
// Staging map (r13-proven, 0 conflicts): thread -> row tid>>2, phys chunk
// tid&3, global chunk = p ^ ((row>>1)&3); read side shares the XOR -> 2-way
// banking (free, m136). Split-K via blockIdx.z supplies grid where M*N/128^2
// < 1024 WGs (out-proj): fp32 partials at Cv + z*M*N (OUT_BF16=0 only).
template <int OUT_BF16>
__global__ __launch_bounds__(512) void gemm_bt(const u16* __restrict__ A,
                                               const u16* __restrict__ B,
                                               void* __restrict__ Cv,
                                               int M, int N, int Kslice, long ldk) {
    __shared__ u16 As[2][128 * 32];   // 2 x 8 KiB
    __shared__ u16 Bs[2][128 * 32];
    const int tid = threadIdx.x;
    const int lane = tid & 63;
    const int w = tid >> 6;            // 0..7
    const int wr = w >> 2, wc = w & 3; // wave grid 2M x 4N
    const int l15 = lane & 15, lg = lane >> 4;
    const int n0 = blockIdx.x * 128;
    const int m0 = blockIdx.y * 128;
    const long kbase = (long)blockIdx.z * Kslice;

    // staging: row r=tid>>2 (0..127), phys 16B chunk p=tid&3 of the 64B row;
    // global chunk g = p ^ ((r>>1)&3). Wave dest base &buf[w*512] is uniform.
    const int r = tid >> 2;
    const int p = tid & 3;
    const int g = p ^ ((r >> 1) & 3);
    const u16* asrc = A + (long)(m0 + r) * ldk + kbase + g * 8;
    int brow = n0 + r; if (brow >= N) brow = N - 1;
    const u16* bsrc = B + (long)brow * ldk + kbase + g * 8;

    f32x4 acc[4][2];
    const f32x4 z = {0.f, 0.f, 0.f, 0.f};
#pragma unroll
    for (int i = 0; i < 4; ++i)
#pragma unroll
        for (int j = 0; j < 2; ++j) acc[i][j] = z;

    auto stage = [&](int bufi, long ko) {
        gld_lds16(asrc + ko, &As[bufi][w * 512]);
        gld_lds16(bsrc + ko, &Bs[bufi][w * 512]);
    };

    const int T = Kslice >> 5;
    stage(0, 0);
    asm volatile("s_waitcnt vmcnt(0)" ::: "memory");
    __builtin_amdgcn_s_barrier();

    int cur = 0;
    for (int t = 0; t < T; ++t) {
        if (t + 1 < T) stage(cur ^ 1, (long)(t + 1) * 32);
        const u16* Ab = As[cur];
        const u16* Bb = Bs[cur];
        bf16x8 a[4], b[2];
#pragma unroll
        for (int i = 0; i < 4; ++i) {
            int row = wr * 64 + i * 16 + l15;
            a[i] = *(const bf16x8*)&Ab[row * 32 + (lg ^ ((row >> 1) & 3)) * 8];
        }
#pragma unroll
        for (int j = 0; j < 2; ++j) {
            int row = wc * 32 + j * 16 + l15;
            b[j] = *(const bf16x8*)&Bb[row * 32 + (lg ^ ((row >> 1) & 3)) * 8];
        }
#pragma unroll
        for (int i = 0; i < 4; ++i)
#pragma unroll
            for (int j = 0; j < 2; ++j)
                acc[i][j] = __builtin_amdgcn_mfma_f32_16x16x32_bf16(a[i], b[j], acc[i][j], 0, 0, 0);
        asm volatile("s_waitcnt vmcnt(0)" ::: "memory");
        __builtin_amdgcn_s_barrier();
        cur ^= 1;
    }

#pragma unroll
    for (int i = 0; i < 4; ++i)
#pragma unroll
        for (int j = 0; j < 2; ++j)
#pragma unroll
            for (int rr = 0; rr < 4; ++rr) {
                int m = m0 + wr * 64 + i * 16 + lg * 4 + rr;
                int n = n0 + wc * 32 + j * 16 + l15;
                if (n < N) {
                    if (OUT_BF16)
                        ((u16*)Cv)[(long)m * N + n] = f2bf(acc[i][j][rr]);
                    else
                        ((float*)Cv)[(long)blockIdx.z * M * N + (long)m * N + n] = acc[i][j][rr];
                }
            }
}

// ---------------- sum split-K partials (fp32), x4 vectorized ----------------
__global__ __launch_bounds__(256) void reduce_parts(const float* __restrict__ parts,
                                                    float* __restrict__ out,
                                                    int nparts, long mn) {
    long i = ((long)blockIdx.x * 256 + threadIdx.x) * 4;
    long stride = (long)gridDim.x * 256 * 4;
    for (; i < mn; i += stride) {
        float4 s = *(const float4*)(parts + i);
        for (int p = 1; p < nparts; ++p) {
            float4 v = *(const float4*)(parts + (long)p * mn + i);
            s.x += v.x; s.y += v.y; s.z += v.z; s.w += v.w;
        }
        *(float4*)(out + i) = s;
    }
}

// ---------------- RMSNorm (row-wise): y = x * rsqrt(mean(x^2)+eps) * w ----------------
__global__ __launch_bounds__(256) void rmsnorm_kernel(const float* __restrict__ x,
                                                      const float* __restrict__ w,
                                                      u16* __restrict__ y,
                                                      int stride, int norm_len) {
    const int row = blockIdx.x;
    const float* xr = x + (long)row * stride;
    float ss = 0.f;
    for (int i = threadIdx.x; i < norm_len; i += 256) {
        float v = xr[i];
        ss += v * v;
    }
#pragma unroll
    for (int off = 32; off > 0; off >>= 1) ss += __shfl_down(ss, off);
    __shared__ float partial[4];
    if ((threadIdx.x & 63) == 0) partial[threadIdx.x >> 6] = ss;
    __syncthreads();
    float tot = partial[0] + partial[1] + partial[2] + partial[3];
    float rs = 1.0f / sqrtf(tot / (float)norm_len + RMS_EPS);
    u16* yr = y + (long)row * norm_len;
    for (int i = threadIdx.x; i < norm_len; i += 256) yr[i] = f2bf(xr[i] * rs * w[i]);
}

// ---------------- RoPE tables (fp32): cos/sin[s][i], i<32 ----------------
__global__ void rope_tables(float* __restrict__ cos_t, float* __restrict__ sin_t) {
    int s = blockIdx.x;
    int i = threadIdx.x;  // 32 threads
    float invf = powf(10000.0f, -((float)(2 * i) / 64.0f));
    float ang = (float)s * invf;
    cos_t[s * 32 + i] = cosf(ang);
    sin_t[s * 32 + i] = sinf(ang);
}

// ---------------- RoPE on q_r, in-place on q_cr (bf16) ----------------
__global__ void rope_q(u16* __restrict__ q_cr, const float* __restrict__ cos_t,
                       const float* __restrict__ sin_t) {
    int s = blockIdx.x;
    int h = blockIdx.y * 2 + (threadIdx.x >> 5);
    int i = threadIdx.x & 31;
    u16* base = q_cr + (s * (NHEAD * 192) + h * 192 + QKD);
    float x1 = bf2f(base[i]);
    float x2 = bf2f(base[i + 32]);
    float c = cos_t[s * 32 + i], sn = sin_t[s * 32 + i];
    base[i]      = f2bf(x1 * c - x2 * sn);
    base[i + 32] = f2bf(x2 * c + x1 * sn);
}

// ---------------- RoPE on k_r (from fp32 ckv_kr cols 512..576) -> bf16 kr ----------------
__global__ void rope_k(const float* __restrict__ ckv_kr, const float* __restrict__ cos_t,
                       const float* __restrict__ sin_t, u16* __restrict__ kr) {
    int s = blockIdx.x;
    int i = threadIdx.x;  // 64 threads; first 32 active
    if (i < 32) {
        const float* base = ckv_kr + (s * 576 + 512);
        float x1 = base[i], x2 = base[i + 32];
        float c = cos_t[s * 32 + i], sn = sin_t[s * 32 + i];
        kr[s * 64 + i]      = f2bf(x1 * c - x2 * sn);
        kr[s * 64 + i + 32] = f2bf(x2 * c + x1 * sn);
    }
}

// ---------------- build vT[h][dv][s] from kv[s][h*256+128+dv] ----------------
__global__ __launch_bounds__(256) void build_vt(const u16* __restrict__ kv,
                                                u16* __restrict__ vT) {
    __shared__ u16 vtile[64][136];  // 272B row stride (16B aligned)
    const int h = blockIdx.x, sb = blockIdx.y, s0 = sb * 64;
    const int tid = threadIdx.x;
#pragma unroll
    for (int it = 0; it < 4; ++it) {
        int c = it * 256 + tid;
        int row = c >> 4;
        int off8 = (c & 15) * 8;
        *(u16x8*)&vtile[row][off8] =
            *(const u16x8*)&kv[(s0 + row) * 32768 + h * 256 + 128 + off8];
    }
    __syncthreads();
    const int sl = tid & 63;
    const int dvb = tid >> 6;  // 0..3
#pragma unroll
    for (int it = 0; it < 32; ++it) {
        int dv = dvb + it * 4;
        vT[(h * 128 + dv) * 1024 + s0 + sl] = vtile[sl][dv];
    }
}

// ---------------- flash attention: 1 block = 128 queries x 1 head, 8 waves ----------------
// T14 async-STAGE (reg prefetch of next tile under compute) + T5 setprio
// around MFMA clusters. p_lds is wave-private -> no barrier after P-write.
__global__ __launch_bounds__(512) void mla_attn(const u16* __restrict__ q_cr,
                                                const u16* __restrict__ kv,
                                                const u16* __restrict__ kr,
                                                const u16* __restrict__ vT,
                                                u16* __restrict__ o_g) {
    __shared__ u16 ks[64][200];        // 64 keys x 192 dims (+pad)
    __shared__ u16 vts[128][72];       // 128 dv x 64 k (+pad)
    __shared__ u16 p_lds[8][16][72];   // per wave: 16 q x 64 k (+pad)
    const int qb = blockIdx.x, h = blockIdx.y;
    const int s0q = qb * 128;
    const int tid = threadIdx.x, lane = tid & 63, w = tid >> 6;
    const int l15 = lane & 15, lg = lane >> 4;
    const float scale = 0.07216878364870323f;  // 1/sqrt(192)

    // Q in registers, A-fragment layout (row = l15, k contiguous per lg group)
    bf16x8 qreg[6];
    {
        const int qrow = s0q + w * 16 + l15;
#pragma unroll
        for (int kk = 0; kk < 6; ++kk)
            qreg[kk] = *(const bf16x8*)&q_cr[qrow * (NHEAD * 192) + h * 192 + kk * 32 + lg * 8];
    }

    // staging-index precompute (512 threads cover: K 2x, kr 1x, V 2x u16x8 each)
    const int krow0 = tid >> 4,           koff0 = (tid & 15) * 8;
    const int krow1 = (512 + tid) >> 4,   koff1 = ((512 + tid) & 15) * 8;
    const int rrow  = tid >> 3,           roff  = (tid & 7) * 8;
    const int vdv0  = tid >> 3,           voff0 = (tid & 7) * 8;
    const int vdv1  = (512 + tid) >> 3,   voff1 = ((512 + tid) & 7) * 8;
    const u16* kvp = kv + h * 256;
    const u16* vtp = vT + (long)(h * 128) * 1024;

    u16x8 kreg0, kreg1, krreg, vreg0, vreg1;
    auto load_tile = [&](int s0k) {
        kreg0 = *(const u16x8*)&kvp[(long)(s0k + krow0) * 32768 + koff0];
        kreg1 = *(const u16x8*)&kvp[(long)(s0k + krow1) * 32768 + koff1];
        krreg = *(const u16x8*)&kr[(s0k + rrow) * 64 + roff];
        vreg0 = *(const u16x8*)&vtp[(long)vdv0 * 1024 + s0k + voff0];
        vreg1 = *(const u16x8*)&vtp[(long)vdv1 * 1024 + s0k + voff1];
    };

    f32x4 o_acc[8];
    const f32x4 z = {0.f, 0.f, 0.f, 0.f};
#pragma unroll
    for (int d = 0; d < 8; ++d) o_acc[d] = z;
    float m_r[4], l_r[4];
#pragma unroll
    for (int r = 0; r < 4; ++r) { m_r[r] = -1e30f; l_r[r] = 0.f; }

    load_tile(0);

    for (int kt = 0; kt < 16; ++kt) {
        __syncthreads();   // prev tile's readers done
        *(u16x8*)&ks[krow0][koff0]      = kreg0;
        *(u16x8*)&ks[krow1][koff1]      = kreg1;
        *(u16x8*)&ks[rrow][128 + roff]  = krreg;
        *(u16x8*)&vts[vdv0][voff0]      = vreg0;
        *(u16x8*)&vts[vdv1][voff1]      = vreg1;
        __syncthreads();   // tile staged
        if (kt + 1 < 16) load_tile((kt + 1) * 64);   // async: hides under compute

        // QK^T : S-frags (16 q x 64 keys per wave)
        f32x4 sf[4];
#pragma unroll
        for (int j = 0; j < 4; ++j) sf[j] = z;
        __builtin_amdgcn_s_setprio(1);
#pragma unroll
        for (int kk = 0; kk < 6; ++kk) {
            bf16x8 a = qreg[kk];
#pragma unroll
            for (int j = 0; j < 4; ++j) {
                bf16x8 b = *(const bf16x8*)&ks[j * 16 + l15][kk * 32 + lg * 8];
                sf[j] = __builtin_amdgcn_mfma_f32_16x16x32_bf16(a, b, sf[j], 0, 0, 0);
            }
        }
        __builtin_amdgcn_s_setprio(0);

        // online softmax (rows live in C-layout: row=(lg)*4+r, col=j*16+l15)
        float p[4][4];
        float alpha[4];
#pragma unroll
        for (int r = 0; r < 4; ++r) {
            float mx = fmaxf(fmaxf(sf[0][r], sf[1][r]), fmaxf(sf[2][r], sf[3][r]));
#pragma unroll
            for (int off = 1; off < 16; off <<= 1) mx = fmaxf(mx, __shfl_xor(mx, off));
            mx *= scale;
            float mnew = fmaxf(m_r[r], mx);
            alpha[r] = __expf(m_r[r] - mnew);
            float rs = 0.f;
#pragma unroll
            for (int j = 0; j < 4; ++j) {
                float pv = __expf(sf[j][r] * scale - mnew);
                p[j][r] = pv;
                rs += pv;
            }
#pragma unroll
            for (int off = 1; off < 16; off <<= 1) rs += __shfl_xor(rs, off);
            l_r[r] = l_r[r] * alpha[r] + rs;
            m_r[r] = mnew;
        }
#pragma unroll
        for (int d = 0; d < 8; ++d)
#pragma unroll
            for (int r = 0; r < 4; ++r) o_acc[d][r] *= alpha[r];

        // P -> LDS (wave-private; no block barrier needed)
#pragma unroll
        for (int j = 0; j < 4; ++j)
#pragma unroll
            for (int r = 0; r < 4; ++r)
                p_lds[w][lg * 4 + r][j * 16 + l15] = f2bf(p[j][r]);

        // PV: O += P @ V
        __builtin_amdgcn_s_setprio(1);
#pragma unroll
        for (int kk2 = 0; kk2 < 2; ++kk2) {
            bf16x8 a = *(const bf16x8*)&p_lds[w][l15][kk2 * 32 + lg * 8];
#pragma unroll
            for (int d = 0; d < 8; ++d) {
                bf16x8 b = *(const bf16x8*)&vts[d * 16 + l15][kk2 * 32 + lg * 8];
                o_acc[d] = __builtin_amdgcn_mfma_f32_16x16x32_bf16(a, b, o_acc[d], 0, 0, 0);
            }
        }
        __builtin_amdgcn_s_setprio(0);
    }

    // epilogue: divide by l, store bf16 o[s][h*128+dv]
#pragma unroll
    for (int d = 0; d < 8; ++d)
#pragma unroll
        for (int r = 0; r < 4; ++r) {
            int srow = s0q + w * 16 + lg * 4 + r;
            float v = o_acc[d][r] / l_r[r];
            o_g[srow * 16384 + h * 128 + d * 16 + l15] = f2bf(v);
        }
}

// ---------------- host launcher ----------------
extern "C" void kernel_launch(void* const* d_in, const int* in_sizes, int n_in,
                              void* d_out, int out_size, void* d_ws, size_t ws_size,
                              hipStream_t stream) {
    const float* hs        = (const float*)d_in[0];
    const float* w_q_down  = (const float*)d_in[1];
    const float* q_norm_w  = (const float*)d_in[2];
    const float* w_q_up    = (const float*)d_in[3];
    const float* w_kv_down = (const float*)d_in[4];
    const float* kv_norm_w = (const float*)d_in[5];
    const float* w_kv_up   = (const float*)d_in[6];
    const float* w_out     = (const float*)d_in[7];
    float* out = (float*)d_out;
    char* ws = (char*)d_ws;

    // ---- workspace layout (contiguous front region is reused for w_out bf16) ----
    const size_t SZ_HS   = (size_t)SEQ * HIDN * 2;
    const size_t SZ_KV   = (size_t)SEQ * 32768 * 2;
    const size_t SZ_QCR  = (size_t)SEQ * (NHEAD * 192) * 2;
    const size_t SZ_VT   = (size_t)NHEAD * 128 * 1024 * 2;
    const size_t SZ_WB   = (size_t)24576 * 1536 * 2;
    const size_t SZ_CQ   = (size_t)SEQ * QLRANK * 4;
    const size_t SZ_CQN  = (size_t)SEQ * QLRANK * 2;
    const size_t SZ_CKV  = (size_t)SEQ * 576 * 4;
    const size_t SZ_CKVN = (size_t)SEQ * KVLRANK * 2;
    const size_t SZ_KR   = (size_t)SEQ * 64 * 2;
    const size_t SZ_OG   = (size_t)SEQ * 16384 * 2;
    const size_t SZ_TAB  = (size_t)SEQ * 32 * 4;

    size_t off = 0;
    u16* hs_bf  = (u16*)(ws + off); off += SZ_HS;
    u16* kvb    = (u16*)(ws + off); off += SZ_KV;
    u16* q_cr   = (u16*)(ws + off); off += SZ_QCR;
    u16* vT     = (u16*)(ws + off); off += SZ_VT;
    u16* W_BUF  = (u16*)(ws + off); off += SZ_WB;
    // split-K partials for c_q/kv_down alias upper W_BUF region (+32MB; weight
    // there is <32MB while these gemms run).
    float* parts = (float*)((char*)W_BUF + 33554432);
    // w_out bf16 (234,881,024 B) aliases [ws .. 235MB), all dead by then
    u16* wout_bf = (u16*)ws;
    float* c_q    = (float*)(ws + off); off += SZ_CQ;
    u16* cq_n     = (u16*)(ws + off); off += SZ_CQN;
    float* ckv_kr = (float*)(ws + off); off += SZ_CKV;
    u16* ckv_n    = (u16*)(ws + off); off += SZ_CKVN;
    u16* kr       = (u16*)(ws + off); off += SZ_KR;
    u16* o_g      = (u16*)(ws + off); off += SZ_OG;
    float* cos_t  = (float*)(ws + off); off += SZ_TAB;
    float* sin_t  = (float*)(ws + off); off += SZ_TAB;
    // out-proj split-K x2 partials at tail (r6/r7 proved tail fits >=4 slices)
    float* parts_op = (float*)(ws + off);
    const size_t szp1 = (size_t)SEQ * HIDN * 4;
    const int nsplit = (off + 2 * szp1 <= ws_size) ? 2 : 1;
    (void)in_sizes; (void)n_in; (void)out_size;

    rope_tables<<<dim3(SEQ), dim3(32), 0, stream>>>(cos_t, sin_t);
    f32_to_bf16<<<2048, 256, 0, stream>>>(hs, hs_bf, (long)SEQ * HIDN);

    // c_q = hs @ w_q_down^T   (split-K x4: 7168 = 4 x 1792)
    f32_to_bf16<<<2048, 256, 0, stream>>>(w_q_down, W_BUF, (long)QLRANK * HIDN);
    gemm_bt<0><<<dim3(QLRANK / 128, SEQ / 128, 4), 512, 0, stream>>>(hs_bf, W_BUF, parts, SEQ, QLRANK, HIDN / 4, HIDN);
    reduce_parts<<<1024, 256, 0, stream>>>(parts, c_q, 4, (long)SEQ * QLRANK);
    rmsnorm_kernel<<<SEQ, 256, 0, stream>>>(c_q, q_norm_w, cq_n, QLRANK, QLRANK);

    // q_cr = rmsnorm(c_q) @ w_q_up^T   (1536 WGs -> 4 WG/CU at 32KiB LDS)
    f32_to_bf16<<<2048, 256, 0, stream>>>(w_q_up, W_BUF, (long)24576 * QLRANK);
    gemm_bt<1><<<dim3(24576 / 128, SEQ / 128), 512, 0, stream>>>(cq_n, W_BUF, q_cr, SEQ, 24576, QLRANK, QLRANK);

    // ckv_kr = hs @ w_kv_down^T   (split-K x8; N=576 ragged)
    f32_to_bf16<<<2048, 256, 0, stream>>>(w_kv_down, W_BUF, (long)576 * HIDN);
    gemm_bt<0><<<dim3(5, SEQ / 128, 8), 512, 0, stream>>>(hs_bf, W_BUF, parts, SEQ, 576, HIDN / 8, HIDN);
    reduce_parts<<<1024, 256, 0, stream>>>(parts, ckv_kr, 8, (long)SEQ * 576);
    rmsnorm_kernel<<<SEQ, 256, 0, stream>>>(ckv_kr, kv_norm_w, ckv_n, 576, KVLRANK);
    rope_k<<<SEQ, 64, 0, stream>>>(ckv_kr, cos_t, sin_t, kr);

    // kv = rmsnorm(c_kv) @ w_kv_up^T   (2048 WGs -> 4 WG/CU)
    f32_to_bf16<<<2048, 256, 0, stream>>>(w_kv_up, W_BUF, (long)32768 * KVLRANK);
    gemm_bt<1><<<dim3(32768 / 128, SEQ / 128), 512, 0, stream>>>(ckv_n, W_BUF, kvb, SEQ, 32768, KVLRANK, KVLRANK);

    rope_q<<<dim3(SEQ, NHEAD / 2), 64, 0, stream>>>(q_cr, cos_t, sin_t);
    build_vt<<<dim3(NHEAD, SEQ / 64), 256, 0, stream>>>(kvb, vT);

    mla_attn<<<dim3(SEQ / 128, NHEAD), 512, 0, stream>>>(q_cr, kvb, kr, vT, o_g);

    // out = o @ w_out^T   (split-K x2 -> 896 WGs -> ~3.5 WG/CU at 32KiB LDS;
    // natural dispatch keeps each B-strip on one XCD's L2: gridDim.x 56 %8==0)
    f32_to_bf16<<<4096, 256, 0, stream>>>(w_out, wout_bf, (long)HIDN * 16384);
    if (nsplit == 2) {
        gemm_bt<0><<<dim3(HIDN / 128, SEQ / 128, 2), 512, 0, stream>>>(o_g, wout_bf, parts_op, SEQ, HIDN, 16384 / 2, 16384);
        reduce_parts<<<1024, 256, 0, stream>>>(parts_op, out, 2, (long)SEQ * HIDN);
    } else {
        gemm_bt<0><<<dim3(HIDN / 128, SEQ / 128), 512, 0, stream>>>(o_g, wout_bf, out, SEQ, HIDN, 16384, 16384);
    }
}

// Round 15
// 977.348 us; speedup vs baseline: 1.0910x; 1.0357x over previous
//
#include <hip/hip_runtime.h>
#include <hip/hip_bf16.h>
#include <math.h>

// ---- problem constants ----
#define HIDN 7168
#define NHEAD 128
#define QLRANK 1536
#define KVLRANK 512
#define QKD 128
#define VHD 128
#define RHD 64
#define SEQ 1024
#define RMS_EPS 1.1920929e-07f

typedef unsigned short u16;
typedef __attribute__((ext_vector_type(8))) short bf16x8;
typedef __attribute__((ext_vector_type(4))) float f32x4;
typedef __attribute__((ext_vector_type(8))) unsigned short u16x8;

__device__ __forceinline__ u16 f2bf(float f) {
    unsigned int u = __float_as_uint(f);
    unsigned int r = (u + 0x7FFFu + ((u >> 16) & 1u)) >> 16;
    return (u16)r;
}
__device__ __forceinline__ float bf2f(u16 v) {
    return __uint_as_float(((unsigned int)v) << 16);
}

// async global->LDS, 16B per lane. LDS dest is wave-uniform base + lane*16.
__device__ __forceinline__ void gld_lds16(const u16* g, u16* l) {
    __builtin_amdgcn_global_load_lds(
        (const __attribute__((address_space(1))) unsigned int*)g,
        (__attribute__((address_space(3))) unsigned int*)l,
        16, 0, 0);
}

// ---------------- fp32 -> bf16 conversion (x8 vectorized) ----------------
__global__ __launch_bounds__(256) void f32_to_bf16(const float* __restrict__ in,
                                                   u16* __restrict__ out, long n) {
    long i = ((long)blockIdx.x * blockDim.x + threadIdx.x) * 8;
    long stride = (long)gridDim.x * blockDim.x * 8;
    for (; i < n; i += stride) {
        float4 a = *(const float4*)(in + i);
        float4 b = *(const float4*)(in + i + 4);
        u16x8 o;
        o[0] = f2bf(a.x); o[1] = f2bf(a.y); o[2] = f2bf(a.z); o[3] = f2bf(a.w);
        o[4] = f2bf(b.x); o[5] = f2bf(b.y); o[6] = f2bf(b.z); o[7] = f2bf(b.w);
        *(u16x8*)(out + i) = o;
    }
}

// ---------------- generic GEMM (r10-proven): C[m][n] = sum_k A[m][k]*B[n][k] ----------------
// 128x128 tile, BK=64, 8 waves (2M x 4N, 64x32 out/wave), LDS 64 KiB dbuf ->
// 2 WG/CU x 8 waves = 4 waves/SIMD TLP; one vmcnt(0)+s_barrier per K-step
// (drain hidden by cross-wave TLP, m114). global_load_lds(16) staging with
// coalesced row-grouped source map + XOR chunk swizzle (0 bank conflicts).
// Natural dispatch order keeps each B-strip on one XCD's L2 (gridDim.x%8==0).
// Split-K via blockIdx.z: fp32 partials at Cv + z*M*N (OUT_BF16=0 only).
template <int OUT_BF16>
__global__ __launch_bounds__(512) void gemm_bt(const u16* __restrict__ A,
                                               const u16* __restrict__ B,
                                               void* __restrict__ Cv,
                                               int M, int N, int Kslice, long ldk) {
    __shared__ u16 As[2 * 128 * 64];   // 2 x 16 KiB
    __shared__ u16 Bs[2 * 128 * 64];
    const int tid = threadIdx.x;
    const int lane = tid & 63;
    const int w = tid >> 6;            // 0..7
    const int wr = w >> 2, wc = w & 3; // wave grid 2M x 4N
    const int l15 = lane & 15, lg = lane >> 4;
    const int n0 = blockIdx.x * 128;
    const int m0 = blockIdx.y * 128;
    const long kbase = (long)blockIdx.z * Kslice;

    // staging: 2 issues per wave per matrix; each issue = 8 rows x 64 cols.
    const u16* asrc[2];
    const u16* bsrc[2];
    int aoff[2];
#pragma unroll
    for (int i = 0; i < 2; ++i) {
        int r = (w * 2 + i) * 8 + (lane >> 3);
        int gc = (lane & 7) ^ (r & 7);
        asrc[i] = A + (long)(m0 + r) * ldk + kbase + gc * 8;
        int br = n0 + r; if (br >= N) br = N - 1;
        bsrc[i] = B + (long)br * ldk + kbase + gc * 8;
        aoff[i] = (w * 2 + i) * 512;
    }

    f32x4 acc[4][2];
    const f32x4 z = {0.f, 0.f, 0.f, 0.f};
#pragma unroll
    for (int i = 0; i < 4; ++i)
#pragma unroll
        for (int j = 0; j < 2; ++j) acc[i][j] = z;

    auto stage = [&](int bufi, int kofs) {
#pragma unroll
        for (int i = 0; i < 2; ++i) {
            gld_lds16(asrc[i] + kofs, As + bufi * 8192 + aoff[i]);
            gld_lds16(bsrc[i] + kofs, Bs + bufi * 8192 + aoff[i]);
        }
    };

    const int nsteps = Kslice >> 6;
    stage(0, 0);
    asm volatile("s_waitcnt vmcnt(0)" ::: "memory");
    __builtin_amdgcn_s_barrier();

    int cur = 0;
    for (int t = 0; t < nsteps; ++t) {
        if (t + 1 < nsteps) stage(cur ^ 1, (t + 1) * 64);
        const u16* Ab = As + cur * 8192;
        const u16* Bb = Bs + cur * 8192;
#pragma unroll
        for (int kk = 0; kk < 2; ++kk) {
            bf16x8 a[4], b[2];
#pragma unroll
            for (int i = 0; i < 4; ++i) {
                int row = wr * 64 + i * 16 + l15;
                a[i] = *(const bf16x8*)&Ab[row * 64 + ((kk * 4 + lg) ^ (row & 7)) * 8];
            }
#pragma unroll
            for (int j = 0; j < 2; ++j) {
                int row = wc * 32 + j * 16 + l15;
                b[j] = *(const bf16x8*)&Bb[row * 64 + ((kk * 4 + lg) ^ (row & 7)) * 8];
            }
#pragma unroll
            for (int i = 0; i < 4; ++i)
#pragma unroll
                for (int j = 0; j < 2; ++j)
                    acc[i][j] = __builtin_amdgcn_mfma_f32_16x16x32_bf16(a[i], b[j], acc[i][j], 0, 0, 0);
        }
        asm volatile("s_waitcnt vmcnt(0)" ::: "memory");
        __builtin_amdgcn_s_barrier();
        cur ^= 1;
    }

#pragma unroll
    for (int i = 0; i < 4; ++i)
#pragma unroll
        for (int j = 0; j < 2; ++j)
#pragma unroll
            for (int r = 0; r < 4; ++r) {
                int m = m0 + wr * 64 + i * 16 + lg * 4 + r;
                int n = n0 + wc * 32 + j * 16 + l15;
                if (n < N) {
                    if (OUT_BF16)
                        ((u16*)Cv)[(long)m * N + n] = f2bf(acc[i][j][r]);
                    else
                        ((float*)Cv)[(long)blockIdx.z * M * N + (long)m * N + n] = acc[i][j][r];
                }
            }
}

// ---------------- sum split-K partials (fp32), x4 vectorized ----------------
__global__ __launch_bounds__(256) void reduce_parts(const float* __restrict__ parts,
                                                    float* __restrict__ out,
                                                    int nparts, long mn) {
    long i = ((long)blockIdx.x * 256 + threadIdx.x) * 4;
    long stride = (long)gridDim.x * 256 * 4;
    for (; i < mn; i += stride) {
        float4 s = *(const float4*)(parts + i);
        for (int p = 1; p < nparts; ++p) {
            float4 v = *(const float4*)(parts + (long)p * mn + i);
            s.x += v.x; s.y += v.y; s.z += v.z; s.w += v.w;
        }
        *(float4*)(out + i) = s;
    }
}

// ---------------- RMSNorm (row-wise): y = x * rsqrt(mean(x^2)+eps) * w ----------------
__global__ __launch_bounds__(256) void rmsnorm_kernel(const float* __restrict__ x,
                                                      const float* __restrict__ w,
                                                      u16* __restrict__ y,
                                                      int stride, int norm_len) {
    const int row = blockIdx.x;
    const float* xr = x + (long)row * stride;
    float ss = 0.f;
    for (int i = threadIdx.x; i < norm_len; i += 256) {
        float v = xr[i];
        ss += v * v;
    }
#pragma unroll
    for (int off = 32; off > 0; off >>= 1) ss += __shfl_down(ss, off);
    __shared__ float partial[4];
    if ((threadIdx.x & 63) == 0) partial[threadIdx.x >> 6] = ss;
    __syncthreads();
    float tot = partial[0] + partial[1] + partial[2] + partial[3];
    float rs = 1.0f / sqrtf(tot / (float)norm_len + RMS_EPS);
    u16* yr = y + (long)row * norm_len;
    for (int i = threadIdx.x; i < norm_len; i += 256) yr[i] = f2bf(xr[i] * rs * w[i]);
}

// ---------------- RoPE tables (fp32): cos/sin[s][i], i<32 ----------------
__global__ void rope_tables(float* __restrict__ cos_t, float* __restrict__ sin_t) {
    int s = blockIdx.x;
    int i = threadIdx.x;  // 32 threads
    float invf = powf(10000.0f, -((float)(2 * i) / 64.0f));
    float ang = (float)s * invf;
    cos_t[s * 32 + i] = cosf(ang);
    sin_t[s * 32 + i] = sinf(ang);
}

// ---------------- RoPE on q_r, in-place on q_cr (bf16) ----------------
__global__ void rope_q(u16* __restrict__ q_cr, const float* __restrict__ cos_t,
                       const float* __restrict__ sin_t) {
    int s = blockIdx.x;
    int h = blockIdx.y * 2 + (threadIdx.x >> 5);
    int i = threadIdx.x & 31;
    u16* base = q_cr + (s * (NHEAD * 192) + h * 192 + QKD);
    float x1 = bf2f(base[i]);
    float x2 = bf2f(base[i + 32]);
    float c = cos_t[s * 32 + i], sn = sin_t[s * 32 + i];
    base[i]      = f2bf(x1 * c - x2 * sn);
    base[i + 32] = f2bf(x2 * c + x1 * sn);
}

// ---------------- RoPE on k_r (from fp32 ckv_kr cols 512..576) -> bf16 kr ----------------
__global__ void rope_k(const float* __restrict__ ckv_kr, const float* __restrict__ cos_t,
                       const float* __restrict__ sin_t, u16* __restrict__ kr) {
    int s = blockIdx.x;
    int i = threadIdx.x;  // 64 threads; first 32 active
    if (i < 32) {
        const float* base = ckv_kr + (s * 576 + 512);
        float x1 = base[i], x2 = base[i + 32];
        float c = cos_t[s * 32 + i], sn = sin_t[s * 32 + i];
        kr[s * 64 + i]      = f2bf(x1 * c - x2 * sn);
        kr[s * 64 + i + 32] = f2bf(x2 * c + x1 * sn);
    }
}

// ---------------- flash attention + fused w_out conversion ----------------
// 1 block = 128 queries x 1 head, 8 waves. V is read DIRECTLY from kv and
// transposed in-LDS (vtile bounce, build_vt inlined) -> vT buffer and
// build_vt kernel eliminated (frees 33.5MB so wout_bf fits in proven ws).
// Fused conversion: attention is compute-bound (<1 TB/s of 6.3); each block
// converts its 229KB share of w_out fp32->bf16 spread over the 16 K/V tiles,
// hiding the 705MB round-trip under MFMA time (inverse of the r12 lesson).
// Barriers/tile: b1 (prev readers done) -> stage writes -> b2 (staged) ->
// [prefetch + convert + transpose vtile->vts + QK^T + softmax + P-write] ->
// b3 (vts ready) -> PV. p_lds stays wave-private.
__global__ __launch_bounds__(512) void mla_attn(const u16* __restrict__ q_cr,
                                                const u16* __restrict__ kv,
                                                const u16* __restrict__ kr,
                                                u16* __restrict__ o_g,
                                                const float* __restrict__ wsrc,
                                                u16* __restrict__ wdst,
                                                int do_conv) {
    __shared__ u16 ks[64][200];        // 64 keys x 192 dims (+pad)        25600B
    __shared__ u16 vts[128][72];       // 128 dv x 64 k (+pad)             18432B
    __shared__ u16 p_lds[8][16][72];   // per wave: 16 q x 64 k (+pad)     18432B
    __shared__ u16 vtile[64][136];     // V rows staging (+pad)            17408B
    const int qb = blockIdx.x, h = blockIdx.y;
    const int s0q = qb * 128;
    const int tid = threadIdx.x, lane = tid & 63, w = tid >> 6;
    const int l15 = lane & 15, lg = lane >> 4;
    const float scale = 0.07216878364870323f;  // 1/sqrt(192)

    // Q in registers, A-fragment layout
    bf16x8 qreg[6];
    {
        const int qrow = s0q + w * 16 + l15;
#pragma unroll
        for (int kk = 0; kk < 6; ++kk)
            qreg[kk] = *(const bf16x8*)&q_cr[qrow * (NHEAD * 192) + h * 192 + kk * 32 + lg * 8];
    }

    // staging-index precompute (512 threads: K 2x, kr 1x, V 2x u16x8 each)
    const int krow0 = tid >> 4,           koff0 = (tid & 15) * 8;
    const int krow1 = (512 + tid) >> 4,   koff1 = ((512 + tid) & 15) * 8;
    const int rrow  = tid >> 3,           roff  = (tid & 7) * 8;
    const u16* kvp = kv + h * 256;         // k_c columns
    const u16* kvv = kv + h * 256 + 128;   // V columns

    u16x8 kreg0, kreg1, krreg, vreg0, vreg1;
    auto load_tile = [&](int s0k) {
        kreg0 = *(const u16x8*)&kvp[(long)(s0k + krow0) * 32768 + koff0];
        kreg1 = *(const u16x8*)&kvp[(long)(s0k + krow1) * 32768 + koff1];
        krreg = *(const u16x8*)&kr[(s0k + rrow) * 64 + roff];
        vreg0 = *(const u16x8*)&kvv[(long)(s0k + krow0) * 32768 + koff0];
        vreg1 = *(const u16x8*)&kvv[(long)(s0k + krow1) * 32768 + koff1];
    };

    // fused-conversion indexing: 1024 blocks x 16 tiles x 896 u16x8 groups
    // = 14,680,064 groups = 7168*16384/8 exactly.
    const long cbase = ((long)(h * 8 + qb)) * 16 * 896;

    f32x4 o_acc[8];
    const f32x4 z = {0.f, 0.f, 0.f, 0.f};
#pragma unroll
    for (int d = 0; d < 8; ++d) o_acc[d] = z;
    float m_r[4], l_r[4];
#pragma unroll
    for (int r = 0; r < 4; ++r) { m_r[r] = -1e30f; l_r[r] = 0.f; }

    load_tile(0);

    for (int kt = 0; kt < 16; ++kt) {
        __syncthreads();   // b1: prev tile's readers done
        *(u16x8*)&ks[krow0][koff0]      = kreg0;
        *(u16x8*)&ks[krow1][koff1]      = kreg1;
        *(u16x8*)&ks[rrow][128 + roff]  = krreg;
        *(u16x8*)&vtile[krow0][koff0]   = vreg0;
        *(u16x8*)&vtile[krow1][koff1]   = vreg1;
        __syncthreads();   // b2: tile staged
        if (kt + 1 < 16) load_tile((kt + 1) * 64);   // T14 prefetch

        // fused w_out conversion chunk (hidden under this tile's compute)
        if (do_conv) {
            long g0 = cbase + (long)kt * 896;
#pragma unroll
            for (int ci = 0; ci < 2; ++ci) {
                int gi = ci * 512 + tid;
                if (gi < 896) {
                    long g8 = (g0 + gi) * 8;
                    float4 a = *(const float4*)(wsrc + g8);
                    float4 b = *(const float4*)(wsrc + g8 + 4);
                    u16x8 o;
                    o[0] = f2bf(a.x); o[1] = f2bf(a.y); o[2] = f2bf(a.z); o[3] = f2bf(a.w);
                    o[4] = f2bf(b.x); o[5] = f2bf(b.y); o[6] = f2bf(b.z); o[7] = f2bf(b.w);
                    *(u16x8*)(wdst + g8) = o;
                }
            }
        }

        // transpose vtile -> vts (each thread: 1 dv column x 16 s)
        {
            const int dv = tid >> 2;
            const int sb = (tid & 3) << 4;
#pragma unroll
            for (int i = 0; i < 16; ++i)
                vts[dv][sb + i] = vtile[sb + i][dv];
        }

        // QK^T : S-frags (16 q x 64 keys per wave)
        f32x4 sf[4];
#pragma unroll
        for (int j = 0; j < 4; ++j) sf[j] = z;
        __builtin_amdgcn_s_setprio(1);
#pragma unroll
        for (int kk = 0; kk < 6; ++kk) {
            bf16x8 a = qreg[kk];
#pragma unroll
            for (int j = 0; j < 4; ++j) {
                bf16x8 b = *(const bf16x8*)&ks[j * 16 + l15][kk * 32 + lg * 8];
                sf[j] = __builtin_amdgcn_mfma_f32_16x16x32_bf16(a, b, sf[j], 0, 0, 0);
            }
        }
        __builtin_amdgcn_s_setprio(0);

        // online softmax (rows in C-layout: row=lg*4+r, col=j*16+l15)
        float p[4][4];
        float alpha[4];
#pragma unroll
        for (int r = 0; r < 4; ++r) {
            float mx = fmaxf(fmaxf(sf[0][r], sf[1][r]), fmaxf(sf[2][r], sf[3][r]));
#pragma unroll
            for (int off = 1; off < 16; off <<= 1) mx = fmaxf(mx, __shfl_xor(mx, off));
            mx *= scale;
            float mnew = fmaxf(m_r[r], mx);
            alpha[r] = __expf(m_r[r] - mnew);
            float rs = 0.f;
#pragma unroll
            for (int j = 0; j < 4; ++j) {
                float pv = __expf(sf[j][r] * scale - mnew);
                p[j][r] = pv;
                rs += pv;
            }
#pragma unroll
            for (int off = 1; off < 16; off <<= 1) rs += __shfl_xor(rs, off);
            l_r[r] = l_r[r] * alpha[r] + rs;
            m_r[r] = mnew;
        }
#pragma unroll
        for (int d = 0; d < 8; ++d)
#pragma unroll
            for (int r = 0; r < 4; ++r) o_acc[d][r] *= alpha[r];

        // P -> LDS (wave-private)
#pragma unroll
        for (int j = 0; j < 4; ++j)
#pragma unroll
            for (int r = 0; r < 4; ++r)
                p_lds[w][lg * 4 + r][j * 16 + l15] = f2bf(p[j][r]);

        __syncthreads();   // b3: vts transpose complete block-wide

        // PV: O += P @ V
        __builtin_amdgcn_s_setprio(1);
#pragma unroll
        for (int kk2 = 0; kk2 < 2; ++kk2) {
            bf16x8 a = *(const bf16x8*)&p_lds[w][l15][kk2 * 32 + lg * 8];
#pragma unroll
            for (int d = 0; d < 8; ++d) {
                bf16x8 b = *(const bf16x8*)&vts[d * 16 + l15][kk2 * 32 + lg * 8];
                o_acc[d] = __builtin_amdgcn_mfma_f32_16x16x32_bf16(a, b, o_acc[d], 0, 0, 0);
            }
        }
        __builtin_amdgcn_s_setprio(0);
    }

    // epilogue: divide by l, store bf16 o[s][h*128+dv]
#pragma unroll
    for (int d = 0; d < 8; ++d)
#pragma unroll
        for (int r = 0; r < 4; ++r) {
            int srow = s0q + w * 16 + lg * 4 + r;
            float v = o_acc[d][r] / l_r[r];
            o_g[srow * 16384 + h * 128 + d * 16 + l15] = f2bf(v);
        }
}

// ---------------- host launcher ----------------
extern "C" void kernel_launch(void* const* d_in, const int* in_sizes, int n_in,
                              void* d_out, int out_size, void* d_ws, size_t ws_size,
                              hipStream_t stream) {
    const float* hs        = (const float*)d_in[0];
    const float* w_q_down  = (const float*)d_in[1];
    const float* q_norm_w  = (const float*)d_in[2];
    const float* w_q_up    = (const float*)d_in[3];
    const float* w_kv_down = (const float*)d_in[4];
    const float* kv_norm_w = (const float*)d_in[5];
    const float* w_kv_up   = (const float*)d_in[6];
    const float* w_out     = (const float*)d_in[7];
    float* out = (float*)d_out;
    char* ws = (char*)d_ws;

    // ---- layout v2: live-at-attention buffers FIRST, then the w_out bf16
    // region; everything pre-attention (W_BUF, partials, intermediates)
    // aliases inside the w_out region (dead by attention start). ----
    const size_t SZ_KV   = (size_t)SEQ * 32768 * 2;           // 67,108,864
    const size_t SZ_QCR  = (size_t)SEQ * (NHEAD * 192) * 2;   // 50,331,648
    const size_t SZ_KR   = (size_t)SEQ * 64 * 2;              // 131,072
    const size_t SZ_OG   = (size_t)SEQ * 16384 * 2;           // 33,554,432
    const size_t SZ_TAB  = (size_t)SEQ * 32 * 4;              // 131,072
    const size_t SZ_WOUT = (size_t)HIDN * 16384 * 2;          // 234,881,024
    const size_t SZ_WB   = (size_t)24576 * 1536 * 2;          // 75,497,472
    const size_t SZ_PART = (size_t)4 * SEQ * QLRANK * 4;      // 25,165,824
    const size_t SZ_HS   = (size_t)SEQ * HIDN * 2;
    const size_t SZ_CQ   = (size_t)SEQ * QLRANK * 4;
    const size_t SZ_CQN  = (size_t)SEQ * QLRANK * 2;
    const size_t SZ_CKV  = (size_t)SEQ * 576 * 4;
    const size_t SZ_CKVN = (size_t)SEQ * KVLRANK * 2;

    size_t off = 0;
    u16* kvb     = (u16*)(ws + off); off += SZ_KV;
    u16* q_cr    = (u16*)(ws + off); off += SZ_QCR;
    u16* kr      = (u16*)(ws + off); off += SZ_KR;
    u16* o_g     = (u16*)(ws + off); off += SZ_OG;
    float* cos_t = (float*)(ws + off); off += SZ_TAB;
    float* sin_t = (float*)(ws + off); off += SZ_TAB;
    const size_t live_end = off;                    // 151,388,160
    u16* wout_bf = (u16*)(ws + live_end);           // [151.4MB, 386.3MB)
    // pre-attention scratch aliases inside the wout region:
    u16* W_BUF   = (u16*)(ws + live_end);
    float* parts = (float*)(ws + live_end + SZ_WB);
    size_t toff = live_end + SZ_WB + SZ_PART;
    u16* hs_bf    = (u16*)(ws + toff); toff += SZ_HS;
    float* c_q    = (float*)(ws + toff); toff += SZ_CQ;
    u16* cq_n     = (u16*)(ws + toff); toff += SZ_CQN;
    float* ckv_kr = (float*)(ws + toff); toff += SZ_CKV;
    u16* ckv_n    = (u16*)(ws + toff); toff += SZ_CKVN;
    const int fuse = (live_end + SZ_WOUT) <= ws_size;   // proven: ws >= 405MB > 386.3MB
    (void)in_sizes; (void)n_in; (void)out_size;

    rope_tables<<<dim3(SEQ), dim3(32), 0, stream>>>(cos_t, sin_t);
    f32_to_bf16<<<2048, 256, 0, stream>>>(hs, hs_bf, (long)SEQ * HIDN);

    // c_q = hs @ w_q_down^T   (split-K x4)
    f32_to_bf16<<<2048, 256, 0, stream>>>(w_q_down, W_BUF, (long)QLRANK * HIDN);
    gemm_bt<0><<<dim3(QLRANK / 128, SEQ / 128, 4), 512, 0, stream>>>(hs_bf, W_BUF, parts, SEQ, QLRANK, HIDN / 4, HIDN);
    reduce_parts<<<1024, 256, 0, stream>>>(parts, c_q, 4, (long)SEQ * QLRANK);
    rmsnorm_kernel<<<SEQ, 256, 0, stream>>>(c_q, q_norm_w, cq_n, QLRANK, QLRANK);

    // q_cr = rmsnorm(c_q) @ w_q_up^T
    f32_to_bf16<<<2048, 256, 0, stream>>>(w_q_up, W_BUF, (long)24576 * QLRANK);
    gemm_bt<1><<<dim3(24576 / 128, SEQ / 128), 512, 0, stream>>>(cq_n, W_BUF, q_cr, SEQ, 24576, QLRANK, QLRANK);

    // ckv_kr = hs @ w_kv_down^T   (split-K x8; N=576 ragged)
    f32_to_bf16<<<2048, 256, 0, stream>>>(w_kv_down, W_BUF, (long)576 * HIDN);
    gemm_bt<0><<<dim3(5, SEQ / 128, 8), 512, 0, stream>>>(hs_bf, W_BUF, parts, SEQ, 576, HIDN / 8, HIDN);
    reduce_parts<<<1024, 256, 0, stream>>>(parts, ckv_kr, 8, (long)SEQ * 576);
    rmsnorm_kernel<<<SEQ, 256, 0, stream>>>(ckv_kr, kv_norm_w, ckv_n, 576, KVLRANK);
    rope_k<<<SEQ, 64, 0, stream>>>(ckv_kr, cos_t, sin_t, kr);

    // kv = rmsnorm(c_kv) @ w_kv_up^T
    f32_to_bf16<<<2048, 256, 0, stream>>>(w_kv_up, W_BUF, (long)32768 * KVLRANK);
    gemm_bt<1><<<dim3(32768 / 128, SEQ / 128), 512, 0, stream>>>(ckv_n, W_BUF, kvb, SEQ, 32768, KVLRANK, KVLRANK);

    rope_q<<<dim3(SEQ, NHEAD / 2), 64, 0, stream>>>(q_cr, cos_t, sin_t);

    // attention (+ fused w_out fp32->bf16 conversion hidden under compute)
    if (!fuse)
        f32_to_bf16<<<4096, 256, 0, stream>>>(w_out, wout_bf, (long)HIDN * 16384);
    mla_attn<<<dim3(SEQ / 128, NHEAD), 512, 0, stream>>>(q_cr, kvb, kr, o_g,
                                                         w_out, wout_bf, fuse ? 1 : 0);

    // out = o @ w_out^T
    gemm_bt<0><<<dim3(HIDN / 128, SEQ / 128), 512, 0, stream>>>(o_g, wout_bf, out, SEQ, HIDN, 16384, 16384);
}

// Round 16
// 968.546 us; speedup vs baseline: 1.1009x; 1.0091x over previous
//
#include <hip/hip_runtime.h>
#include <hip/hip_bf16.h>
#include <math.h>

// ---- problem constants ----
#define HIDN 7168
#define NHEAD 128
#define QLRANK 1536
#define KVLRANK 512
#define QKD 128
#define VHD 128
#define RHD 64
#define SEQ 1024
#define RMS_EPS 1.1920929e-07f

typedef unsigned short u16;
typedef __attribute__((ext_vector_type(8))) short bf16x8;
typedef __attribute__((ext_vector_type(4))) float f32x4;
typedef __attribute__((ext_vector_type(8))) unsigned short u16x8;

__device__ __forceinline__ u16 f2bf(float f) {
    unsigned int u = __float_as_uint(f);
    unsigned int r = (u + 0x7FFFu + ((u >> 16) & 1u)) >> 16;
    return (u16)r;
}
__device__ __forceinline__ float bf2f(u16 v) {
    return __uint_as_float(((unsigned int)v) << 16);
}

// async global->LDS, 16B per lane. LDS dest is wave-uniform base + lane*16.
__device__ __forceinline__ void gld_lds16(const u16* g, u16* l) {
    __builtin_amdgcn_global_load_lds(
        (const __attribute__((address_space(1))) unsigned int*)g,
        (__attribute__((address_space(3))) unsigned int*)l,
        16, 0, 0);
}

// ---------------- fp32 -> bf16 conversion (x8 vectorized) ----------------
__global__ __launch_bounds__(256) void f32_to_bf16(const float* __restrict__ in,
                                                   u16* __restrict__ out, long n) {
    long i = ((long)blockIdx.x * blockDim.x + threadIdx.x) * 8;
    long stride = (long)gridDim.x * blockDim.x * 8;
    for (; i < n; i += stride) {
        float4 a = *(const float4*)(in + i);
        float4 b = *(const float4*)(in + i + 4);
        u16x8 o;
        o[0] = f2bf(a.x); o[1] = f2bf(a.y); o[2] = f2bf(a.z); o[3] = f2bf(a.w);
        o[4] = f2bf(b.x); o[5] = f2bf(b.y); o[6] = f2bf(b.z); o[7] = f2bf(b.w);
        *(u16x8*)(out + i) = o;
    }
}

// ---------------- generic GEMM (r10-proven): C[m][n] = sum_k A[m][k]*B[n][k] ----------------
// 128x128 tile, BK=64, 8 waves (2M x 4N, 64x32 out/wave), LDS 64 KiB dbuf ->
// 2 WG/CU x 8 waves = 4 waves/SIMD TLP; one vmcnt(0)+s_barrier per K-step
// (drain hidden by cross-wave TLP, m114). global_load_lds(16) staging with
// coalesced row-grouped source map + XOR chunk swizzle (0 bank conflicts).
// Natural dispatch order keeps each B-strip on one XCD's L2 (gridDim.x%8==0).
// Split-K via blockIdx.z: fp32 partials at Cv + z*M*N (OUT_BF16=0 only).
template <int OUT_BF16>
__global__ __launch_bounds__(512) void gemm_bt(const u16* __restrict__ A,
                                               const u16* __restrict__ B,
                                               void* __restrict__ Cv,
                                               int M, int N, int Kslice, long ldk) {
    __shared__ u16 As[2 * 128 * 64];   // 2 x 16 KiB
    __shared__ u16 Bs[2 * 128 * 64];
    const int tid = threadIdx.x;
    const int lane = tid & 63;
    const int w = tid >> 6;            // 0..7
    const int wr = w >> 2, wc = w & 3; // wave grid 2M x 4N
    const int l15 = lane & 15, lg = lane >> 4;
    const int n0 = blockIdx.x * 128;
    const int m0 = blockIdx.y * 128;
    const long kbase = (long)blockIdx.z * Kslice;

    // staging: 2 issues per wave per matrix; each issue = 8 rows x 64 cols.
    const u16* asrc[2];
    const u16* bsrc[2];
    int aoff[2];
#pragma unroll
    for (int i = 0; i < 2; ++i) {
        int r = (w * 2 + i) * 8 + (lane >> 3);
        int gc = (lane & 7) ^ (r & 7);
        asrc[i] = A + (long)(m0 + r) * ldk + kbase + gc * 8;
        int br = n0 + r; if (br >= N) br = N - 1;
        bsrc[i] = B + (long)br * ldk + kbase + gc * 8;
        aoff[i] = (w * 2 + i) * 512;
    }

    f32x4 acc[4][2];
    const f32x4 z = {0.f, 0.f, 0.f, 0.f};
#pragma unroll
    for (int i = 0; i < 4; ++i)
#pragma unroll
        for (int j = 0; j < 2; ++j) acc[i][j] = z;

    auto stage = [&](int bufi, int kofs) {
#pragma unroll
        for (int i = 0; i < 2; ++i) {
            gld_lds16(asrc[i] + kofs, As + bufi * 8192 + aoff[i]);
            gld_lds16(bsrc[i] + kofs, Bs + bufi * 8192 + aoff[i]);
        }
    };

    const int nsteps = Kslice >> 6;
    stage(0, 0);
    asm volatile("s_waitcnt vmcnt(0)" ::: "memory");
    __builtin_amdgcn_s_barrier();

    int cur = 0;
    for (int t = 0; t < nsteps; ++t) {
        if (t + 1 < nsteps) stage(cur ^ 1, (t + 1) * 64);
        const u16* Ab = As + cur * 8192;
        const u16* Bb = Bs + cur * 8192;
#pragma unroll
        for (int kk = 0; kk < 2; ++kk) {
            bf16x8 a[4], b[2];
#pragma unroll
            for (int i = 0; i < 4; ++i) {
                int row = wr * 64 + i * 16 + l15;
                a[i] = *(const bf16x8*)&Ab[row * 64 + ((kk * 4 + lg) ^ (row & 7)) * 8];
            }
#pragma unroll
            for (int j = 0; j < 2; ++j) {
                int row = wc * 32 + j * 16 + l15;
                b[j] = *(const bf16x8*)&Bb[row * 64 + ((kk * 4 + lg) ^ (row & 7)) * 8];
            }
#pragma unroll
            for (int i = 0; i < 4; ++i)
#pragma unroll
                for (int j = 0; j < 2; ++j)
                    acc[i][j] = __builtin_amdgcn_mfma_f32_16x16x32_bf16(a[i], b[j], acc[i][j], 0, 0, 0);
        }
        asm volatile("s_waitcnt vmcnt(0)" ::: "memory");
        __builtin_amdgcn_s_barrier();
        cur ^= 1;
    }

#pragma unroll
    for (int i = 0; i < 4; ++i)
#pragma unroll
        for (int j = 0; j < 2; ++j)
#pragma unroll
            for (int r = 0; r < 4; ++r) {
                int m = m0 + wr * 64 + i * 16 + lg * 4 + r;
                int n = n0 + wc * 32 + j * 16 + l15;
                if (n < N) {
                    if (OUT_BF16)
                        ((u16*)Cv)[(long)m * N + n] = f2bf(acc[i][j][r]);
                    else
                        ((float*)Cv)[(long)blockIdx.z * M * N + (long)m * N + n] = acc[i][j][r];
                }
            }
}

// ---------------- sum split-K partials (fp32), x4 vectorized ----------------
__global__ __launch_bounds__(256) void reduce_parts(const float* __restrict__ parts,
                                                    float* __restrict__ out,
                                                    int nparts, long mn) {
    long i = ((long)blockIdx.x * 256 + threadIdx.x) * 4;
    long stride = (long)gridDim.x * 256 * 4;
    for (; i < mn; i += stride) {
        float4 s = *(const float4*)(parts + i);
        for (int p = 1; p < nparts; ++p) {
            float4 v = *(const float4*)(parts + (long)p * mn + i);
            s.x += v.x; s.y += v.y; s.z += v.z; s.w += v.w;
        }
        *(float4*)(out + i) = s;
    }
}

// ---------------- RMSNorm (row-wise): y = x * rsqrt(mean(x^2)+eps) * w ----------------
__global__ __launch_bounds__(256) void rmsnorm_kernel(const float* __restrict__ x,
                                                      const float* __restrict__ w,
                                                      u16* __restrict__ y,
                                                      int stride, int norm_len) {
    const int row = blockIdx.x;
    const float* xr = x + (long)row * stride;
    float ss = 0.f;
    for (int i = threadIdx.x; i < norm_len; i += 256) {
        float v = xr[i];
        ss += v * v;
    }
#pragma unroll
    for (int off = 32; off > 0; off >>= 1) ss += __shfl_down(ss, off);
    __shared__ float partial[4];
    if ((threadIdx.x & 63) == 0) partial[threadIdx.x >> 6] = ss;
    __syncthreads();
    float tot = partial[0] + partial[1] + partial[2] + partial[3];
    float rs = 1.0f / sqrtf(tot / (float)norm_len + RMS_EPS);
    u16* yr = y + (long)row * norm_len;
    for (int i = threadIdx.x; i < norm_len; i += 256) yr[i] = f2bf(xr[i] * rs * w[i]);
}

// ---------------- RoPE tables (fp32): cos/sin[s][i], i<32 ----------------
__global__ void rope_tables(float* __restrict__ cos_t, float* __restrict__ sin_t) {
    int s = blockIdx.x;
    int i = threadIdx.x;  // 32 threads
    float invf = powf(10000.0f, -((float)(2 * i) / 64.0f));
    float ang = (float)s * invf;
    cos_t[s * 32 + i] = cosf(ang);
    sin_t[s * 32 + i] = sinf(ang);
}

// ---------------- RoPE on q_r, in-place on q_cr (bf16) ----------------
__global__ void rope_q(u16* __restrict__ q_cr, const float* __restrict__ cos_t,
                       const float* __restrict__ sin_t) {
    int s = blockIdx.x;
    int h = blockIdx.y * 2 + (threadIdx.x >> 5);
    int i = threadIdx.x & 31;
    u16* base = q_cr + (s * (NHEAD * 192) + h * 192 + QKD);
    float x1 = bf2f(base[i]);
    float x2 = bf2f(base[i + 32]);
    float c = cos_t[s * 32 + i], sn = sin_t[s * 32 + i];
    base[i]      = f2bf(x1 * c - x2 * sn);
    base[i + 32] = f2bf(x2 * c + x1 * sn);
}

// ---------------- RoPE on k_r (from fp32 ckv_kr cols 512..576) -> bf16 kr ----------------
__global__ void rope_k(const float* __restrict__ ckv_kr, const float* __restrict__ cos_t,
                       const float* __restrict__ sin_t, u16* __restrict__ kr) {
    int s = blockIdx.x;
    int i = threadIdx.x;  // 64 threads; first 32 active
    if (i < 32) {
        const float* base = ckv_kr + (s * 576 + 512);
        float x1 = base[i], x2 = base[i + 32];
        float c = cos_t[s * 32 + i], sn = sin_t[s * 32 + i];
        kr[s * 64 + i]      = f2bf(x1 * c - x2 * sn);
        kr[s * 64 + i + 32] = f2bf(x2 * c + x1 * sn);
    }
}

// ---------------- flash attention + fused w_out conversion ----------------
// r15 structure with the transpose bank-conflict FIX: each wave's 64 lanes
// own 64 CONSECUTIVE dv columns (dv = tid&127), so the scalar column-reads
// of vtile hit all 32 banks 2-way-in-word (free, m136); the 8-way conflict
// of r15's mapping (3.46e7 conflicts) is gone. Gather 16 u16 to regs, then
// two ds_write_b128 into vts (inherent throughput).
__global__ __launch_bounds__(512) void mla_attn(const u16* __restrict__ q_cr,
                                                const u16* __restrict__ kv,
                                                const u16* __restrict__ kr,
                                                u16* __restrict__ o_g,
                                                const float* __restrict__ wsrc,
                                                u16* __restrict__ wdst,
                                                int do_conv) {
    __shared__ u16 ks[64][200];        // 64 keys x 192 dims (+pad)
    __shared__ u16 vts[128][72];       // 128 dv x 64 k (+pad)
    __shared__ u16 p_lds[8][16][72];   // per wave: 16 q x 64 k (+pad)
    __shared__ u16 vtile[64][136];     // V rows staging (+pad)
    const int qb = blockIdx.x, h = blockIdx.y;
    const int s0q = qb * 128;
    const int tid = threadIdx.x, lane = tid & 63, w = tid >> 6;
    const int l15 = lane & 15, lg = lane >> 4;
    const float scale = 0.07216878364870323f;  // 1/sqrt(192)

    // Q in registers, A-fragment layout
    bf16x8 qreg[6];
    {
        const int qrow = s0q + w * 16 + l15;
#pragma unroll
        for (int kk = 0; kk < 6; ++kk)
            qreg[kk] = *(const bf16x8*)&q_cr[qrow * (NHEAD * 192) + h * 192 + kk * 32 + lg * 8];
    }

    // staging-index precompute (512 threads: K 2x, kr 1x, V 2x u16x8 each)
    const int krow0 = tid >> 4,           koff0 = (tid & 15) * 8;
    const int krow1 = (512 + tid) >> 4,   koff1 = ((512 + tid) & 15) * 8;
    const int rrow  = tid >> 3,           roff  = (tid & 7) * 8;
    const u16* kvp = kv + h * 256;         // k_c columns
    const u16* kvv = kv + h * 256 + 128;   // V columns

    u16x8 kreg0, kreg1, krreg, vreg0, vreg1;
    auto load_tile = [&](int s0k) {
        kreg0 = *(const u16x8*)&kvp[(long)(s0k + krow0) * 32768 + koff0];
        kreg1 = *(const u16x8*)&kvp[(long)(s0k + krow1) * 32768 + koff1];
        krreg = *(const u16x8*)&kr[(s0k + rrow) * 64 + roff];
        vreg0 = *(const u16x8*)&kvv[(long)(s0k + krow0) * 32768 + koff0];
        vreg1 = *(const u16x8*)&kvv[(long)(s0k + krow1) * 32768 + koff1];
    };

    // fused-conversion indexing: 1024 blocks x 16 tiles x 896 u16x8 groups
    const long cbase = ((long)(h * 8 + qb)) * 16 * 896;

    f32x4 o_acc[8];
    const f32x4 z = {0.f, 0.f, 0.f, 0.f};
#pragma unroll
    for (int d = 0; d < 8; ++d) o_acc[d] = z;
    float m_r[4], l_r[4];
#pragma unroll
    for (int r = 0; r < 4; ++r) { m_r[r] = -1e30f; l_r[r] = 0.f; }

    load_tile(0);

    // transpose ownership: wave w covers dv = (w&1)*64 + lane, sb = (w>>1)*16
    const int tdv = tid & 127;
    const int tsb = (tid >> 7) << 4;

    for (int kt = 0; kt < 16; ++kt) {
        __syncthreads();   // b1: prev tile's readers done
        *(u16x8*)&ks[krow0][koff0]      = kreg0;
        *(u16x8*)&ks[krow1][koff1]      = kreg1;
        *(u16x8*)&ks[rrow][128 + roff]  = krreg;
        *(u16x8*)&vtile[krow0][koff0]   = vreg0;
        *(u16x8*)&vtile[krow1][koff1]   = vreg1;
        __syncthreads();   // b2: tile staged
        if (kt + 1 < 16) load_tile((kt + 1) * 64);   // T14 prefetch

        // fused w_out conversion chunk (hidden under this tile's compute)
        if (do_conv) {
            long g0 = cbase + (long)kt * 896;
#pragma unroll
            for (int ci = 0; ci < 2; ++ci) {
                int gi = ci * 512 + tid;
                if (gi < 896) {
                    long g8 = (g0 + gi) * 8;
                    float4 a = *(const float4*)(wsrc + g8);
                    float4 b = *(const float4*)(wsrc + g8 + 4);
                    u16x8 o;
                    o[0] = f2bf(a.x); o[1] = f2bf(a.y); o[2] = f2bf(a.z); o[3] = f2bf(a.w);
                    o[4] = f2bf(b.x); o[5] = f2bf(b.y); o[6] = f2bf(b.z); o[7] = f2bf(b.w);
                    *(u16x8*)(wdst + g8) = o;
                }
            }
        }

        // transpose vtile -> vts: lane-consecutive dv => conflict-free reads
        {
            u16x8 t0, t1;
#pragma unroll
            for (int i = 0; i < 8; ++i) t0[i] = vtile[tsb + i][tdv];
#pragma unroll
            for (int i = 0; i < 8; ++i) t1[i] = vtile[tsb + 8 + i][tdv];
            *(u16x8*)&vts[tdv][tsb]     = t0;
            *(u16x8*)&vts[tdv][tsb + 8] = t1;
        }

        // QK^T : S-frags (16 q x 64 keys per wave)
        f32x4 sf[4];
#pragma unroll
        for (int j = 0; j < 4; ++j) sf[j] = z;
        __builtin_amdgcn_s_setprio(1);
#pragma unroll
        for (int kk = 0; kk < 6; ++kk) {
            bf16x8 a = qreg[kk];
#pragma unroll
            for (int j = 0; j < 4; ++j) {
                bf16x8 b = *(const bf16x8*)&ks[j * 16 + l15][kk * 32 + lg * 8];
                sf[j] = __builtin_amdgcn_mfma_f32_16x16x32_bf16(a, b, sf[j], 0, 0, 0);
            }
        }
        __builtin_amdgcn_s_setprio(0);

        // online softmax (rows in C-layout: row=lg*4+r, col=j*16+l15)
        float p[4][4];
        float alpha[4];
#pragma unroll
        for (int r = 0; r < 4; ++r) {
            float mx = fmaxf(fmaxf(sf[0][r], sf[1][r]), fmaxf(sf[2][r], sf[3][r]));
#pragma unroll
            for (int off = 1; off < 16; off <<= 1) mx = fmaxf(mx, __shfl_xor(mx, off));
            mx *= scale;
            float mnew = fmaxf(m_r[r], mx);
            alpha[r] = __expf(m_r[r] - mnew);
            float rs = 0.f;
#pragma unroll
            for (int j = 0; j < 4; ++j) {
                float pv = __expf(sf[j][r] * scale - mnew);
                p[j][r] = pv;
                rs += pv;
            }
#pragma unroll
            for (int off = 1; off < 16; off <<= 1) rs += __shfl_xor(rs, off);
            l_r[r] = l_r[r] * alpha[r] + rs;
            m_r[r] = mnew;
        }
#pragma unroll
        for (int d = 0; d < 8; ++d)
#pragma unroll
            for (int r = 0; r < 4; ++r) o_acc[d][r] *= alpha[r];

        // P -> LDS (wave-private)
#pragma unroll
        for (int j = 0; j < 4; ++j)
#pragma unroll
            for (int r = 0; r < 4; ++r)
                p_lds[w][lg * 4 + r][j * 16 + l15] = f2bf(p[j][r]);

        __syncthreads();   // b3: vts transpose complete block-wide

        // PV: O += P @ V
        __builtin_amdgcn_s_setprio(1);
#pragma unroll
        for (int kk2 = 0; kk2 < 2; ++kk2) {
            bf16x8 a = *(const bf16x8*)&p_lds[w][l15][kk2 * 32 + lg * 8];
#pragma unroll
            for (int d = 0; d < 8; ++d) {
                bf16x8 b = *(const bf16x8*)&vts[d * 16 + l15][kk2 * 32 + lg * 8];
                o_acc[d] = __builtin_amdgcn_mfma_f32_16x16x32_bf16(a, b, o_acc[d], 0, 0, 0);
            }
        }
        __builtin_amdgcn_s_setprio(0);
    }

    // epilogue: divide by l, store bf16 o[s][h*128+dv]
#pragma unroll
    for (int d = 0; d < 8; ++d)
#pragma unroll
        for (int r = 0; r < 4; ++r) {
            int srow = s0q + w * 16 + lg * 4 + r;
            float v = o_acc[d][r] / l_r[r];
            o_g[srow * 16384 + h * 128 + d * 16 + l15] = f2bf(v);
        }
}

// ---------------- host launcher ----------------
extern "C" void kernel_launch(void* const* d_in, const int* in_sizes, int n_in,
                              void* d_out, int out_size, void* d_ws, size_t ws_size,
                              hipStream_t stream) {
    const float* hs        = (const float*)d_in[0];
    const float* w_q_down  = (const float*)d_in[1];
    const float* q_norm_w  = (const float*)d_in[2];
    const float* w_q_up    = (const float*)d_in[3];
    const float* w_kv_down = (const float*)d_in[4];
    const float* kv_norm_w = (const float*)d_in[5];
    const float* w_kv_up   = (const float*)d_in[6];
    const float* w_out     = (const float*)d_in[7];
    float* out = (float*)d_out;
    char* ws = (char*)d_ws;

    // ---- layout v2: live-at-attention buffers FIRST, then the w_out bf16
    // region; pre-attention scratch aliases inside the w_out region. ----
    const size_t SZ_KV   = (size_t)SEQ * 32768 * 2;
    const size_t SZ_QCR  = (size_t)SEQ * (NHEAD * 192) * 2;
    const size_t SZ_KR   = (size_t)SEQ * 64 * 2;
    const size_t SZ_OG   = (size_t)SEQ * 16384 * 2;
    const size_t SZ_TAB  = (size_t)SEQ * 32 * 4;
    const size_t SZ_WOUT = (size_t)HIDN * 16384 * 2;
    const size_t SZ_WB   = (size_t)24576 * 1536 * 2;
    const size_t SZ_PART = (size_t)4 * SEQ * QLRANK * 4;
    const size_t SZ_HS   = (size_t)SEQ * HIDN * 2;
    const size_t SZ_CQ   = (size_t)SEQ * QLRANK * 4;
    const size_t SZ_CQN  = (size_t)SEQ * QLRANK * 2;
    const size_t SZ_CKV  = (size_t)SEQ * 576 * 4;
    const size_t SZ_CKVN = (size_t)SEQ * KVLRANK * 2;

    size_t off = 0;
    u16* kvb     = (u16*)(ws + off); off += SZ_KV;
    u16* q_cr    = (u16*)(ws + off); off += SZ_QCR;
    u16* kr      = (u16*)(ws + off); off += SZ_KR;
    u16* o_g     = (u16*)(ws + off); off += SZ_OG;
    float* cos_t = (float*)(ws + off); off += SZ_TAB;
    float* sin_t = (float*)(ws + off); off += SZ_TAB;
    const size_t live_end = off;                    // ~151.4MB
    u16* wout_bf = (u16*)(ws + live_end);           // [151.4MB, 386.3MB)
    u16* W_BUF   = (u16*)(ws + live_end);
    float* parts = (float*)(ws + live_end + SZ_WB);
    size_t toff = live_end + SZ_WB + SZ_PART;
    u16* hs_bf    = (u16*)(ws + toff); toff += SZ_HS;
    float* c_q    = (float*)(ws + toff); toff += SZ_CQ;
    u16* cq_n     = (u16*)(ws + toff); toff += SZ_CQN;
    float* ckv_kr = (float*)(ws + toff); toff += SZ_CKV;
    u16* ckv_n    = (u16*)(ws + toff); toff += SZ_CKVN;
    const int fuse = (live_end + SZ_WOUT) <= ws_size;
    (void)in_sizes; (void)n_in; (void)out_size;

    rope_tables<<<dim3(SEQ), dim3(32), 0, stream>>>(cos_t, sin_t);
    f32_to_bf16<<<2048, 256, 0, stream>>>(hs, hs_bf, (long)SEQ * HIDN);

    // c_q = hs @ w_q_down^T   (split-K x4)
    f32_to_bf16<<<2048, 256, 0, stream>>>(w_q_down, W_BUF, (long)QLRANK * HIDN);
    gemm_bt<0><<<dim3(QLRANK / 128, SEQ / 128, 4), 512, 0, stream>>>(hs_bf, W_BUF, parts, SEQ, QLRANK, HIDN / 4, HIDN);
    reduce_parts<<<1024, 256, 0, stream>>>(parts, c_q, 4, (long)SEQ * QLRANK);
    rmsnorm_kernel<<<SEQ, 256, 0, stream>>>(c_q, q_norm_w, cq_n, QLRANK, QLRANK);

    // q_cr = rmsnorm(c_q) @ w_q_up^T
    f32_to_bf16<<<2048, 256, 0, stream>>>(w_q_up, W_BUF, (long)24576 * QLRANK);
    gemm_bt<1><<<dim3(24576 / 128, SEQ / 128), 512, 0, stream>>>(cq_n, W_BUF, q_cr, SEQ, 24576, QLRANK, QLRANK);

    // ckv_kr = hs @ w_kv_down^T   (split-K x8; N=576 ragged)
    f32_to_bf16<<<2048, 256, 0, stream>>>(w_kv_down, W_BUF, (long)576 * HIDN);
    gemm_bt<0><<<dim3(5, SEQ / 128, 8), 512, 0, stream>>>(hs_bf, W_BUF, parts, SEQ, 576, HIDN / 8, HIDN);
    reduce_parts<<<1024, 256, 0, stream>>>(parts, ckv_kr, 8, (long)SEQ * 576);
    rmsnorm_kernel<<<SEQ, 256, 0, stream>>>(ckv_kr, kv_norm_w, ckv_n, 576, KVLRANK);
    rope_k<<<SEQ, 64, 0, stream>>>(ckv_kr, cos_t, sin_t, kr);

    // kv = rmsnorm(c_kv) @ w_kv_up^T
    f32_to_bf16<<<2048, 256, 0, stream>>>(w_kv_up, W_BUF, (long)32768 * KVLRANK);
    gemm_bt<1><<<dim3(32768 / 128, SEQ / 128), 512, 0, stream>>>(ckv_n, W_BUF, kvb, SEQ, 32768, KVLRANK, KVLRANK);

    rope_q<<<dim3(SEQ, NHEAD / 2), 64, 0, stream>>>(q_cr, cos_t, sin_t);

    // attention (+ fused w_out fp32->bf16 conversion hidden under compute)
    if (!fuse)
        f32_to_bf16<<<4096, 256, 0, stream>>>(w_out, wout_bf, (long)HIDN * 16384);
    mla_attn<<<dim3(SEQ / 128, NHEAD), 512, 0, stream>>>(q_cr, kvb, kr, o_g,
                                                         w_out, wout_bf, fuse ? 1 : 0);

    // out = o @ w_out^T
    gemm_bt<0><<<dim3(HIDN / 128, SEQ / 128), 512, 0, stream>>>(o_g, wout_bf, out, SEQ, HIDN, 16384, 16384);
}

// Round 17
// 955.405 us; speedup vs baseline: 1.1161x; 1.0138x over previous
//
#include <hip/hip_runtime.h>
#include <hip/hip_bf16.h>
#include <math.h>

// ---- problem constants ----
#define HIDN 7168
#define NHEAD 128
#define QLRANK 1536
#define KVLRANK 512
#define QKD 128
#define VHD 128
#define RHD 64
#define SEQ 1024
#define RMS_EPS 1.1920929e-07f

typedef unsigned short u16;
typedef __attribute__((ext_vector_type(8))) short bf16x8;
typedef __attribute__((ext_vector_type(4))) float f32x4;
typedef __attribute__((ext_vector_type(4))) unsigned short u16x4;
typedef __attribute__((ext_vector_type(8))) unsigned short u16x8;

__device__ __forceinline__ u16 f2bf(float f) {
    unsigned int u = __float_as_uint(f);
    unsigned int r = (u + 0x7FFFu + ((u >> 16) & 1u)) >> 16;
    return (u16)r;
}
__device__ __forceinline__ float bf2f(u16 v) {
    return __uint_as_float(((unsigned int)v) << 16);
}

// async global->LDS, 16B per lane. LDS dest is wave-uniform base + lane*16.
__device__ __forceinline__ void gld_lds16(const u16* g, u16* l) {
    __builtin_amdgcn_global_load_lds(
        (const __attribute__((address_space(1))) unsigned int*)g,
        (__attribute__((address_space(3))) unsigned int*)l,
        16, 0, 0);
}

// ---------------- fp32 -> bf16 conversion (x8 vectorized) ----------------
__global__ __launch_bounds__(256) void f32_to_bf16(const float* __restrict__ in,
                                                   u16* __restrict__ out, long n) {
    long i = ((long)blockIdx.x * blockDim.x + threadIdx.x) * 8;
    long stride = (long)gridDim.x * blockDim.x * 8;
    for (; i < n; i += stride) {
        float4 a = *(const float4*)(in + i);
        float4 b = *(const float4*)(in + i + 4);
        u16x8 o;
        o[0] = f2bf(a.x); o[1] = f2bf(a.y); o[2] = f2bf(a.z); o[3] = f2bf(a.w);
        o[4] = f2bf(b.x); o[5] = f2bf(b.y); o[6] = f2bf(b.z); o[7] = f2bf(b.w);
        *(u16x8*)(out + i) = o;
    }
}

// ---------------- generic GEMM (r10-proven): C[m][n] = sum_k A[m][k]*B[n][k] ----------------
// 128x128 tile, BK=64, 8 waves (2M x 4N, 64x32 out/wave), LDS 64 KiB dbuf ->
// 2 WG/CU x 8 waves = 4 waves/SIMD TLP; one vmcnt(0)+s_barrier per K-step.
// global_load_lds(16) staging, coalesced row-grouped source + XOR chunk swizzle.
// Split-K via blockIdx.z: fp32 partials at Cv + z*M*N (OUT_BF16=0 only).
template <int OUT_BF16>
__global__ __launch_bounds__(512) void gemm_bt(const u16* __restrict__ A,
                                               const u16* __restrict__ B,
                                               void* __restrict__ Cv,
                                               int M, int N, int Kslice, long ldk) {
    __shared__ u16 As[2 * 128 * 64];
    __shared__ u16 Bs[2 * 128 * 64];
    const int tid = threadIdx.x;
    const int lane = tid & 63;
    const int w = tid >> 6;
    const int wr = w >> 2, wc = w & 3;
    const int l15 = lane & 15, lg = lane >> 4;
    const int n0 = blockIdx.x * 128;
    const int m0 = blockIdx.y * 128;
    const long kbase = (long)blockIdx.z * Kslice;

    const u16* asrc[2];
    const u16* bsrc[2];
    int aoff[2];
#pragma unroll
    for (int i = 0; i < 2; ++i) {
        int r = (w * 2 + i) * 8 + (lane >> 3);
        int gc = (lane & 7) ^ (r & 7);
        asrc[i] = A + (long)(m0 + r) * ldk + kbase + gc * 8;
        int br = n0 + r; if (br >= N) br = N - 1;
        bsrc[i] = B + (long)br * ldk + kbase + gc * 8;
        aoff[i] = (w * 2 + i) * 512;
    }

    f32x4 acc[4][2];
    const f32x4 z = {0.f, 0.f, 0.f, 0.f};
#pragma unroll
    for (int i = 0; i < 4; ++i)
#pragma unroll
        for (int j = 0; j < 2; ++j) acc[i][j] = z;

    auto stage = [&](int bufi, int kofs) {
#pragma unroll
        for (int i = 0; i < 2; ++i) {
            gld_lds16(asrc[i] + kofs, As + bufi * 8192 + aoff[i]);
            gld_lds16(bsrc[i] + kofs, Bs + bufi * 8192 + aoff[i]);
        }
    };

    const int nsteps = Kslice >> 6;
    stage(0, 0);
    asm volatile("s_waitcnt vmcnt(0)" ::: "memory");
    __builtin_amdgcn_s_barrier();

    int cur = 0;
    for (int t = 0; t < nsteps; ++t) {
        if (t + 1 < nsteps) stage(cur ^ 1, (t + 1) * 64);
        const u16* Ab = As + cur * 8192;
        const u16* Bb = Bs + cur * 8192;
#pragma unroll
        for (int kk = 0; kk < 2; ++kk) {
            bf16x8 a[4], b[2];
#pragma unroll
            for (int i = 0; i < 4; ++i) {
                int row = wr * 64 + i * 16 + l15;
                a[i] = *(const bf16x8*)&Ab[row * 64 + ((kk * 4 + lg) ^ (row & 7)) * 8];
            }
#pragma unroll
            for (int j = 0; j < 2; ++j) {
                int row = wc * 32 + j * 16 + l15;
                b[j] = *(const bf16x8*)&Bb[row * 64 + ((kk * 4 + lg) ^ (row & 7)) * 8];
            }
#pragma unroll
            for (int i = 0; i < 4; ++i)
#pragma unroll
                for (int j = 0; j < 2; ++j)
                    acc[i][j] = __builtin_amdgcn_mfma_f32_16x16x32_bf16(a[i], b[j], acc[i][j], 0, 0, 0);
        }
        asm volatile("s_waitcnt vmcnt(0)" ::: "memory");
        __builtin_amdgcn_s_barrier();
        cur ^= 1;
    }

#pragma unroll
    for (int i = 0; i < 4; ++i)
#pragma unroll
        for (int j = 0; j < 2; ++j)
#pragma unroll
            for (int r = 0; r < 4; ++r) {
                int m = m0 + wr * 64 + i * 16 + lg * 4 + r;
                int n = n0 + wc * 32 + j * 16 + l15;
                if (n < N) {
                    if (OUT_BF16)
                        ((u16*)Cv)[(long)m * N + n] = f2bf(acc[i][j][r]);
                    else
                        ((float*)Cv)[(long)blockIdx.z * M * N + (long)m * N + n] = acc[i][j][r];
                }
            }
}

// ---------------- GEMM with fused fp32->bf16 on B (r12-proven) ----------------
// Fallback out-proj when wout_bf doesn't fit in ws: B fp32 read directly,
// converted in-registers, ds_write into the swizzled layout. Same schedule.
__global__ __launch_bounds__(512) void gemm_bt_f32b(const u16* __restrict__ A,
                                                    const float* __restrict__ B,
                                                    float* __restrict__ Cv,
                                                    int M, int N, int K, long ldk) {
    __shared__ u16 As[2 * 128 * 64];
    __shared__ u16 Bs[2 * 128 * 64];
    const int tid = threadIdx.x;
    const int lane = tid & 63;
    const int w = tid >> 6;
    const int wr = w >> 2, wc = w & 3;
    const int l15 = lane & 15, lg = lane >> 4;
    const int n0 = blockIdx.x * 128;
    const int m0 = blockIdx.y * 128;

    const u16* asrc[2];
    int aoff[2];
#pragma unroll
    for (int i = 0; i < 2; ++i) {
        int r = (w * 2 + i) * 8 + (lane >> 3);
        int gc = (lane & 7) ^ (r & 7);
        asrc[i] = A + (long)(m0 + r) * ldk + gc * 8;
        aoff[i] = (w * 2 + i) * 512;
    }

    const float* bsrcf[4];
    int bdst[4];
#pragma unroll
    for (int i = 0; i < 4; ++i) {
        int c = i * 64 + lane;
        int rl = c >> 4, ch = c & 15;
        int lrow = w * 16 + rl;
        int gr = n0 + lrow; if (gr >= N) gr = N - 1;
        bsrcf[i] = B + (long)gr * ldk + ch * 4;
        bdst[i] = lrow * 64 + (((ch >> 1) ^ (lrow & 7)) * 8) + (ch & 1) * 4;
    }

    f32x4 acc[4][2];
    const f32x4 z = {0.f, 0.f, 0.f, 0.f};
#pragma unroll
    for (int i = 0; i < 4; ++i)
#pragma unroll
        for (int j = 0; j < 2; ++j) acc[i][j] = z;

    float4 bv[4];
    auto stageA = [&](int bufi, int kofs) {
#pragma unroll
        for (int i = 0; i < 2; ++i)
            gld_lds16(asrc[i] + kofs, As + bufi * 8192 + aoff[i]);
    };
    auto loadB = [&](int kofs) {
#pragma unroll
        for (int i = 0; i < 4; ++i) bv[i] = *(const float4*)(bsrcf[i] + kofs);
    };
    auto writeB = [&](int bufi) {
#pragma unroll
        for (int i = 0; i < 4; ++i) {
            u16x4 o;
            o[0] = f2bf(bv[i].x); o[1] = f2bf(bv[i].y);
            o[2] = f2bf(bv[i].z); o[3] = f2bf(bv[i].w);
            *(u16x4*)&Bs[bufi * 8192 + bdst[i]] = o;
        }
    };

    const int nsteps = K >> 6;
    stageA(0, 0);
    loadB(0);
    asm volatile("s_waitcnt vmcnt(0)" ::: "memory");
    writeB(0);
    asm volatile("s_waitcnt lgkmcnt(0)" ::: "memory");
    __builtin_amdgcn_s_barrier();

    int cur = 0;
    for (int t = 0; t < nsteps; ++t) {
        if (t + 1 < nsteps) {
            stageA(cur ^ 1, (t + 1) * 64);
            loadB((t + 1) * 64);
        }
        const u16* Ab = As + cur * 8192;
        const u16* Bb = Bs + cur * 8192;
#pragma unroll
        for (int kk = 0; kk < 2; ++kk) {
            bf16x8 a[4], b[2];
#pragma unroll
            for (int i = 0; i < 4; ++i) {
                int row = wr * 64 + i * 16 + l15;
                a[i] = *(const bf16x8*)&Ab[row * 64 + ((kk * 4 + lg) ^ (row & 7)) * 8];
            }
#pragma unroll
            for (int j = 0; j < 2; ++j) {
                int row = wc * 32 + j * 16 + l15;
                b[j] = *(const bf16x8*)&Bb[row * 64 + ((kk * 4 + lg) ^ (row & 7)) * 8];
            }
#pragma unroll
            for (int i = 0; i < 4; ++i)
#pragma unroll
                for (int j = 0; j < 2; ++j)
                    acc[i][j] = __builtin_amdgcn_mfma_f32_16x16x32_bf16(a[i], b[j], acc[i][j], 0, 0, 0);
        }
        asm volatile("s_waitcnt vmcnt(0)" ::: "memory");
        if (t + 1 < nsteps) writeB(cur ^ 1);
        asm volatile("s_waitcnt lgkmcnt(0)" ::: "memory");
        __builtin_amdgcn_s_barrier();
        cur ^= 1;
    }

#pragma unroll
    for (int i = 0; i < 4; ++i)
#pragma unroll
        for (int j = 0; j < 2; ++j)
#pragma unroll
            for (int r = 0; r < 4; ++r) {
                int m = m0 + wr * 64 + i * 16 + lg * 4 + r;
                int n = n0 + wc * 32 + j * 16 + l15;
                if (n < N) Cv[(long)m * N + n] = acc[i][j][r];
            }
}

// ---------------- sum split-K partials (fp32), x4 vectorized ----------------
__global__ __launch_bounds__(256) void reduce_parts(const float* __restrict__ parts,
                                                    float* __restrict__ out,
                                                    int nparts, long mn) {
    long i = ((long)blockIdx.x * 256 + threadIdx.x) * 4;
    long stride = (long)gridDim.x * 256 * 4;
    for (; i < mn; i += stride) {
        float4 s = *(const float4*)(parts + i);
        for (int p = 1; p < nparts; ++p) {
            float4 v = *(const float4*)(parts + (long)p * mn + i);
            s.x += v.x; s.y += v.y; s.z += v.z; s.w += v.w;
        }
        *(float4*)(out + i) = s;
    }
}

// ---------------- RMSNorm ----------------
__global__ __launch_bounds__(256) void rmsnorm_kernel(const float* __restrict__ x,
                                                      const float* __restrict__ w,
                                                      u16* __restrict__ y,
                                                      int stride, int norm_len) {
    const int row = blockIdx.x;
    const float* xr = x + (long)row * stride;
    float ss = 0.f;
    for (int i = threadIdx.x; i < norm_len; i += 256) {
        float v = xr[i];
        ss += v * v;
    }
#pragma unroll
    for (int off = 32; off > 0; off >>= 1) ss += __shfl_down(ss, off);
    __shared__ float partial[4];
    if ((threadIdx.x & 63) == 0) partial[threadIdx.x >> 6] = ss;
    __syncthreads();
    float tot = partial[0] + partial[1] + partial[2] + partial[3];
    float rs = 1.0f / sqrtf(tot / (float)norm_len + RMS_EPS);
    u16* yr = y + (long)row * norm_len;
    for (int i = threadIdx.x; i < norm_len; i += 256) yr[i] = f2bf(xr[i] * rs * w[i]);
}

// ---------------- RoPE tables ----------------
__global__ void rope_tables(float* __restrict__ cos_t, float* __restrict__ sin_t) {
    int s = blockIdx.x;
    int i = threadIdx.x;
    float invf = powf(10000.0f, -((float)(2 * i) / 64.0f));
    float ang = (float)s * invf;
    cos_t[s * 32 + i] = cosf(ang);
    sin_t[s * 32 + i] = sinf(ang);
}

// ---------------- RoPE on q_r ----------------
__global__ void rope_q(u16* __restrict__ q_cr, const float* __restrict__ cos_t,
                       const float* __restrict__ sin_t) {
    int s = blockIdx.x;
    int h = blockIdx.y * 2 + (threadIdx.x >> 5);
    int i = threadIdx.x & 31;
    u16* base = q_cr + (s * (NHEAD * 192) + h * 192 + QKD);
    float x1 = bf2f(base[i]);
    float x2 = bf2f(base[i + 32]);
    float c = cos_t[s * 32 + i], sn = sin_t[s * 32 + i];
    base[i]      = f2bf(x1 * c - x2 * sn);
    base[i + 32] = f2bf(x2 * c + x1 * sn);
}

// ---------------- RoPE on k_r ----------------
__global__ void rope_k(const float* __restrict__ ckv_kr, const float* __restrict__ cos_t,
                       const float* __restrict__ sin_t, u16* __restrict__ kr) {
    int s = blockIdx.x;
    int i = threadIdx.x;
    if (i < 32) {
        const float* base = ckv_kr + (s * 576 + 512);
        float x1 = base[i], x2 = base[i + 32];
        float c = cos_t[s * 32 + i], sn = sin_t[s * 32 + i];
        kr[s * 64 + i]      = f2bf(x1 * c - x2 * sn);
        kr[s * 64 + i + 32] = f2bf(x2 * c + x1 * sn);
    }
}

// ---------------- build vT[h][dv][s] from kv[s][h*256+128+dv] ----------------
__global__ __launch_bounds__(256) void build_vt(const u16* __restrict__ kv,
                                                u16* __restrict__ vT) {
    __shared__ u16 vtile[64][136];
    const int h = blockIdx.x, sb = blockIdx.y, s0 = sb * 64;
    const int tid = threadIdx.x;
#pragma unroll
    for (int it = 0; it < 4; ++it) {
        int c = it * 256 + tid;
        int row = c >> 4;
        int off8 = (c & 15) * 8;
        *(u16x8*)&vtile[row][off8] =
            *(const u16x8*)&kv[(s0 + row) * 32768 + h * 256 + 128 + off8];
    }
    __syncthreads();
    const int sl = tid & 63;
    const int dvb = tid >> 6;
#pragma unroll
    for (int it = 0; it < 32; ++it) {
        int dv = dvb + it * 4;
        vT[(h * 128 + dv) * 1024 + s0 + sl] = vtile[sl][dv];
    }
}

// ---------------- flash attention (r10 form) + optional fused w_out conversion ----------------
// 1 block = 128 queries x 1 head, 8 waves; K/V/kr staged via T14 reg prefetch;
// V from precomputed vT (global transpose, coalesced). 62.4KB LDS, 2 WG/CU.
// do_conv: each block converts its 229KB share of w_out fp32->bf16 spread
// over 16 tiles — hidden under the compute phases (idle-BW fusion).
__global__ __launch_bounds__(512) void mla_attn(const u16* __restrict__ q_cr,
                                                const u16* __restrict__ kv,
                                                const u16* __restrict__ kr,
                                                const u16* __restrict__ vT,
                                                u16* __restrict__ o_g,
                                                const float* __restrict__ wsrc,
                                                u16* __restrict__ wdst,
                                                int do_conv) {
    __shared__ u16 ks[64][200];
    __shared__ u16 vts[128][72];
    __shared__ u16 p_lds[8][16][72];
    const int qb = blockIdx.x, h = blockIdx.y;
    const int s0q = qb * 128;
    const int tid = threadIdx.x, lane = tid & 63, w = tid >> 6;
    const int l15 = lane & 15, lg = lane >> 4;
    const float scale = 0.07216878364870323f;

    bf16x8 qreg[6];
    {
        const int qrow = s0q + w * 16 + l15;
#pragma unroll
        for (int kk = 0; kk < 6; ++kk)
            qreg[kk] = *(const bf16x8*)&q_cr[qrow * (NHEAD * 192) + h * 192 + kk * 32 + lg * 8];
    }

    const int krow0 = tid >> 4,           koff0 = (tid & 15) * 8;
    const int krow1 = (512 + tid) >> 4,   koff1 = ((512 + tid) & 15) * 8;
    const int rrow  = tid >> 3,           roff  = (tid & 7) * 8;
    const int vdv0  = tid >> 3,           voff0 = (tid & 7) * 8;
    const int vdv1  = (512 + tid) >> 3,   voff1 = ((512 + tid) & 7) * 8;
    const u16* kvp = kv + h * 256;
    const u16* vtp = vT + (long)(h * 128) * 1024;

    u16x8 kreg0, kreg1, krreg, vreg0, vreg1;
    auto load_tile = [&](int s0k) {
        kreg0 = *(const u16x8*)&kvp[(long)(s0k + krow0) * 32768 + koff0];
        kreg1 = *(const u16x8*)&kvp[(long)(s0k + krow1) * 32768 + koff1];
        krreg = *(const u16x8*)&kr[(s0k + rrow) * 64 + roff];
        vreg0 = *(const u16x8*)&vtp[(long)vdv0 * 1024 + s0k + voff0];
        vreg1 = *(const u16x8*)&vtp[(long)vdv1 * 1024 + s0k + voff1];
    };

    const long cbase = ((long)(h * 8 + qb)) * 16 * 896;

    f32x4 o_acc[8];
    const f32x4 z = {0.f, 0.f, 0.f, 0.f};
#pragma unroll
    for (int d = 0; d < 8; ++d) o_acc[d] = z;
    float m_r[4], l_r[4];
#pragma unroll
    for (int r = 0; r < 4; ++r) { m_r[r] = -1e30f; l_r[r] = 0.f; }

    load_tile(0);

    for (int kt = 0; kt < 16; ++kt) {
        __syncthreads();
        *(u16x8*)&ks[krow0][koff0]      = kreg0;
        *(u16x8*)&ks[krow1][koff1]      = kreg1;
        *(u16x8*)&ks[rrow][128 + roff]  = krreg;
        *(u16x8*)&vts[vdv0][voff0]      = vreg0;
        *(u16x8*)&vts[vdv1][voff1]      = vreg1;
        __syncthreads();
        if (kt + 1 < 16) load_tile((kt + 1) * 64);

        // fused w_out conversion chunk (hidden under compute)
        if (do_conv) {
            long g0 = cbase + (long)kt * 896;
#pragma unroll
            for (int ci = 0; ci < 2; ++ci) {
                int gi = ci * 512 + tid;
                if (gi < 896) {
                    long g8 = (g0 + gi) * 8;
                    float4 a = *(const float4*)(wsrc + g8);
                    float4 b = *(const float4*)(wsrc + g8 + 4);
                    u16x8 o;
                    o[0] = f2bf(a.x); o[1] = f2bf(a.y); o[2] = f2bf(a.z); o[3] = f2bf(a.w);
                    o[4] = f2bf(b.x); o[5] = f2bf(b.y); o[6] = f2bf(b.z); o[7] = f2bf(b.w);
                    *(u16x8*)(wdst + g8) = o;
                }
            }
        }

        // QK^T
        f32x4 sf[4];
#pragma unroll
        for (int j = 0; j < 4; ++j) sf[j] = z;
        __builtin_amdgcn_s_setprio(1);
#pragma unroll
        for (int kk = 0; kk < 6; ++kk) {
            bf16x8 a = qreg[kk];
#pragma unroll
            for (int j = 0; j < 4; ++j) {
                bf16x8 b = *(const bf16x8*)&ks[j * 16 + l15][kk * 32 + lg * 8];
                sf[j] = __builtin_amdgcn_mfma_f32_16x16x32_bf16(a, b, sf[j], 0, 0, 0);
            }
        }
        __builtin_amdgcn_s_setprio(0);

        // online softmax
        float p[4][4];
        float alpha[4];
#pragma unroll
        for (int r = 0; r < 4; ++r) {
            float mx = fmaxf(fmaxf(sf[0][r], sf[1][r]), fmaxf(sf[2][r], sf[3][r]));
#pragma unroll
            for (int off = 1; off < 16; off <<= 1) mx = fmaxf(mx, __shfl_xor(mx, off));
            mx *= scale;
            float mnew = fmaxf(m_r[r], mx);
            alpha[r] = __expf(m_r[r] - mnew);
            float rs = 0.f;
#pragma unroll
            for (int j = 0; j < 4; ++j) {
                float pv = __expf(sf[j][r] * scale - mnew);
                p[j][r] = pv;
                rs += pv;
            }
#pragma unroll
            for (int off = 1; off < 16; off <<= 1) rs += __shfl_xor(rs, off);
            l_r[r] = l_r[r] * alpha[r] + rs;
            m_r[r] = mnew;
        }
#pragma unroll
        for (int d = 0; d < 8; ++d)
#pragma unroll
            for (int r = 0; r < 4; ++r) o_acc[d][r] *= alpha[r];

        // P -> LDS (wave-private)
#pragma unroll
        for (int j = 0; j < 4; ++j)
#pragma unroll
            for (int r = 0; r < 4; ++r)
                p_lds[w][lg * 4 + r][j * 16 + l15] = f2bf(p[j][r]);

        // PV
        __builtin_amdgcn_s_setprio(1);
#pragma unroll
        for (int kk2 = 0; kk2 < 2; ++kk2) {
            bf16x8 a = *(const bf16x8*)&p_lds[w][l15][kk2 * 32 + lg * 8];
#pragma unroll
            for (int d = 0; d < 8; ++d) {
                bf16x8 b = *(const bf16x8*)&vts[d * 16 + l15][kk2 * 32 + lg * 8];
                o_acc[d] = __builtin_amdgcn_mfma_f32_16x16x32_bf16(a, b, o_acc[d], 0, 0, 0);
            }
        }
        __builtin_amdgcn_s_setprio(0);
    }

#pragma unroll
    for (int d = 0; d < 8; ++d)
#pragma unroll
        for (int r = 0; r < 4; ++r) {
            int srow = s0q + w * 16 + lg * 4 + r;
            float v = o_acc[d][r] / l_r[r];
            o_g[srow * 16384 + h * 128 + d * 16 + l15] = f2bf(v);
        }
}

// ---------------- host launcher ----------------
extern "C" void kernel_launch(void* const* d_in, const int* in_sizes, int n_in,
                              void* d_out, int out_size, void* d_ws, size_t ws_size,
                              hipStream_t stream) {
    const float* hs        = (const float*)d_in[0];
    const float* w_q_down  = (const float*)d_in[1];
    const float* q_norm_w  = (const float*)d_in[2];
    const float* w_q_up    = (const float*)d_in[3];
    const float* w_kv_down = (const float*)d_in[4];
    const float* kv_norm_w = (const float*)d_in[5];
    const float* w_kv_up   = (const float*)d_in[6];
    const float* w_out     = (const float*)d_in[7];
    float* out = (float*)d_out;
    char* ws = (char*)d_ws;

    // ---- layout v3: live-at-attention set FIRST (incl. vT), wout after ----
    const size_t SZ_KV   = (size_t)SEQ * 32768 * 2;
    const size_t SZ_QCR  = (size_t)SEQ * (NHEAD * 192) * 2;
    const size_t SZ_KR   = (size_t)SEQ * 64 * 2;
    const size_t SZ_TAB  = (size_t)SEQ * 32 * 4;
    const size_t SZ_VT   = (size_t)NHEAD * 128 * 1024 * 2;
    const size_t SZ_OG   = (size_t)SEQ * 16384 * 2;
    const size_t SZ_WOUT = (size_t)HIDN * 16384 * 2;
    const size_t SZ_WB   = (size_t)24576 * 1536 * 2;
    const size_t SZ_PART = (size_t)4 * SEQ * QLRANK * 4;
    const size_t SZ_HS   = (size_t)SEQ * HIDN * 2;
    const size_t SZ_CQ   = (size_t)SEQ * QLRANK * 4;
    const size_t SZ_CQN  = (size_t)SEQ * QLRANK * 2;
    const size_t SZ_CKV  = (size_t)SEQ * 576 * 4;
    const size_t SZ_CKVN = (size_t)SEQ * KVLRANK * 2;

    size_t off = 0;
    u16* kvb     = (u16*)(ws + off); off += SZ_KV;
    u16* q_cr    = (u16*)(ws + off); off += SZ_QCR;
    u16* kr      = (u16*)(ws + off); off += SZ_KR;
    float* cos_t = (float*)(ws + off); off += SZ_TAB;
    float* sin_t = (float*)(ws + off); off += SZ_TAB;
    u16* vT      = (u16*)(ws + off); off += SZ_VT;
    u16* o_g     = (u16*)(ws + off); off += SZ_OG;
    const size_t live_end = off;                     // ~184.9MB
    u16* wout_bf = (u16*)(ws + live_end);            // [184.9MB, 419.8MB) if it fits
    // pre-attention scratch aliases the region after live_end (dead by attn)
    u16* W_BUF   = (u16*)(ws + live_end);
    float* parts = (float*)(ws + live_end + SZ_WB);
    size_t toff = live_end + SZ_WB + SZ_PART;
    u16* hs_bf    = (u16*)(ws + toff); toff += SZ_HS;
    float* c_q    = (float*)(ws + toff); toff += SZ_CQ;
    u16* cq_n     = (u16*)(ws + toff); toff += SZ_CQN;
    float* ckv_kr = (float*)(ws + toff); toff += SZ_CKV;
    u16* ckv_n    = (u16*)(ws + toff); toff += SZ_CKVN;
    const int fuse = (live_end + SZ_WOUT) <= ws_size;
    (void)in_sizes; (void)n_in; (void)out_size;

    rope_tables<<<dim3(SEQ), dim3(32), 0, stream>>>(cos_t, sin_t);
    f32_to_bf16<<<2048, 256, 0, stream>>>(hs, hs_bf, (long)SEQ * HIDN);

    // c_q = hs @ w_q_down^T   (split-K x4)
    f32_to_bf16<<<2048, 256, 0, stream>>>(w_q_down, W_BUF, (long)QLRANK * HIDN);
    gemm_bt<0><<<dim3(QLRANK / 128, SEQ / 128, 4), 512, 0, stream>>>(hs_bf, W_BUF, parts, SEQ, QLRANK, HIDN / 4, HIDN);
    reduce_parts<<<1024, 256, 0, stream>>>(parts, c_q, 4, (long)SEQ * QLRANK);
    rmsnorm_kernel<<<SEQ, 256, 0, stream>>>(c_q, q_norm_w, cq_n, QLRANK, QLRANK);

    // q_cr = rmsnorm(c_q) @ w_q_up^T
    f32_to_bf16<<<2048, 256, 0, stream>>>(w_q_up, W_BUF, (long)24576 * QLRANK);
    gemm_bt<1><<<dim3(24576 / 128, SEQ / 128), 512, 0, stream>>>(cq_n, W_BUF, q_cr, SEQ, 24576, QLRANK, QLRANK);

    // ckv_kr = hs @ w_kv_down^T   (split-K x8; N=576 ragged)
    f32_to_bf16<<<2048, 256, 0, stream>>>(w_kv_down, W_BUF, (long)576 * HIDN);
    gemm_bt<0><<<dim3(5, SEQ / 128, 8), 512, 0, stream>>>(hs_bf, W_BUF, parts, SEQ, 576, HIDN / 8, HIDN);
    reduce_parts<<<1024, 256, 0, stream>>>(parts, ckv_kr, 8, (long)SEQ * 576);
    rmsnorm_kernel<<<SEQ, 256, 0, stream>>>(ckv_kr, kv_norm_w, ckv_n, 576, KVLRANK);
    rope_k<<<SEQ, 64, 0, stream>>>(ckv_kr, cos_t, sin_t, kr);

    // kv = rmsnorm(c_kv) @ w_kv_up^T
    f32_to_bf16<<<2048, 256, 0, stream>>>(w_kv_up, W_BUF, (long)32768 * KVLRANK);
    gemm_bt<1><<<dim3(32768 / 128, SEQ / 128), 512, 0, stream>>>(ckv_n, W_BUF, kvb, SEQ, 32768, KVLRANK, KVLRANK);

    rope_q<<<dim3(SEQ, NHEAD / 2), 64, 0, stream>>>(q_cr, cos_t, sin_t);
    build_vt<<<dim3(NHEAD, SEQ / 64), 256, 0, stream>>>(kvb, vT);

    // attention; if wout fits, convert w_out under attention's idle BW
    mla_attn<<<dim3(SEQ / 128, NHEAD), 512, 0, stream>>>(q_cr, kvb, kr, vT, o_g,
                                                         w_out, wout_bf, fuse ? 1 : 0);

    // out = o @ w_out^T
    if (fuse) {
        gemm_bt<0><<<dim3(HIDN / 128, SEQ / 128), 512, 0, stream>>>(o_g, wout_bf, out, SEQ, HIDN, 16384, 16384);
    } else {
        // fallback (r12-proven): read w_out fp32 directly, convert in-kernel
        gemm_bt_f32b<<<dim3(HIDN / 128, SEQ / 128), 512, 0, stream>>>(o_g, w_out, out, SEQ, HIDN, 16384, 16384);
    }
}

// Round 18
// 915.508 us; speedup vs baseline: 1.1647x; 1.0436x over previous
//
#include <hip/hip_runtime.h>
#include <hip/hip_bf16.h>
#include <math.h>

// ---- problem constants ----
#define HIDN 7168
#define NHEAD 128
#define QLRANK 1536
#define KVLRANK 512
#define QKD 128
#define VHD 128
#define RHD 64
#define SEQ 1024
#define RMS_EPS 1.1920929e-07f

typedef unsigned short u16;
typedef __attribute__((ext_vector_type(8))) short bf16x8;
typedef __attribute__((ext_vector_type(4))) float f32x4;
typedef __attribute__((ext_vector_type(4))) unsigned short u16x4;
typedef __attribute__((ext_vector_type(8))) unsigned short u16x8;

__device__ __forceinline__ u16 f2bf(float f) {
    unsigned int u = __float_as_uint(f);
    unsigned int r = (u + 0x7FFFu + ((u >> 16) & 1u)) >> 16;
    return (u16)r;
}
__device__ __forceinline__ float bf2f(u16 v) {
    return __uint_as_float(((unsigned int)v) << 16);
}

// async global->LDS, 16B per lane. LDS dest is wave-uniform base + lane*16.
__device__ __forceinline__ void gld_lds16(const u16* g, u16* l) {
    __builtin_amdgcn_global_load_lds(
        (const __attribute__((address_space(1))) unsigned int*)g,
        (__attribute__((address_space(3))) unsigned int*)l,
        16, 0, 0);
}

// ---------------- fp32 -> bf16 conversion (x8 vectorized) ----------------
__global__ __launch_bounds__(256) void f32_to_bf16(const float* __restrict__ in,
                                                   u16* __restrict__ out, long n) {
    long i = ((long)blockIdx.x * blockDim.x + threadIdx.x) * 8;
    long stride = (long)gridDim.x * blockDim.x * 8;
    for (; i < n; i += stride) {
        float4 a = *(const float4*)(in + i);
        float4 b = *(const float4*)(in + i + 4);
        u16x8 o;
        o[0] = f2bf(a.x); o[1] = f2bf(a.y); o[2] = f2bf(a.z); o[3] = f2bf(a.w);
        o[4] = f2bf(b.x); o[5] = f2bf(b.y); o[6] = f2bf(b.z); o[7] = f2bf(b.w);
        *(u16x8*)(out + i) = o;
    }
}

// ---------------- generic GEMM (r10-proven): C[m][n] = sum_k A[m][k]*B[n][k] ----------------
// 128x128 tile, BK=64, 8 waves (2M x 4N, 64x32 out/wave), LDS 64 KiB dbuf ->
// 2 WG/CU x 8 waves = 4 waves/SIMD TLP; one vmcnt(0)+s_barrier per K-step.
// global_load_lds(16) staging, coalesced row-grouped source + XOR chunk swizzle.
// Split-K via blockIdx.z: fp32 partials at Cv + z*M*N (OUT_BF16=0 only).
template <int OUT_BF16>
__global__ __launch_bounds__(512) void gemm_bt(const u16* __restrict__ A,
                                               const u16* __restrict__ B,
                                               void* __restrict__ Cv,
                                               int M, int N, int Kslice, long ldk) {
    __shared__ u16 As[2 * 128 * 64];
    __shared__ u16 Bs[2 * 128 * 64];
    const int tid = threadIdx.x;
    const int lane = tid & 63;
    const int w = tid >> 6;
    const int wr = w >> 2, wc = w & 3;
    const int l15 = lane & 15, lg = lane >> 4;
    const int n0 = blockIdx.x * 128;
    const int m0 = blockIdx.y * 128;
    const long kbase = (long)blockIdx.z * Kslice;

    const u16* asrc[2];
    const u16* bsrc[2];
    int aoff[2];
#pragma unroll
    for (int i = 0; i < 2; ++i) {
        int r = (w * 2 + i) * 8 + (lane >> 3);
        int gc = (lane & 7) ^ (r & 7);
        asrc[i] = A + (long)(m0 + r) * ldk + kbase + gc * 8;
        int br = n0 + r; if (br >= N) br = N - 1;
        bsrc[i] = B + (long)br * ldk + kbase + gc * 8;
        aoff[i] = (w * 2 + i) * 512;
    }

    f32x4 acc[4][2];
    const f32x4 z = {0.f, 0.f, 0.f, 0.f};
#pragma unroll
    for (int i = 0; i < 4; ++i)
#pragma unroll
        for (int j = 0; j < 2; ++j) acc[i][j] = z;

    auto stage = [&](int bufi, int kofs) {
#pragma unroll
        for (int i = 0; i < 2; ++i) {
            gld_lds16(asrc[i] + kofs, As + bufi * 8192 + aoff[i]);
            gld_lds16(bsrc[i] + kofs, Bs + bufi * 8192 + aoff[i]);
        }
    };

    const int nsteps = Kslice >> 6;
    stage(0, 0);
    asm volatile("s_waitcnt vmcnt(0)" ::: "memory");
    __builtin_amdgcn_s_barrier();

    int cur = 0;
    for (int t = 0; t < nsteps; ++t) {
        if (t + 1 < nsteps) stage(cur ^ 1, (t + 1) * 64);
        const u16* Ab = As + cur * 8192;
        const u16* Bb = Bs + cur * 8192;
#pragma unroll
        for (int kk = 0; kk < 2; ++kk) {
            bf16x8 a[4], b[2];
#pragma unroll
            for (int i = 0; i < 4; ++i) {
                int row = wr * 64 + i * 16 + l15;
                a[i] = *(const bf16x8*)&Ab[row * 64 + ((kk * 4 + lg) ^ (row & 7)) * 8];
            }
#pragma unroll
            for (int j = 0; j < 2; ++j) {
                int row = wc * 32 + j * 16 + l15;
                b[j] = *(const bf16x8*)&Bb[row * 64 + ((kk * 4 + lg) ^ (row & 7)) * 8];
            }
#pragma unroll
            for (int i = 0; i < 4; ++i)
#pragma unroll
                for (int j = 0; j < 2; ++j)
                    acc[i][j] = __builtin_amdgcn_mfma_f32_16x16x32_bf16(a[i], b[j], acc[i][j], 0, 0, 0);
        }
        asm volatile("s_waitcnt vmcnt(0)" ::: "memory");
        __builtin_amdgcn_s_barrier();
        cur ^= 1;
    }

#pragma unroll
    for (int i = 0; i < 4; ++i)
#pragma unroll
        for (int j = 0; j < 2; ++j)
#pragma unroll
            for (int r = 0; r < 4; ++r) {
                int m = m0 + wr * 64 + i * 16 + lg * 4 + r;
                int n = n0 + wc * 32 + j * 16 + l15;
                if (n < N) {
                    if (OUT_BF16)
                        ((u16*)Cv)[(long)m * N + n] = f2bf(acc[i][j][r]);
                    else
                        ((float*)Cv)[(long)blockIdx.z * M * N + (long)m * N + n] = acc[i][j][r];
                }
            }
}

// ---------------- GEMM with fused fp32->bf16 on B (r12-proven fallback) ----------------
__global__ __launch_bounds__(512) void gemm_bt_f32b(const u16* __restrict__ A,
                                                    const float* __restrict__ B,
                                                    float* __restrict__ Cv,
                                                    int M, int N, int K, long ldk) {
    __shared__ u16 As[2 * 128 * 64];
    __shared__ u16 Bs[2 * 128 * 64];
    const int tid = threadIdx.x;
    const int lane = tid & 63;
    const int w = tid >> 6;
    const int wr = w >> 2, wc = w & 3;
    const int l15 = lane & 15, lg = lane >> 4;
    const int n0 = blockIdx.x * 128;
    const int m0 = blockIdx.y * 128;

    const u16* asrc[2];
    int aoff[2];
#pragma unroll
    for (int i = 0; i < 2; ++i) {
        int r = (w * 2 + i) * 8 + (lane >> 3);
        int gc = (lane & 7) ^ (r & 7);
        asrc[i] = A + (long)(m0 + r) * ldk + gc * 8;
        aoff[i] = (w * 2 + i) * 512;
    }

    const float* bsrcf[4];
    int bdst[4];
#pragma unroll
    for (int i = 0; i < 4; ++i) {
        int c = i * 64 + lane;
        int rl = c >> 4, ch = c & 15;
        int lrow = w * 16 + rl;
        int gr = n0 + lrow; if (gr >= N) gr = N - 1;
        bsrcf[i] = B + (long)gr * ldk + ch * 4;
        bdst[i] = lrow * 64 + (((ch >> 1) ^ (lrow & 7)) * 8) + (ch & 1) * 4;
    }

    f32x4 acc[4][2];
    const f32x4 z = {0.f, 0.f, 0.f, 0.f};
#pragma unroll
    for (int i = 0; i < 4; ++i)
#pragma unroll
        for (int j = 0; j < 2; ++j) acc[i][j] = z;

    float4 bv[4];
    auto stageA = [&](int bufi, int kofs) {
#pragma unroll
        for (int i = 0; i < 2; ++i)
            gld_lds16(asrc[i] + kofs, As + bufi * 8192 + aoff[i]);
    };
    auto loadB = [&](int kofs) {
#pragma unroll
        for (int i = 0; i < 4; ++i) bv[i] = *(const float4*)(bsrcf[i] + kofs);
    };
    auto writeB = [&](int bufi) {
#pragma unroll
        for (int i = 0; i < 4; ++i) {
            u16x4 o;
            o[0] = f2bf(bv[i].x); o[1] = f2bf(bv[i].y);
            o[2] = f2bf(bv[i].z); o[3] = f2bf(bv[i].w);
            *(u16x4*)&Bs[bufi * 8192 + bdst[i]] = o;
        }
    };

    const int nsteps = K >> 6;
    stageA(0, 0);
    loadB(0);
    asm volatile("s_waitcnt vmcnt(0)" ::: "memory");
    writeB(0);
    asm volatile("s_waitcnt lgkmcnt(0)" ::: "memory");
    __builtin_amdgcn_s_barrier();

    int cur = 0;
    for (int t = 0; t < nsteps; ++t) {
        if (t + 1 < nsteps) {
            stageA(cur ^ 1, (t + 1) * 64);
            loadB((t + 1) * 64);
        }
        const u16* Ab = As + cur * 8192;
        const u16* Bb = Bs + cur * 8192;
#pragma unroll
        for (int kk = 0; kk < 2; ++kk) {
            bf16x8 a[4], b[2];
#pragma unroll
            for (int i = 0; i < 4; ++i) {
                int row = wr * 64 + i * 16 + l15;
                a[i] = *(const bf16x8*)&Ab[row * 64 + ((kk * 4 + lg) ^ (row & 7)) * 8];
            }
#pragma unroll
            for (int j = 0; j < 2; ++j) {
                int row = wc * 32 + j * 16 + l15;
                b[j] = *(const bf16x8*)&Bb[row * 64 + ((kk * 4 + lg) ^ (row & 7)) * 8];
            }
#pragma unroll
            for (int i = 0; i < 4; ++i)
#pragma unroll
                for (int j = 0; j < 2; ++j)
                    acc[i][j] = __builtin_amdgcn_mfma_f32_16x16x32_bf16(a[i], b[j], acc[i][j], 0, 0, 0);
        }
        asm volatile("s_waitcnt vmcnt(0)" ::: "memory");
        if (t + 1 < nsteps) writeB(cur ^ 1);
        asm volatile("s_waitcnt lgkmcnt(0)" ::: "memory");
        __builtin_amdgcn_s_barrier();
        cur ^= 1;
    }

#pragma unroll
    for (int i = 0; i < 4; ++i)
#pragma unroll
        for (int j = 0; j < 2; ++j)
#pragma unroll
            for (int r = 0; r < 4; ++r) {
                int m = m0 + wr * 64 + i * 16 + lg * 4 + r;
                int n = n0 + wc * 32 + j * 16 + l15;
                if (n < N) Cv[(long)m * N + n] = acc[i][j][r];
            }
}

// ---------------- sum split-K partials (fp32), x4 vectorized ----------------
__global__ __launch_bounds__(256) void reduce_parts(const float* __restrict__ parts,
                                                    float* __restrict__ out,
                                                    int nparts, long mn) {
    long i = ((long)blockIdx.x * 256 + threadIdx.x) * 4;
    long stride = (long)gridDim.x * 256 * 4;
    for (; i < mn; i += stride) {
        float4 s = *(const float4*)(parts + i);
        for (int p = 1; p < nparts; ++p) {
            float4 v = *(const float4*)(parts + (long)p * mn + i);
            s.x += v.x; s.y += v.y; s.z += v.z; s.w += v.w;
        }
        *(float4*)(out + i) = s;
    }
}

// ---------------- RMSNorm ----------------
__global__ __launch_bounds__(256) void rmsnorm_kernel(const float* __restrict__ x,
                                                      const float* __restrict__ w,
                                                      u16* __restrict__ y,
                                                      int stride, int norm_len) {
    const int row = blockIdx.x;
    const float* xr = x + (long)row * stride;
    float ss = 0.f;
    for (int i = threadIdx.x; i < norm_len; i += 256) {
        float v = xr[i];
        ss += v * v;
    }
#pragma unroll
    for (int off = 32; off > 0; off >>= 1) ss += __shfl_down(ss, off);
    __shared__ float partial[4];
    if ((threadIdx.x & 63) == 0) partial[threadIdx.x >> 6] = ss;
    __syncthreads();
    float tot = partial[0] + partial[1] + partial[2] + partial[3];
    float rs = 1.0f / sqrtf(tot / (float)norm_len + RMS_EPS);
    u16* yr = y + (long)row * norm_len;
    for (int i = threadIdx.x; i < norm_len; i += 256) yr[i] = f2bf(xr[i] * rs * w[i]);
}

// ---------------- RoPE tables ----------------
__global__ void rope_tables(float* __restrict__ cos_t, float* __restrict__ sin_t) {
    int s = blockIdx.x;
    int i = threadIdx.x;
    float invf = powf(10000.0f, -((float)(2 * i) / 64.0f));
    float ang = (float)s * invf;
    cos_t[s * 32 + i] = cosf(ang);
    sin_t[s * 32 + i] = sinf(ang);
}

// ---------------- RoPE on q_r ----------------
__global__ void rope_q(u16* __restrict__ q_cr, const float* __restrict__ cos_t,
                       const float* __restrict__ sin_t) {
    int s = blockIdx.x;
    int h = blockIdx.y * 2 + (threadIdx.x >> 5);
    int i = threadIdx.x & 31;
    u16* base = q_cr + (s * (NHEAD * 192) + h * 192 + QKD);
    float x1 = bf2f(base[i]);
    float x2 = bf2f(base[i + 32]);
    float c = cos_t[s * 32 + i], sn = sin_t[s * 32 + i];
    base[i]      = f2bf(x1 * c - x2 * sn);
    base[i + 32] = f2bf(x2 * c + x1 * sn);
}

// ---------------- RoPE on k_r ----------------
__global__ void rope_k(const float* __restrict__ ckv_kr, const float* __restrict__ cos_t,
                       const float* __restrict__ sin_t, u16* __restrict__ kr) {
    int s = blockIdx.x;
    int i = threadIdx.x;
    if (i < 32) {
        const float* base = ckv_kr + (s * 576 + 512);
        float x1 = base[i], x2 = base[i + 32];
        float c = cos_t[s * 32 + i], sn = sin_t[s * 32 + i];
        kr[s * 64 + i]      = f2bf(x1 * c - x2 * sn);
        kr[s * 64 + i + 32] = f2bf(x2 * c + x1 * sn);
    }
}

// ---------------- build vT[h][dv][s] from kv[s][h*256+128+dv] ----------------
__global__ __launch_bounds__(256) void build_vt(const u16* __restrict__ kv,
                                                u16* __restrict__ vT) {
    __shared__ u16 vtile[64][136];
    const int h = blockIdx.x, sb = blockIdx.y, s0 = sb * 64;
    const int tid = threadIdx.x;
#pragma unroll
    for (int it = 0; it < 4; ++it) {
        int c = it * 256 + tid;
        int row = c >> 4;
        int off8 = (c & 15) * 8;
        *(u16x8*)&vtile[row][off8] =
            *(const u16x8*)&kv[(s0 + row) * 32768 + h * 256 + 128 + off8];
    }
    __syncthreads();
    const int sl = tid & 63;
    const int dvb = tid >> 6;
#pragma unroll
    for (int it = 0; it < 32; ++it) {
        int dv = dvb + it * 4;
        vT[(h * 128 + dv) * 1024 + s0 + sl] = vtile[sl][dv];
    }
}

// ---------------- flash attention + double-buffered fused w_out conversion ----------------
// r17 structure; the conversion is now pipelined T14-style: chunk kt is
// LOADED at tile kt-1 and STORED at tile kt (the store's implicit waitcnt
// sits behind load_tile(kt+1)'s 5 newer loads -> non-blocking; the fresh
// loads get a full tile of compute as latency cover). +16 VGPR.
__global__ __launch_bounds__(512) void mla_attn(const u16* __restrict__ q_cr,
                                                const u16* __restrict__ kv,
                                                const u16* __restrict__ kr,
                                                const u16* __restrict__ vT,
                                                u16* __restrict__ o_g,
                                                const float* __restrict__ wsrc,
                                                u16* __restrict__ wdst,
                                                int do_conv) {
    __shared__ u16 ks[64][200];
    __shared__ u16 vts[128][72];
    __shared__ u16 p_lds[8][16][72];
    const int qb = blockIdx.x, h = blockIdx.y;
    const int s0q = qb * 128;
    const int tid = threadIdx.x, lane = tid & 63, w = tid >> 6;
    const int l15 = lane & 15, lg = lane >> 4;
    const float scale = 0.07216878364870323f;

    bf16x8 qreg[6];
    {
        const int qrow = s0q + w * 16 + l15;
#pragma unroll
        for (int kk = 0; kk < 6; ++kk)
            qreg[kk] = *(const bf16x8*)&q_cr[qrow * (NHEAD * 192) + h * 192 + kk * 32 + lg * 8];
    }

    const int krow0 = tid >> 4,           koff0 = (tid & 15) * 8;
    const int krow1 = (512 + tid) >> 4,   koff1 = ((512 + tid) & 15) * 8;
    const int rrow  = tid >> 3,           roff  = (tid & 7) * 8;
    const int vdv0  = tid >> 3,           voff0 = (tid & 7) * 8;
    const int vdv1  = (512 + tid) >> 3,   voff1 = ((512 + tid) & 7) * 8;
    const u16* kvp = kv + h * 256;
    const u16* vtp = vT + (long)(h * 128) * 1024;

    u16x8 kreg0, kreg1, krreg, vreg0, vreg1;
    auto load_tile = [&](int s0k) {
        kreg0 = *(const u16x8*)&kvp[(long)(s0k + krow0) * 32768 + koff0];
        kreg1 = *(const u16x8*)&kvp[(long)(s0k + krow1) * 32768 + koff1];
        krreg = *(const u16x8*)&kr[(s0k + rrow) * 64 + roff];
        vreg0 = *(const u16x8*)&vtp[(long)vdv0 * 1024 + s0k + voff0];
        vreg1 = *(const u16x8*)&vtp[(long)vdv1 * 1024 + s0k + voff1];
    };

    // conversion chunking: block owns groups [cbase, cbase+16*896);
    // per tile: up to 2 u16x8 groups per thread (896 = 512 + 384).
    const long cbase = ((long)(h * 8 + qb)) * 16 * 896;
    float4 cva0, cvb0, cva1, cvb1;   // double-buffer regs for 2 groups
    const int gi0 = tid;             // group 0 index within chunk
    const int gi1 = 512 + tid;       // group 1 (active when tid < 384)
    auto conv_load = [&](int kt) {
        long g0 = cbase + (long)kt * 896;
        long a0 = (g0 + gi0) * 8;
        cva0 = *(const float4*)(wsrc + a0);
        cvb0 = *(const float4*)(wsrc + a0 + 4);
        if (gi1 < 896) {
            long a1 = (g0 + gi1) * 8;
            cva1 = *(const float4*)(wsrc + a1);
            cvb1 = *(const float4*)(wsrc + a1 + 4);
        }
    };
    auto conv_store = [&](int kt) {
        long g0 = cbase + (long)kt * 896;
        u16x8 o;
        o[0] = f2bf(cva0.x); o[1] = f2bf(cva0.y); o[2] = f2bf(cva0.z); o[3] = f2bf(cva0.w);
        o[4] = f2bf(cvb0.x); o[5] = f2bf(cvb0.y); o[6] = f2bf(cvb0.z); o[7] = f2bf(cvb0.w);
        *(u16x8*)(wdst + (g0 + gi0) * 8) = o;
        if (gi1 < 896) {
            u16x8 o1;
            o1[0] = f2bf(cva1.x); o1[1] = f2bf(cva1.y); o1[2] = f2bf(cva1.z); o1[3] = f2bf(cva1.w);
            o1[4] = f2bf(cvb1.x); o1[5] = f2bf(cvb1.y); o1[6] = f2bf(cvb1.z); o1[7] = f2bf(cvb1.w);
            *(u16x8*)(wdst + (g0 + gi1) * 8) = o1;
        }
    };

    f32x4 o_acc[8];
    const f32x4 z = {0.f, 0.f, 0.f, 0.f};
#pragma unroll
    for (int d = 0; d < 8; ++d) o_acc[d] = z;
    float m_r[4], l_r[4];
#pragma unroll
    for (int r = 0; r < 4; ++r) { m_r[r] = -1e30f; l_r[r] = 0.f; }

    load_tile(0);
    if (do_conv) conv_load(0);       // prologue: chunk 0 in flight

    for (int kt = 0; kt < 16; ++kt) {
        __syncthreads();
        *(u16x8*)&ks[krow0][koff0]      = kreg0;
        *(u16x8*)&ks[krow1][koff1]      = kreg1;
        *(u16x8*)&ks[rrow][128 + roff]  = krreg;
        *(u16x8*)&vts[vdv0][voff0]      = vreg0;
        *(u16x8*)&vts[vdv1][voff1]      = vreg1;
        __syncthreads();
        if (kt + 1 < 16) load_tile((kt + 1) * 64);

        // pipelined conversion: store chunk kt (loaded last tile), load kt+1
        if (do_conv) {
            conv_store(kt);
            if (kt + 1 < 16) conv_load(kt + 1);
        }

        // QK^T
        f32x4 sf[4];
#pragma unroll
        for (int j = 0; j < 4; ++j) sf[j] = z;
        __builtin_amdgcn_s_setprio(1);
#pragma unroll
        for (int kk = 0; kk < 6; ++kk) {
            bf16x8 a = qreg[kk];
#pragma unroll
            for (int j = 0; j < 4; ++j) {
                bf16x8 b = *(const bf16x8*)&ks[j * 16 + l15][kk * 32 + lg * 8];
                sf[j] = __builtin_amdgcn_mfma_f32_16x16x32_bf16(a, b, sf[j], 0, 0, 0);
            }
        }
        __builtin_amdgcn_s_setprio(0);

        // online softmax
        float p[4][4];
        float alpha[4];
#pragma unroll
        for (int r = 0; r < 4; ++r) {
            float mx = fmaxf(fmaxf(sf[0][r], sf[1][r]), fmaxf(sf[2][r], sf[3][r]));
#pragma unroll
            for (int off = 1; off < 16; off <<= 1) mx = fmaxf(mx, __shfl_xor(mx, off));
            mx *= scale;
            float mnew = fmaxf(m_r[r], mx);
            alpha[r] = __expf(m_r[r] - mnew);
            float rs = 0.f;
#pragma unroll
            for (int j = 0; j < 4; ++j) {
                float pv = __expf(sf[j][r] * scale - mnew);
                p[j][r] = pv;
                rs += pv;
            }
#pragma unroll
            for (int off = 1; off < 16; off <<= 1) rs += __shfl_xor(rs, off);
            l_r[r] = l_r[r] * alpha[r] + rs;
            m_r[r] = mnew;
        }
#pragma unroll
        for (int d = 0; d < 8; ++d)
#pragma unroll
            for (int r = 0; r < 4; ++r) o_acc[d][r] *= alpha[r];

        // P -> LDS (wave-private)
#pragma unroll
        for (int j = 0; j < 4; ++j)
#pragma unroll
            for (int r = 0; r < 4; ++r)
                p_lds[w][lg * 4 + r][j * 16 + l15] = f2bf(p[j][r]);

        // PV
        __builtin_amdgcn_s_setprio(1);
#pragma unroll
        for (int kk2 = 0; kk2 < 2; ++kk2) {
            bf16x8 a = *(const bf16x8*)&p_lds[w][l15][kk2 * 32 + lg * 8];
#pragma unroll
            for (int d = 0; d < 8; ++d) {
                bf16x8 b = *(const bf16x8*)&vts[d * 16 + l15][kk2 * 32 + lg * 8];
                o_acc[d] = __builtin_amdgcn_mfma_f32_16x16x32_bf16(a, b, o_acc[d], 0, 0, 0);
            }
        }
        __builtin_amdgcn_s_setprio(0);
    }

#pragma unroll
    for (int d = 0; d < 8; ++d)
#pragma unroll
        for (int r = 0; r < 4; ++r) {
            int srow = s0q + w * 16 + lg * 4 + r;
            float v = o_acc[d][r] / l_r[r];
            o_g[srow * 16384 + h * 128 + d * 16 + l15] = f2bf(v);
        }
}

// ---------------- host launcher ----------------
extern "C" void kernel_launch(void* const* d_in, const int* in_sizes, int n_in,
                              void* d_out, int out_size, void* d_ws, size_t ws_size,
                              hipStream_t stream) {
    const float* hs        = (const float*)d_in[0];
    const float* w_q_down  = (const float*)d_in[1];
    const float* q_norm_w  = (const float*)d_in[2];
    const float* w_q_up    = (const float*)d_in[3];
    const float* w_kv_down = (const float*)d_in[4];
    const float* kv_norm_w = (const float*)d_in[5];
    const float* w_kv_up   = (const float*)d_in[6];
    const float* w_out     = (const float*)d_in[7];
    float* out = (float*)d_out;
    char* ws = (char*)d_ws;

    // ---- layout v3: live-at-attention set FIRST (incl. vT), wout after ----
    const size_t SZ_KV   = (size_t)SEQ * 32768 * 2;
    const size_t SZ_QCR  = (size_t)SEQ * (NHEAD * 192) * 2;
    const size_t SZ_KR   = (size_t)SEQ * 64 * 2;
    const size_t SZ_TAB  = (size_t)SEQ * 32 * 4;
    const size_t SZ_VT   = (size_t)NHEAD * 128 * 1024 * 2;
    const size_t SZ_OG   = (size_t)SEQ * 16384 * 2;
    const size_t SZ_WOUT = (size_t)HIDN * 16384 * 2;
    const size_t SZ_WB   = (size_t)24576 * 1536 * 2;
    const size_t SZ_PART = (size_t)4 * SEQ * QLRANK * 4;
    const size_t SZ_HS   = (size_t)SEQ * HIDN * 2;
    const size_t SZ_CQ   = (size_t)SEQ * QLRANK * 4;
    const size_t SZ_CQN  = (size_t)SEQ * QLRANK * 2;
    const size_t SZ_CKV  = (size_t)SEQ * 576 * 4;
    const size_t SZ_CKVN = (size_t)SEQ * KVLRANK * 2;

    size_t off = 0;
    u16* kvb     = (u16*)(ws + off); off += SZ_KV;
    u16* q_cr    = (u16*)(ws + off); off += SZ_QCR;
    u16* kr      = (u16*)(ws + off); off += SZ_KR;
    float* cos_t = (float*)(ws + off); off += SZ_TAB;
    float* sin_t = (float*)(ws + off); off += SZ_TAB;
    u16* vT      = (u16*)(ws + off); off += SZ_VT;
    u16* o_g     = (u16*)(ws + off); off += SZ_OG;
    const size_t live_end = off;
    u16* wout_bf = (u16*)(ws + live_end);
    u16* W_BUF   = (u16*)(ws + live_end);
    float* parts = (float*)(ws + live_end + SZ_WB);
    size_t toff = live_end + SZ_WB + SZ_PART;
    u16* hs_bf    = (u16*)(ws + toff); toff += SZ_HS;
    float* c_q    = (float*)(ws + toff); toff += SZ_CQ;
    u16* cq_n     = (u16*)(ws + toff); toff += SZ_CQN;
    float* ckv_kr = (float*)(ws + toff); toff += SZ_CKV;
    u16* ckv_n    = (u16*)(ws + toff); toff += SZ_CKVN;
    const int fuse = (live_end + SZ_WOUT) <= ws_size;
    (void)in_sizes; (void)n_in; (void)out_size;

    rope_tables<<<dim3(SEQ), dim3(32), 0, stream>>>(cos_t, sin_t);
    f32_to_bf16<<<2048, 256, 0, stream>>>(hs, hs_bf, (long)SEQ * HIDN);

    // c_q = hs @ w_q_down^T   (split-K x4)
    f32_to_bf16<<<2048, 256, 0, stream>>>(w_q_down, W_BUF, (long)QLRANK * HIDN);
    gemm_bt<0><<<dim3(QLRANK / 128, SEQ / 128, 4), 512, 0, stream>>>(hs_bf, W_BUF, parts, SEQ, QLRANK, HIDN / 4, HIDN);
    reduce_parts<<<1024, 256, 0, stream>>>(parts, c_q, 4, (long)SEQ * QLRANK);
    rmsnorm_kernel<<<SEQ, 256, 0, stream>>>(c_q, q_norm_w, cq_n, QLRANK, QLRANK);

    // q_cr = rmsnorm(c_q) @ w_q_up^T
    f32_to_bf16<<<2048, 256, 0, stream>>>(w_q_up, W_BUF, (long)24576 * QLRANK);
    gemm_bt<1><<<dim3(24576 / 128, SEQ / 128), 512, 0, stream>>>(cq_n, W_BUF, q_cr, SEQ, 24576, QLRANK, QLRANK);

    // ckv_kr = hs @ w_kv_down^T   (split-K x8; N=576 ragged)
    f32_to_bf16<<<2048, 256, 0, stream>>>(w_kv_down, W_BUF, (long)576 * HIDN);
    gemm_bt<0><<<dim3(5, SEQ / 128, 8), 512, 0, stream>>>(hs_bf, W_BUF, parts, SEQ, 576, HIDN / 8, HIDN);
    reduce_parts<<<1024, 256, 0, stream>>>(parts, ckv_kr, 8, (long)SEQ * 576);
    rmsnorm_kernel<<<SEQ, 256, 0, stream>>>(ckv_kr, kv_norm_w, ckv_n, 576, KVLRANK);
    rope_k<<<SEQ, 64, 0, stream>>>(ckv_kr, cos_t, sin_t, kr);

    // kv = rmsnorm(c_kv) @ w_kv_up^T
    f32_to_bf16<<<2048, 256, 0, stream>>>(w_kv_up, W_BUF, (long)32768 * KVLRANK);
    gemm_bt<1><<<dim3(32768 / 128, SEQ / 128), 512, 0, stream>>>(ckv_n, W_BUF, kvb, SEQ, 32768, KVLRANK, KVLRANK);

    rope_q<<<dim3(SEQ, NHEAD / 2), 64, 0, stream>>>(q_cr, cos_t, sin_t);
    build_vt<<<dim3(NHEAD, SEQ / 64), 256, 0, stream>>>(kvb, vT);

    // attention; if wout fits, convert w_out under attention's idle BW
    mla_attn<<<dim3(SEQ / 128, NHEAD), 512, 0, stream>>>(q_cr, kvb, kr, vT, o_g,
                                                         w_out, wout_bf, fuse ? 1 : 0);

    // out = o @ w_out^T
    if (fuse) {
        gemm_bt<0><<<dim3(HIDN / 128, SEQ / 128), 512, 0, stream>>>(o_g, wout_bf, out, SEQ, HIDN, 16384, 16384);
    } else {
        gemm_bt_f32b<<<dim3(HIDN / 128, SEQ / 128), 512, 0, stream>>>(o_g, w_out, out, SEQ, HIDN, 16384, 16384);
    }
}

// Round 19
// 897.426 us; speedup vs baseline: 1.1882x; 1.0201x over previous
//
#include <hip/hip_runtime.h>
#include <hip/hip_bf16.h>
#include <math.h>

// ---- problem constants ----
#define HIDN 7168
#define NHEAD 128
#define QLRANK 1536
#define KVLRANK 512
#define QKD 128
#define VHD 128
#define RHD 64
#define SEQ 1024
#define RMS_EPS 1.1920929e-07f

typedef unsigned short u16;
typedef __attribute__((ext_vector_type(8))) short bf16x8;
typedef __attribute__((ext_vector_type(4))) float f32x4;
typedef __attribute__((ext_vector_type(4))) unsigned short u16x4;
typedef __attribute__((ext_vector_type(8))) unsigned short u16x8;

__device__ __forceinline__ u16 f2bf(float f) {
    unsigned int u = __float_as_uint(f);
    unsigned int r = (u + 0x7FFFu + ((u >> 16) & 1u)) >> 16;
    return (u16)r;
}
__device__ __forceinline__ float bf2f(u16 v) {
    return __uint_as_float(((unsigned int)v) << 16);
}

// async global->LDS, 16B per lane. LDS dest is wave-uniform base + lane*16.
__device__ __forceinline__ void gld_lds16(const u16* g, u16* l) {
    __builtin_amdgcn_global_load_lds(
        (const __attribute__((address_space(1))) unsigned int*)g,
        (__attribute__((address_space(3))) unsigned int*)l,
        16, 0, 0);
}

// ---------------- fp32 -> bf16 conversion (x8 vectorized) ----------------
__global__ __launch_bounds__(256) void f32_to_bf16(const float* __restrict__ in,
                                                   u16* __restrict__ out, long n) {
    long i = ((long)blockIdx.x * blockDim.x + threadIdx.x) * 8;
    long stride = (long)gridDim.x * blockDim.x * 8;
    for (; i < n; i += stride) {
        float4 a = *(const float4*)(in + i);
        float4 b = *(const float4*)(in + i + 4);
        u16x8 o;
        o[0] = f2bf(a.x); o[1] = f2bf(a.y); o[2] = f2bf(a.z); o[3] = f2bf(a.w);
        o[4] = f2bf(b.x); o[5] = f2bf(b.y); o[6] = f2bf(b.z); o[7] = f2bf(b.w);
        *(u16x8*)(out + i) = o;
    }
}

// ---------------- generic GEMM (r10-proven) + optional fused side-conversion ----------------
// 128x128 tile, BK=64, 8 waves, 64 KiB LDS dbuf -> 2 WG/CU, 4 waves/SIMD TLP.
// One vmcnt(0)+s_barrier per K-step (drain hidden by cross-wave TLP).
// FCONV: double-buffered fp32->bf16 side-conversion of an unrelated weight
// (r18-proven pattern): window t loaded at step t, stored at step t+1; the
// end-of-step vmcnt(0) drains conv loads alongside the stage loads (same
// latency cover). Each block converts share=ceil(total/nblocks) u16x8 groups.
// Split-K via blockIdx.z: fp32 partials at Cv + z*M*N (OUT_BF16=0 only).
template <int OUT_BF16, int FCONV>
__global__ __launch_bounds__(512) void gemm_bt(const u16* __restrict__ A,
                                               const u16* __restrict__ B,
                                               void* __restrict__ Cv,
                                               int M, int N, int Kslice, long ldk,
                                               const float* __restrict__ cvsrc,
                                               u16* __restrict__ cvdst,
                                               long cvtotal) {
    __shared__ u16 As[2 * 128 * 64];
    __shared__ u16 Bs[2 * 128 * 64];
    const int tid = threadIdx.x;
    const int lane = tid & 63;
    const int w = tid >> 6;
    const int wr = w >> 2, wc = w & 3;
    const int l15 = lane & 15, lg = lane >> 4;
    const int n0 = blockIdx.x * 128;
    const int m0 = blockIdx.y * 128;
    const long kbase = (long)blockIdx.z * Kslice;

    const u16* asrc[2];
    const u16* bsrc[2];
    int aoff[2];
#pragma unroll
    for (int i = 0; i < 2; ++i) {
        int r = (w * 2 + i) * 8 + (lane >> 3);
        int gc = (lane & 7) ^ (r & 7);
        asrc[i] = A + (long)(m0 + r) * ldk + kbase + gc * 8;
        int br = n0 + r; if (br >= N) br = N - 1;
        bsrc[i] = B + (long)br * ldk + kbase + gc * 8;
        aoff[i] = (w * 2 + i) * 512;
    }

    // side-conversion bookkeeping
    long gbase = 0, gend = 0;
    int nwin = 0;
    float4 cva, cvb;
    long gcur = -1, gprev = -1;
    if (FCONV) {
        const int nblocks = gridDim.x * gridDim.y * gridDim.z;
        const int bl = (blockIdx.z * gridDim.y + blockIdx.y) * gridDim.x + blockIdx.x;
        long share = (cvtotal + nblocks - 1) / nblocks;
        gbase = (long)bl * share;
        gend = gbase + share; if (gend > cvtotal) gend = cvtotal;
        nwin = (int)((share + 511) >> 9);
    }

    f32x4 acc[4][2];
    const f32x4 z = {0.f, 0.f, 0.f, 0.f};
#pragma unroll
    for (int i = 0; i < 4; ++i)
#pragma unroll
        for (int j = 0; j < 2; ++j) acc[i][j] = z;

    auto stage = [&](int bufi, int kofs) {
#pragma unroll
        for (int i = 0; i < 2; ++i) {
            gld_lds16(asrc[i] + kofs, As + bufi * 8192 + aoff[i]);
            gld_lds16(bsrc[i] + kofs, Bs + bufi * 8192 + aoff[i]);
        }
    };

    const int nsteps = Kslice >> 6;
    stage(0, 0);
    asm volatile("s_waitcnt vmcnt(0)" ::: "memory");
    __builtin_amdgcn_s_barrier();

    int cur = 0;
    for (int t = 0; t < nsteps; ++t) {
        if (t + 1 < nsteps) stage(cur ^ 1, (t + 1) * 64);
        if (FCONV) {
            // store window t-1 (regs loaded last step, already drained)
            if (gprev >= 0) {
                u16x8 o;
                o[0] = f2bf(cva.x); o[1] = f2bf(cva.y); o[2] = f2bf(cva.z); o[3] = f2bf(cva.w);
                o[4] = f2bf(cvb.x); o[5] = f2bf(cvb.y); o[6] = f2bf(cvb.z); o[7] = f2bf(cvb.w);
                *(u16x8*)(cvdst + gprev * 8) = o;
            }
            gprev = -1;
            // load window t
            if (t < nwin) {
                long g = gbase + (long)t * 512 + tid;
                if (g < gend) {
                    cva = *(const float4*)(cvsrc + g * 8);
                    cvb = *(const float4*)(cvsrc + g * 8 + 4);
                    gprev = g;
                }
            }
        }
        const u16* Ab = As + cur * 8192;
        const u16* Bb = Bs + cur * 8192;
#pragma unroll
        for (int kk = 0; kk < 2; ++kk) {
            bf16x8 a[4], b[2];
#pragma unroll
            for (int i = 0; i < 4; ++i) {
                int row = wr * 64 + i * 16 + l15;
                a[i] = *(const bf16x8*)&Ab[row * 64 + ((kk * 4 + lg) ^ (row & 7)) * 8];
            }
#pragma unroll
            for (int j = 0; j < 2; ++j) {
                int row = wc * 32 + j * 16 + l15;
                b[j] = *(const bf16x8*)&Bb[row * 64 + ((kk * 4 + lg) ^ (row & 7)) * 8];
            }
#pragma unroll
            for (int i = 0; i < 4; ++i)
#pragma unroll
                for (int j = 0; j < 2; ++j)
                    acc[i][j] = __builtin_amdgcn_mfma_f32_16x16x32_bf16(a[i], b[j], acc[i][j], 0, 0, 0);
        }
        asm volatile("s_waitcnt vmcnt(0)" ::: "memory");
        __builtin_amdgcn_s_barrier();
        cur ^= 1;
    }
    // final pending conversion store (loads drained by last vmcnt(0))
    if (FCONV && gprev >= 0) {
        u16x8 o;
        o[0] = f2bf(cva.x); o[1] = f2bf(cva.y); o[2] = f2bf(cva.z); o[3] = f2bf(cva.w);
        o[4] = f2bf(cvb.x); o[5] = f2bf(cvb.y); o[6] = f2bf(cvb.z); o[7] = f2bf(cvb.w);
        *(u16x8*)(cvdst + gprev * 8) = o;
    }

#pragma unroll
    for (int i = 0; i < 4; ++i)
#pragma unroll
        for (int j = 0; j < 2; ++j)
#pragma unroll
            for (int r = 0; r < 4; ++r) {
                int m = m0 + wr * 64 + i * 16 + lg * 4 + r;
                int n = n0 + wc * 32 + j * 16 + l15;
                if (n < N) {
                    if (OUT_BF16)
                        ((u16*)Cv)[(long)m * N + n] = f2bf(acc[i][j][r]);
                    else
                        ((float*)Cv)[(long)blockIdx.z * M * N + (long)m * N + n] = acc[i][j][r];
                }
            }
}

// ---------------- sum split-K partials (fp32), x4 vectorized ----------------
__global__ __launch_bounds__(256) void reduce_parts(const float* __restrict__ parts,
                                                    float* __restrict__ out,
                                                    int nparts, long mn) {
    long i = ((long)blockIdx.x * 256 + threadIdx.x) * 4;
    long stride = (long)gridDim.x * 256 * 4;
    for (; i < mn; i += stride) {
        float4 s = *(const float4*)(parts + i);
        for (int p = 1; p < nparts; ++p) {
            float4 v = *(const float4*)(parts + (long)p * mn + i);
            s.x += v.x; s.y += v.y; s.z += v.z; s.w += v.w;
        }
        *(float4*)(out + i) = s;
    }
}

// ---------------- RMSNorm ----------------
__global__ __launch_bounds__(256) void rmsnorm_kernel(const float* __restrict__ x,
                                                      const float* __restrict__ w,
                                                      u16* __restrict__ y,
                                                      int stride, int norm_len) {
    const int row = blockIdx.x;
    const float* xr = x + (long)row * stride;
    float ss = 0.f;
    for (int i = threadIdx.x; i < norm_len; i += 256) {
        float v = xr[i];
        ss += v * v;
    }
#pragma unroll
    for (int off = 32; off > 0; off >>= 1) ss += __shfl_down(ss, off);
    __shared__ float partial[4];
    if ((threadIdx.x & 63) == 0) partial[threadIdx.x >> 6] = ss;
    __syncthreads();
    float tot = partial[0] + partial[1] + partial[2] + partial[3];
    float rs = 1.0f / sqrtf(tot / (float)norm_len + RMS_EPS);
    u16* yr = y + (long)row * norm_len;
    for (int i = threadIdx.x; i < norm_len; i += 256) yr[i] = f2bf(xr[i] * rs * w[i]);
}

// ---------------- RoPE tables ----------------
__global__ void rope_tables(float* __restrict__ cos_t, float* __restrict__ sin_t) {
    int s = blockIdx.x;
    int i = threadIdx.x;
    float invf = powf(10000.0f, -((float)(2 * i) / 64.0f));
    float ang = (float)s * invf;
    cos_t[s * 32 + i] = cosf(ang);
    sin_t[s * 32 + i] = sinf(ang);
}

// ---------------- RoPE on q_r ----------------
__global__ void rope_q(u16* __restrict__ q_cr, const float* __restrict__ cos_t,
                       const float* __restrict__ sin_t) {
    int s = blockIdx.x;
    int h = blockIdx.y * 2 + (threadIdx.x >> 5);
    int i = threadIdx.x & 31;
    u16* base = q_cr + (s * (NHEAD * 192) + h * 192 + QKD);
    float x1 = bf2f(base[i]);
    float x2 = bf2f(base[i + 32]);
    float c = cos_t[s * 32 + i], sn = sin_t[s * 32 + i];
    base[i]      = f2bf(x1 * c - x2 * sn);
    base[i + 32] = f2bf(x2 * c + x1 * sn);
}

// ---------------- RoPE on k_r ----------------
__global__ void rope_k(const float* __restrict__ ckv_kr, const float* __restrict__ cos_t,
                       const float* __restrict__ sin_t, u16* __restrict__ kr) {
    int s = blockIdx.x;
    int i = threadIdx.x;
    if (i < 32) {
        const float* base = ckv_kr + (s * 576 + 512);
        float x1 = base[i], x2 = base[i + 32];
        float c = cos_t[s * 32 + i], sn = sin_t[s * 32 + i];
        kr[s * 64 + i]      = f2bf(x1 * c - x2 * sn);
        kr[s * 64 + i + 32] = f2bf(x2 * c + x1 * sn);
    }
}

// ---------------- build vT[h][dv][s] from kv[s][h*256+128+dv] ----------------
__global__ __launch_bounds__(256) void build_vt(const u16* __restrict__ kv,
                                                u16* __restrict__ vT) {
    __shared__ u16 vtile[64][136];
    const int h = blockIdx.x, sb = blockIdx.y, s0 = sb * 64;
    const int tid = threadIdx.x;
#pragma unroll
    for (int it = 0; it < 4; ++it) {
        int c = it * 256 + tid;
        int row = c >> 4;
        int off8 = (c & 15) * 8;
        *(u16x8*)&vtile[row][off8] =
            *(const u16x8*)&kv[(s0 + row) * 32768 + h * 256 + 128 + off8];
    }
    __syncthreads();
    const int sl = tid & 63;
    const int dvb = tid >> 6;
#pragma unroll
    for (int it = 0; it < 32; ++it) {
        int dv = dvb + it * 4;
        vT[(h * 128 + dv) * 1024 + s0 + sl] = vtile[sl][dv];
    }
}

// ---------------- flash attention + double-buffered fused w_out conversion ----------------
// r18 structure; p_lds row stride 72 -> 68: write-side lg-groups now land at
// dword offsets {0,8,16,24} (4 distinct vs {0,16,0,16}) -> ~2x fewer LDS
// bank conflicts on the scalar P writes; read starts stay 2-way (free).
__global__ __launch_bounds__(512) void mla_attn(const u16* __restrict__ q_cr,
                                                const u16* __restrict__ kv,
                                                const u16* __restrict__ kr,
                                                const u16* __restrict__ vT,
                                                u16* __restrict__ o_g,
                                                const float* __restrict__ wsrc,
                                                u16* __restrict__ wdst,
                                                int do_conv) {
    __shared__ u16 ks[64][200];
    __shared__ u16 vts[128][72];
    __shared__ u16 p_lds[8][16][68];
    const int qb = blockIdx.x, h = blockIdx.y;
    const int s0q = qb * 128;
    const int tid = threadIdx.x, lane = tid & 63, w = tid >> 6;
    const int l15 = lane & 15, lg = lane >> 4;
    const float scale = 0.07216878364870323f;

    bf16x8 qreg[6];
    {
        const int qrow = s0q + w * 16 + l15;
#pragma unroll
        for (int kk = 0; kk < 6; ++kk)
            qreg[kk] = *(const bf16x8*)&q_cr[qrow * (NHEAD * 192) + h * 192 + kk * 32 + lg * 8];
    }

    const int krow0 = tid >> 4,           koff0 = (tid & 15) * 8;
    const int krow1 = (512 + tid) >> 4,   koff1 = ((512 + tid) & 15) * 8;
    const int rrow  = tid >> 3,           roff  = (tid & 7) * 8;
    const int vdv0  = tid >> 3,           voff0 = (tid & 7) * 8;
    const int vdv1  = (512 + tid) >> 3,   voff1 = ((512 + tid) & 7) * 8;
    const u16* kvp = kv + h * 256;
    const u16* vtp = vT + (long)(h * 128) * 1024;

    u16x8 kreg0, kreg1, krreg, vreg0, vreg1;
    auto load_tile = [&](int s0k) {
        kreg0 = *(const u16x8*)&kvp[(long)(s0k + krow0) * 32768 + koff0];
        kreg1 = *(const u16x8*)&kvp[(long)(s0k + krow1) * 32768 + koff1];
        krreg = *(const u16x8*)&kr[(s0k + rrow) * 64 + roff];
        vreg0 = *(const u16x8*)&vtp[(long)vdv0 * 1024 + s0k + voff0];
        vreg1 = *(const u16x8*)&vtp[(long)vdv1 * 1024 + s0k + voff1];
    };

    const long cbase = ((long)(h * 8 + qb)) * 16 * 896;
    float4 cva0, cvb0, cva1, cvb1;
    const int gi0 = tid;
    const int gi1 = 512 + tid;
    auto conv_load = [&](int kt) {
        long g0 = cbase + (long)kt * 896;
        long a0 = (g0 + gi0) * 8;
        cva0 = *(const float4*)(wsrc + a0);
        cvb0 = *(const float4*)(wsrc + a0 + 4);
        if (gi1 < 896) {
            long a1 = (g0 + gi1) * 8;
            cva1 = *(const float4*)(wsrc + a1);
            cvb1 = *(const float4*)(wsrc + a1 + 4);
        }
    };
    auto conv_store = [&](int kt) {
        long g0 = cbase + (long)kt * 896;
        u16x8 o;
        o[0] = f2bf(cva0.x); o[1] = f2bf(cva0.y); o[2] = f2bf(cva0.z); o[3] = f2bf(cva0.w);
        o[4] = f2bf(cvb0.x); o[5] = f2bf(cvb0.y); o[6] = f2bf(cvb0.z); o[7] = f2bf(cvb0.w);
        *(u16x8*)(wdst + (g0 + gi0) * 8) = o;
        if (gi1 < 896) {
            u16x8 o1;
            o1[0] = f2bf(cva1.x); o1[1] = f2bf(cva1.y); o1[2] = f2bf(cva1.z); o1[3] = f2bf(cva1.w);
            o1[4] = f2bf(cvb1.x); o1[5] = f2bf(cvb1.y); o1[6] = f2bf(cvb1.z); o1[7] = f2bf(cvb1.w);
            *(u16x8*)(wdst + (g0 + gi1) * 8) = o1;
        }
    };

    f32x4 o_acc[8];
    const f32x4 z = {0.f, 0.f, 0.f, 0.f};
#pragma unroll
    for (int d = 0; d < 8; ++d) o_acc[d] = z;
    float m_r[4], l_r[4];
#pragma unroll
    for (int r = 0; r < 4; ++r) { m_r[r] = -1e30f; l_r[r] = 0.f; }

    load_tile(0);
    if (do_conv) conv_load(0);

    for (int kt = 0; kt < 16; ++kt) {
        __syncthreads();
        *(u16x8*)&ks[krow0][koff0]      = kreg0;
        *(u16x8*)&ks[krow1][koff1]      = kreg1;
        *(u16x8*)&ks[rrow][128 + roff]  = krreg;
        *(u16x8*)&vts[vdv0][voff0]      = vreg0;
        *(u16x8*)&vts[vdv1][voff1]      = vreg1;
        __syncthreads();
        if (kt + 1 < 16) load_tile((kt + 1) * 64);

        if (do_conv) {
            conv_store(kt);
            if (kt + 1 < 16) conv_load(kt + 1);
        }

        // QK^T
        f32x4 sf[4];
#pragma unroll
        for (int j = 0; j < 4; ++j) sf[j] = z;
        __builtin_amdgcn_s_setprio(1);
#pragma unroll
        for (int kk = 0; kk < 6; ++kk) {
            bf16x8 a = qreg[kk];
#pragma unroll
            for (int j = 0; j < 4; ++j) {
                bf16x8 b = *(const bf16x8*)&ks[j * 16 + l15][kk * 32 + lg * 8];
                sf[j] = __builtin_amdgcn_mfma_f32_16x16x32_bf16(a, b, sf[j], 0, 0, 0);
            }
        }
        __builtin_amdgcn_s_setprio(0);

        // online softmax
        float p[4][4];
        float alpha[4];
#pragma unroll
        for (int r = 0; r < 4; ++r) {
            float mx = fmaxf(fmaxf(sf[0][r], sf[1][r]), fmaxf(sf[2][r], sf[3][r]));
#pragma unroll
            for (int off = 1; off < 16; off <<= 1) mx = fmaxf(mx, __shfl_xor(mx, off));
            mx *= scale;
            float mnew = fmaxf(m_r[r], mx);
            alpha[r] = __expf(m_r[r] - mnew);
            float rs = 0.f;
#pragma unroll
            for (int j = 0; j < 4; ++j) {
                float pv = __expf(sf[j][r] * scale - mnew);
                p[j][r] = pv;
                rs += pv;
            }
#pragma unroll
            for (int off = 1; off < 16; off <<= 1) rs += __shfl_xor(rs, off);
            l_r[r] = l_r[r] * alpha[r] + rs;
            m_r[r] = mnew;
        }
#pragma unroll
        for (int d = 0; d < 8; ++d)
#pragma unroll
            for (int r = 0; r < 4; ++r) o_acc[d][r] *= alpha[r];

        // P -> LDS (wave-private)
#pragma unroll
        for (int j = 0; j < 4; ++j)
#pragma unroll
            for (int r = 0; r < 4; ++r)
                p_lds[w][lg * 4 + r][j * 16 + l15] = f2bf(p[j][r]);

        // PV
        __builtin_amdgcn_s_setprio(1);
#pragma unroll
        for (int kk2 = 0; kk2 < 2; ++kk2) {
            bf16x8 a = *(const bf16x8*)&p_lds[w][l15][kk2 * 32 + lg * 8];
#pragma unroll
            for (int d = 0; d < 8; ++d) {
                bf16x8 b = *(const bf16x8*)&vts[d * 16 + l15][kk2 * 32 + lg * 8];
                o_acc[d] = __builtin_amdgcn_mfma_f32_16x16x32_bf16(a, b, o_acc[d], 0, 0, 0);
            }
        }
        __builtin_amdgcn_s_setprio(0);
    }

#pragma unroll
    for (int d = 0; d < 8; ++d)
#pragma unroll
        for (int r = 0; r < 4; ++r) {
            int srow = s0q + w * 16 + lg * 4 + r;
            float v = o_acc[d][r] / l_r[r];
            o_g[srow * 16384 + h * 128 + d * 16 + l15] = f2bf(v);
        }
}

// ---------------- host launcher ----------------
extern "C" void kernel_launch(void* const* d_in, const int* in_sizes, int n_in,
                              void* d_out, int out_size, void* d_ws, size_t ws_size,
                              hipStream_t stream) {
    const float* hs        = (const float*)d_in[0];
    const float* w_q_down  = (const float*)d_in[1];
    const float* q_norm_w  = (const float*)d_in[2];
    const float* w_q_up    = (const float*)d_in[3];
    const float* w_kv_down = (const float*)d_in[4];
    const float* kv_norm_w = (const float*)d_in[5];
    const float* w_kv_up   = (const float*)d_in[6];
    const float* w_out     = (const float*)d_in[7];
    float* out = (float*)d_out;
    char* ws = (char*)d_ws;

    // ---- layout: live-at-attention set first; all weight bf16 buffers
    // (each distinct) + intermediates live inside the wout region (dead by
    // the time attention overwrites it with wout_bf). ----
    const size_t SZ_KV   = (size_t)SEQ * 32768 * 2;
    const size_t SZ_QCR  = (size_t)SEQ * (NHEAD * 192) * 2;
    const size_t SZ_KR   = (size_t)SEQ * 64 * 2;
    const size_t SZ_TAB  = (size_t)SEQ * 32 * 4;
    const size_t SZ_VT   = (size_t)NHEAD * 128 * 1024 * 2;
    const size_t SZ_OG   = (size_t)SEQ * 16384 * 2;
    const size_t SZ_WOUT = (size_t)HIDN * 16384 * 2;          // 234.9 MB
    const size_t SZ_WQD  = (size_t)QLRANK * HIDN * 2;         // 22 MB
    const size_t SZ_WQU  = (size_t)24576 * QLRANK * 2;        // 75.5 MB
    const size_t SZ_WKD  = (size_t)576 * HIDN * 2;            // 8.3 MB
    const size_t SZ_WKU  = (size_t)32768 * KVLRANK * 2;       // 33.6 MB
    const size_t SZ_PART = (size_t)4 * SEQ * QLRANK * 4;      // 25.2 MB
    const size_t SZ_HS   = (size_t)SEQ * HIDN * 2;
    const size_t SZ_CQ   = (size_t)SEQ * QLRANK * 4;
    const size_t SZ_CQN  = (size_t)SEQ * QLRANK * 2;
    const size_t SZ_CKV  = (size_t)SEQ * 576 * 4;
    const size_t SZ_CKVN = (size_t)SEQ * KVLRANK * 2;

    size_t off = 0;
    u16* kvb     = (u16*)(ws + off); off += SZ_KV;
    u16* q_cr    = (u16*)(ws + off); off += SZ_QCR;
    u16* kr      = (u16*)(ws + off); off += SZ_KR;
    float* cos_t = (float*)(ws + off); off += SZ_TAB;
    float* sin_t = (float*)(ws + off); off += SZ_TAB;
    u16* vT      = (u16*)(ws + off); off += SZ_VT;
    u16* o_g     = (u16*)(ws + off); off += SZ_OG;
    const size_t live_end = off;                     // ~184.9 MB
    u16* wout_bf = (u16*)(ws + live_end);
    // scratch inside wout region (dead before attention):
    size_t toff = live_end;
    u16* wqd_bf  = (u16*)(ws + toff); toff += SZ_WQD;
    u16* wqu_bf  = (u16*)(ws + toff); toff += SZ_WQU;
    u16* wkd_bf  = (u16*)(ws + toff); toff += SZ_WKD;
    u16* wku_bf  = (u16*)(ws + toff); toff += SZ_WKU;
    float* parts = (float*)(ws + toff); toff += SZ_PART;
    u16* hs_bf    = (u16*)(ws + toff); toff += SZ_HS;
    float* c_q    = (float*)(ws + toff); toff += SZ_CQ;
    u16* cq_n     = (u16*)(ws + toff); toff += SZ_CQN;
    float* ckv_kr = (float*)(ws + toff); toff += SZ_CKV;
    u16* ckv_n    = (u16*)(ws + toff); toff += SZ_CKVN;
    const int fuse = (live_end + SZ_WOUT) <= ws_size;
    (void)in_sizes; (void)n_in; (void)out_size;

    rope_tables<<<dim3(SEQ), dim3(32), 0, stream>>>(cos_t, sin_t);
    f32_to_bf16<<<2048, 256, 0, stream>>>(hs, hs_bf, (long)SEQ * HIDN);

    // c_q = hs @ w_q_down^T   (split-K x4) + fused conversion of w_q_up
    f32_to_bf16<<<2048, 256, 0, stream>>>(w_q_down, wqd_bf, (long)QLRANK * HIDN);
    gemm_bt<0, 1><<<dim3(QLRANK / 128, SEQ / 128, 4), 512, 0, stream>>>(
        hs_bf, wqd_bf, parts, SEQ, QLRANK, HIDN / 4, HIDN,
        w_q_up, wqu_bf, ((long)24576 * QLRANK) / 8);
    reduce_parts<<<1024, 256, 0, stream>>>(parts, c_q, 4, (long)SEQ * QLRANK);
    rmsnorm_kernel<<<SEQ, 256, 0, stream>>>(c_q, q_norm_w, cq_n, QLRANK, QLRANK);

    // q_cr = rmsnorm(c_q) @ w_q_up^T + fused conversion of w_kv_up
    gemm_bt<1, 1><<<dim3(24576 / 128, SEQ / 128), 512, 0, stream>>>(
        cq_n, wqu_bf, q_cr, SEQ, 24576, QLRANK, QLRANK,
        w_kv_up, wku_bf, ((long)32768 * KVLRANK) / 8);

    // ckv_kr = hs @ w_kv_down^T   (split-K x8; N=576 ragged)
    f32_to_bf16<<<2048, 256, 0, stream>>>(w_kv_down, wkd_bf, (long)576 * HIDN);
    gemm_bt<0, 0><<<dim3(5, SEQ / 128, 8), 512, 0, stream>>>(
        hs_bf, wkd_bf, parts, SEQ, 576, HIDN / 8, HIDN, nullptr, nullptr, 0);
    reduce_parts<<<1024, 256, 0, stream>>>(parts, ckv_kr, 8, (long)SEQ * 576);
    rmsnorm_kernel<<<SEQ, 256, 0, stream>>>(ckv_kr, kv_norm_w, ckv_n, 576, KVLRANK);
    rope_k<<<SEQ, 64, 0, stream>>>(ckv_kr, cos_t, sin_t, kr);

    // kv = rmsnorm(c_kv) @ w_kv_up^T
    gemm_bt<1, 0><<<dim3(32768 / 128, SEQ / 128), 512, 0, stream>>>(
        ckv_n, wku_bf, kvb, SEQ, 32768, KVLRANK, KVLRANK, nullptr, nullptr, 0);

    rope_q<<<dim3(SEQ, NHEAD / 2), 64, 0, stream>>>(q_cr, cos_t, sin_t);
    build_vt<<<dim3(NHEAD, SEQ / 64), 256, 0, stream>>>(kvb, vT);

    // attention; convert w_out under attention's idle BW
    if (!fuse)
        f32_to_bf16<<<4096, 256, 0, stream>>>(w_out, wout_bf, (long)HIDN * 16384);
    mla_attn<<<dim3(SEQ / 128, NHEAD), 512, 0, stream>>>(q_cr, kvb, kr, vT, o_g,
                                                         w_out, wout_bf, fuse ? 1 : 0);

    // out = o @ w_out^T
    gemm_bt<0, 0><<<dim3(HIDN / 128, SEQ / 128), 512, 0, stream>>>(
        o_g, wout_bf, out, SEQ, HIDN, 16384, 16384, nullptr, nullptr, 0);
}

// Round 20
// 886.766 us; speedup vs baseline: 1.2025x; 1.0120x over previous
//
#include <hip/hip_runtime.h>
#include <hip/hip_bf16.h>
#include <math.h>

// ---- problem constants ----
#define HIDN 7168
#define NHEAD 128
#define QLRANK 1536
#define KVLRANK 512
#define QKD 128
#define VHD 128
#define RHD 64
#define SEQ 1024
#define RMS_EPS 1.1920929e-07f

typedef unsigned short u16;
typedef __attribute__((ext_vector_type(8))) short bf16x8;
typedef __attribute__((ext_vector_type(4))) float f32x4;
typedef __attribute__((ext_vector_type(8))) unsigned short u16x8;

__device__ __forceinline__ u16 f2bf(float f) {
    unsigned int u = __float_as_uint(f);
    unsigned int r = (u + 0x7FFFu + ((u >> 16) & 1u)) >> 16;
    return (u16)r;
}
__device__ __forceinline__ float bf2f(u16 v) {
    return __uint_as_float(((unsigned int)v) << 16);
}

// async global->LDS, 16B per lane. LDS dest is wave-uniform base + lane*16.
__device__ __forceinline__ void gld_lds16(const u16* g, u16* l) {
    __builtin_amdgcn_global_load_lds(
        (const __attribute__((address_space(1))) unsigned int*)g,
        (__attribute__((address_space(3))) unsigned int*)l,
        16, 0, 0);
}

// ---------------- fused 3-way fp32 -> bf16 conversion ----------------
__global__ __launch_bounds__(256) void conv3(const float* __restrict__ s0, u16* __restrict__ d0, long n0,
                                             const float* __restrict__ s1, u16* __restrict__ d1, long n1,
                                             const float* __restrict__ s2, u16* __restrict__ d2, long n2) {
    const long stride = (long)gridDim.x * blockDim.x * 8;
#pragma unroll 1
    for (int seg = 0; seg < 3; ++seg) {
        const float* s = seg == 0 ? s0 : (seg == 1 ? s1 : s2);
        u16* d        = seg == 0 ? d0 : (seg == 1 ? d1 : d2);
        long n        = seg == 0 ? n0 : (seg == 1 ? n1 : n2);
        for (long i = ((long)blockIdx.x * blockDim.x + threadIdx.x) * 8; i < n; i += stride) {
            float4 a = *(const float4*)(s + i);
            float4 b = *(const float4*)(s + i + 4);
            u16x8 o;
            o[0] = f2bf(a.x); o[1] = f2bf(a.y); o[2] = f2bf(a.z); o[3] = f2bf(a.w);
            o[4] = f2bf(b.x); o[5] = f2bf(b.y); o[6] = f2bf(b.z); o[7] = f2bf(b.w);
            *(u16x8*)(d + i) = o;
        }
    }
}

// ---------------- single fp32 -> bf16 conversion (fallback path) ----------------
__global__ __launch_bounds__(256) void f32_to_bf16(const float* __restrict__ in,
                                                   u16* __restrict__ out, long n) {
    long i = ((long)blockIdx.x * blockDim.x + threadIdx.x) * 8;
    long stride = (long)gridDim.x * blockDim.x * 8;
    for (; i < n; i += stride) {
        float4 a = *(const float4*)(in + i);
        float4 b = *(const float4*)(in + i + 4);
        u16x8 o;
        o[0] = f2bf(a.x); o[1] = f2bf(a.y); o[2] = f2bf(a.z); o[3] = f2bf(a.w);
        o[4] = f2bf(b.x); o[5] = f2bf(b.y); o[6] = f2bf(b.z); o[7] = f2bf(b.w);
        *(u16x8*)(out + i) = o;
    }
}

// ---------------- generic GEMM (r10-proven) + optional fused side-conversion ----------------
// 128x128 tile, BK=64, 8 waves, 64 KiB LDS dbuf -> 2 WG/CU, 4 waves/SIMD TLP.
// One vmcnt(0)+s_barrier per K-step. FCONV: double-buffered fp32->bf16 side
// conversion of an unrelated weight (r18/r19-proven). Split-K via blockIdx.z.
template <int OUT_BF16, int FCONV>
__global__ __launch_bounds__(512) void gemm_bt(const u16* __restrict__ A,
                                               const u16* __restrict__ B,
                                               void* __restrict__ Cv,
                                               int M, int N, int Kslice, long ldk,
                                               const float* __restrict__ cvsrc,
                                               u16* __restrict__ cvdst,
                                               long cvtotal) {
    __shared__ u16 As[2 * 128 * 64];
    __shared__ u16 Bs[2 * 128 * 64];
    const int tid = threadIdx.x;
    const int lane = tid & 63;
    const int w = tid >> 6;
    const int wr = w >> 2, wc = w & 3;
    const int l15 = lane & 15, lg = lane >> 4;
    const int n0 = blockIdx.x * 128;
    const int m0 = blockIdx.y * 128;
    const long kbase = (long)blockIdx.z * Kslice;

    const u16* asrc[2];
    const u16* bsrc[2];
    int aoff[2];
#pragma unroll
    for (int i = 0; i < 2; ++i) {
        int r = (w * 2 + i) * 8 + (lane >> 3);
        int gc = (lane & 7) ^ (r & 7);
        asrc[i] = A + (long)(m0 + r) * ldk + kbase + gc * 8;
        int br = n0 + r; if (br >= N) br = N - 1;
        bsrc[i] = B + (long)br * ldk + kbase + gc * 8;
        aoff[i] = (w * 2 + i) * 512;
    }

    long gbase = 0, gend = 0;
    int nwin = 0;
    float4 cva, cvb;
    long gprev = -1;
    if (FCONV) {
        const int nblocks = gridDim.x * gridDim.y * gridDim.z;
        const int bl = (blockIdx.z * gridDim.y + blockIdx.y) * gridDim.x + blockIdx.x;
        long share = (cvtotal + nblocks - 1) / nblocks;
        gbase = (long)bl * share;
        gend = gbase + share; if (gend > cvtotal) gend = cvtotal;
        nwin = (int)((share + 511) >> 9);
    }

    f32x4 acc[4][2];
    const f32x4 z = {0.f, 0.f, 0.f, 0.f};
#pragma unroll
    for (int i = 0; i < 4; ++i)
#pragma unroll
        for (int j = 0; j < 2; ++j) acc[i][j] = z;

    auto stage = [&](int bufi, int kofs) {
#pragma unroll
        for (int i = 0; i < 2; ++i) {
            gld_lds16(asrc[i] + kofs, As + bufi * 8192 + aoff[i]);
            gld_lds16(bsrc[i] + kofs, Bs + bufi * 8192 + aoff[i]);
        }
    };

    const int nsteps = Kslice >> 6;
    stage(0, 0);
    asm volatile("s_waitcnt vmcnt(0)" ::: "memory");
    __builtin_amdgcn_s_barrier();

    int cur = 0;
    for (int t = 0; t < nsteps; ++t) {
        if (t + 1 < nsteps) stage(cur ^ 1, (t + 1) * 64);
        if (FCONV) {
            if (gprev >= 0) {
                u16x8 o;
                o[0] = f2bf(cva.x); o[1] = f2bf(cva.y); o[2] = f2bf(cva.z); o[3] = f2bf(cva.w);
                o[4] = f2bf(cvb.x); o[5] = f2bf(cvb.y); o[6] = f2bf(cvb.z); o[7] = f2bf(cvb.w);
                *(u16x8*)(cvdst + gprev * 8) = o;
            }
            gprev = -1;
            if (t < nwin) {
                long g = gbase + (long)t * 512 + tid;
                if (g < gend) {
                    cva = *(const float4*)(cvsrc + g * 8);
                    cvb = *(const float4*)(cvsrc + g * 8 + 4);
                    gprev = g;
                }
            }
        }
        const u16* Ab = As + cur * 8192;
        const u16* Bb = Bs + cur * 8192;
#pragma unroll
        for (int kk = 0; kk < 2; ++kk) {
            bf16x8 a[4], b[2];
#pragma unroll
            for (int i = 0; i < 4; ++i) {
                int row = wr * 64 + i * 16 + l15;
                a[i] = *(const bf16x8*)&Ab[row * 64 + ((kk * 4 + lg) ^ (row & 7)) * 8];
            }
#pragma unroll
            for (int j = 0; j < 2; ++j) {
                int row = wc * 32 + j * 16 + l15;
                b[j] = *(const bf16x8*)&Bb[row * 64 + ((kk * 4 + lg) ^ (row & 7)) * 8];
            }
#pragma unroll
            for (int i = 0; i < 4; ++i)
#pragma unroll
                for (int j = 0; j < 2; ++j)
                    acc[i][j] = __builtin_amdgcn_mfma_f32_16x16x32_bf16(a[i], b[j], acc[i][j], 0, 0, 0);
        }
        asm volatile("s_waitcnt vmcnt(0)" ::: "memory");
        __builtin_amdgcn_s_barrier();
        cur ^= 1;
    }
    if (FCONV && gprev >= 0) {
        u16x8 o;
        o[0] = f2bf(cva.x); o[1] = f2bf(cva.y); o[2] = f2bf(cva.z); o[3] = f2bf(cva.w);
        o[4] = f2bf(cvb.x); o[5] = f2bf(cvb.y); o[6] = f2bf(cvb.z); o[7] = f2bf(cvb.w);
        *(u16x8*)(cvdst + gprev * 8) = o;
    }

#pragma unroll
    for (int i = 0; i < 4; ++i)
#pragma unroll
        for (int j = 0; j < 2; ++j)
#pragma unroll
            for (int r = 0; r < 4; ++r) {
                int m = m0 + wr * 64 + i * 16 + lg * 4 + r;
                int n = n0 + wc * 32 + j * 16 + l15;
                if (n < N) {
                    if (OUT_BF16)
                        ((u16*)Cv)[(long)m * N + n] = f2bf(acc[i][j][r]);
                    else
                        ((float*)Cv)[(long)blockIdx.z * M * N + (long)m * N + n] = acc[i][j][r];
                }
            }
}

// ---------------- fused reduce x4 + RMSNorm (c_q chain) ----------------
// parts[z][row][0..1536) summed in registers (6 f32/thread), ss reduced
// across the block, bf16 normed row written directly.
__global__ __launch_bounds__(256) void reduce_rms_cq(const float* __restrict__ parts,
                                                     const float* __restrict__ wnorm,
                                                     u16* __restrict__ y) {
    const int row = blockIdx.x;
    const long mn = (long)SEQ * QLRANK;
    const float* base = parts + (long)row * QLRANK;
    float v[6];
    float ss = 0.f;
#pragma unroll
    for (int i = 0; i < 6; ++i) {
        int col = i * 256 + threadIdx.x;
        float s = base[col];
#pragma unroll
        for (int p = 1; p < 4; ++p) s += base[(long)p * mn + col];
        v[i] = s;
        ss += s * s;
    }
#pragma unroll
    for (int off = 32; off > 0; off >>= 1) ss += __shfl_down(ss, off);
    __shared__ float partial[4];
    if ((threadIdx.x & 63) == 0) partial[threadIdx.x >> 6] = ss;
    __syncthreads();
    float tot = partial[0] + partial[1] + partial[2] + partial[3];
    float rs = 1.0f / sqrtf(tot / (float)QLRANK + RMS_EPS);
    u16* yr = y + (long)row * QLRANK;
#pragma unroll
    for (int i = 0; i < 6; ++i) {
        int col = i * 256 + threadIdx.x;
        yr[col] = f2bf(v[i] * rs * wnorm[col]);
    }
}

// ---------------- fused reduce x8 + RMSNorm + RoPE-k (ckv chain) ----------------
// parts[z][row][0..576): cols<512 -> rmsnorm bf16; cols 512..575 -> rope -> kr.
__global__ __launch_bounds__(256) void reduce_rms_rope_kv(const float* __restrict__ parts,
                                                          const float* __restrict__ wnorm,
                                                          u16* __restrict__ y,
                                                          const float* __restrict__ cos_t,
                                                          const float* __restrict__ sin_t,
                                                          u16* __restrict__ kr) {
    const int row = blockIdx.x;
    const long mn = (long)SEQ * 576;
    const float* base = parts + (long)row * 576;
    __shared__ float rope_buf[64];
    __shared__ float partial[4];
    float v[3];
    float ss = 0.f;
#pragma unroll
    for (int i = 0; i < 3; ++i) {
        int col = i * 256 + threadIdx.x;
        if (col < 576) {
            float s = base[col];
#pragma unroll
            for (int p = 1; p < 8; ++p) s += base[(long)p * mn + col];
            v[i] = s;
            if (col < KVLRANK) ss += s * s;
            else rope_buf[col - KVLRANK] = s;
        }
    }
#pragma unroll
    for (int off = 32; off > 0; off >>= 1) ss += __shfl_down(ss, off);
    if ((threadIdx.x & 63) == 0) partial[threadIdx.x >> 6] = ss;
    __syncthreads();
    float tot = partial[0] + partial[1] + partial[2] + partial[3];
    float rs = 1.0f / sqrtf(tot / (float)KVLRANK + RMS_EPS);
    u16* yr = y + (long)row * KVLRANK;
#pragma unroll
    for (int i = 0; i < 3; ++i) {
        int col = i * 256 + threadIdx.x;
        if (col < KVLRANK) yr[col] = f2bf(v[i] * rs * wnorm[col]);
    }
    // rope on cols 512..575 (threads 0..31)
    if (threadIdx.x < 32) {
        float x1 = rope_buf[threadIdx.x];
        float x2 = rope_buf[threadIdx.x + 32];
        float c = cos_t[row * 32 + threadIdx.x], sn = sin_t[row * 32 + threadIdx.x];
        kr[row * 64 + threadIdx.x]      = f2bf(x1 * c - x2 * sn);
        kr[row * 64 + threadIdx.x + 32] = f2bf(x2 * c + x1 * sn);
    }
}

// ---------------- RoPE tables ----------------
__global__ void rope_tables(float* __restrict__ cos_t, float* __restrict__ sin_t) {
    int s = blockIdx.x;
    int i = threadIdx.x;
    float invf = powf(10000.0f, -((float)(2 * i) / 64.0f));
    float ang = (float)s * invf;
    cos_t[s * 32 + i] = cosf(ang);
    sin_t[s * 32 + i] = sinf(ang);
}

// ---------------- RoPE on q_r ----------------
__global__ void rope_q(u16* __restrict__ q_cr, const float* __restrict__ cos_t,
                       const float* __restrict__ sin_t) {
    int s = blockIdx.x;
    int h = blockIdx.y * 2 + (threadIdx.x >> 5);
    int i = threadIdx.x & 31;
    u16* base = q_cr + (s * (NHEAD * 192) + h * 192 + QKD);
    float x1 = bf2f(base[i]);
    float x2 = bf2f(base[i + 32]);
    float c = cos_t[s * 32 + i], sn = sin_t[s * 32 + i];
    base[i]      = f2bf(x1 * c - x2 * sn);
    base[i + 32] = f2bf(x2 * c + x1 * sn);
}

// ---------------- build vT[h][dv][s] from kv[s][h*256+128+dv] ----------------
__global__ __launch_bounds__(256) void build_vt(const u16* __restrict__ kv,
                                                u16* __restrict__ vT) {
    __shared__ u16 vtile[64][136];
    const int h = blockIdx.x, sb = blockIdx.y, s0 = sb * 64;
    const int tid = threadIdx.x;
#pragma unroll
    for (int it = 0; it < 4; ++it) {
        int c = it * 256 + tid;
        int row = c >> 4;
        int off8 = (c & 15) * 8;
        *(u16x8*)&vtile[row][off8] =
            *(const u16x8*)&kv[(s0 + row) * 32768 + h * 256 + 128 + off8];
    }
    __syncthreads();
    const int sl = tid & 63;
    const int dvb = tid >> 6;
#pragma unroll
    for (int it = 0; it < 32; ++it) {
        int dv = dvb + it * 4;
        vT[(h * 128 + dv) * 1024 + s0 + sl] = vtile[sl][dv];
    }
}

// ---------------- flash attention + double-buffered fused w_out conversion ----------------
__global__ __launch_bounds__(512) void mla_attn(const u16* __restrict__ q_cr,
                                                const u16* __restrict__ kv,
                                                const u16* __restrict__ kr,
                                                const u16* __restrict__ vT,
                                                u16* __restrict__ o_g,
                                                const float* __restrict__ wsrc,
                                                u16* __restrict__ wdst,
                                                int do_conv) {
    __shared__ u16 ks[64][200];
    __shared__ u16 vts[128][72];
    __shared__ u16 p_lds[8][16][68];
    const int qb = blockIdx.x, h = blockIdx.y;
    const int s0q = qb * 128;
    const int tid = threadIdx.x, lane = tid & 63, w = tid >> 6;
    const int l15 = lane & 15, lg = lane >> 4;
    const float scale = 0.07216878364870323f;

    bf16x8 qreg[6];
    {
        const int qrow = s0q + w * 16 + l15;
#pragma unroll
        for (int kk = 0; kk < 6; ++kk)
            qreg[kk] = *(const bf16x8*)&q_cr[qrow * (NHEAD * 192) + h * 192 + kk * 32 + lg * 8];
    }

    const int krow0 = tid >> 4,           koff0 = (tid & 15) * 8;
    const int krow1 = (512 + tid) >> 4,   koff1 = ((512 + tid) & 15) * 8;
    const int rrow  = tid >> 3,           roff  = (tid & 7) * 8;
    const int vdv0  = tid >> 3,           voff0 = (tid & 7) * 8;
    const int vdv1  = (512 + tid) >> 3,   voff1 = ((512 + tid) & 7) * 8;
    const u16* kvp = kv + h * 256;
    const u16* vtp = vT + (long)(h * 128) * 1024;

    u16x8 kreg0, kreg1, krreg, vreg0, vreg1;
    auto load_tile = [&](int s0k) {
        kreg0 = *(const u16x8*)&kvp[(long)(s0k + krow0) * 32768 + koff0];
        kreg1 = *(const u16x8*)&kvp[(long)(s0k + krow1) * 32768 + koff1];
        krreg = *(const u16x8*)&kr[(s0k + rrow) * 64 + roff];
        vreg0 = *(const u16x8*)&vtp[(long)vdv0 * 1024 + s0k + voff0];
        vreg1 = *(const u16x8*)&vtp[(long)vdv1 * 1024 + s0k + voff1];
    };

    const long cbase = ((long)(h * 8 + qb)) * 16 * 896;
    float4 cva0, cvb0, cva1, cvb1;
    const int gi0 = tid;
    const int gi1 = 512 + tid;
    auto conv_load = [&](int kt) {
        long g0 = cbase + (long)kt * 896;
        long a0 = (g0 + gi0) * 8;
        cva0 = *(const float4*)(wsrc + a0);
        cvb0 = *(const float4*)(wsrc + a0 + 4);
        if (gi1 < 896) {
            long a1 = (g0 + gi1) * 8;
            cva1 = *(const float4*)(wsrc + a1);
            cvb1 = *(const float4*)(wsrc + a1 + 4);
        }
    };
    auto conv_store = [&](int kt) {
        long g0 = cbase + (long)kt * 896;
        u16x8 o;
        o[0] = f2bf(cva0.x); o[1] = f2bf(cva0.y); o[2] = f2bf(cva0.z); o[3] = f2bf(cva0.w);
        o[4] = f2bf(cvb0.x); o[5] = f2bf(cvb0.y); o[6] = f2bf(cvb0.z); o[7] = f2bf(cvb0.w);
        *(u16x8*)(wdst + (g0 + gi0) * 8) = o;
        if (gi1 < 896) {
            u16x8 o1;
            o1[0] = f2bf(cva1.x); o1[1] = f2bf(cva1.y); o1[2] = f2bf(cva1.z); o1[3] = f2bf(cva1.w);
            o1[4] = f2bf(cvb1.x); o1[5] = f2bf(cvb1.y); o1[6] = f2bf(cvb1.z); o1[7] = f2bf(cvb1.w);
            *(u16x8*)(wdst + (g0 + gi1) * 8) = o1;
        }
    };

    f32x4 o_acc[8];
    const f32x4 z = {0.f, 0.f, 0.f, 0.f};
#pragma unroll
    for (int d = 0; d < 8; ++d) o_acc[d] = z;
    float m_r[4], l_r[4];
#pragma unroll
    for (int r = 0; r < 4; ++r) { m_r[r] = -1e30f; l_r[r] = 0.f; }

    load_tile(0);
    if (do_conv) conv_load(0);

    for (int kt = 0; kt < 16; ++kt) {
        __syncthreads();
        *(u16x8*)&ks[krow0][koff0]      = kreg0;
        *(u16x8*)&ks[krow1][koff1]      = kreg1;
        *(u16x8*)&ks[rrow][128 + roff]  = krreg;
        *(u16x8*)&vts[vdv0][voff0]      = vreg0;
        *(u16x8*)&vts[vdv1][voff1]      = vreg1;
        __syncthreads();
        if (kt + 1 < 16) load_tile((kt + 1) * 64);

        if (do_conv) {
            conv_store(kt);
            if (kt + 1 < 16) conv_load(kt + 1);
        }

        // QK^T
        f32x4 sf[4];
#pragma unroll
        for (int j = 0; j < 4; ++j) sf[j] = z;
        __builtin_amdgcn_s_setprio(1);
#pragma unroll
        for (int kk = 0; kk < 6; ++kk) {
            bf16x8 a = qreg[kk];
#pragma unroll
            for (int j = 0; j < 4; ++j) {
                bf16x8 b = *(const bf16x8*)&ks[j * 16 + l15][kk * 32 + lg * 8];
                sf[j] = __builtin_amdgcn_mfma_f32_16x16x32_bf16(a, b, sf[j], 0, 0, 0);
            }
        }
        __builtin_amdgcn_s_setprio(0);

        // online softmax
        float p[4][4];
        float alpha[4];
#pragma unroll
        for (int r = 0; r < 4; ++r) {
            float mx = fmaxf(fmaxf(sf[0][r], sf[1][r]), fmaxf(sf[2][r], sf[3][r]));
#pragma unroll
            for (int off = 1; off < 16; off <<= 1) mx = fmaxf(mx, __shfl_xor(mx, off));
            mx *= scale;
            float mnew = fmaxf(m_r[r], mx);
            alpha[r] = __expf(m_r[r] - mnew);
            float rs = 0.f;
#pragma unroll
            for (int j = 0; j < 4; ++j) {
                float pv = __expf(sf[j][r] * scale - mnew);
                p[j][r] = pv;
                rs += pv;
            }
#pragma unroll
            for (int off = 1; off < 16; off <<= 1) rs += __shfl_xor(rs, off);
            l_r[r] = l_r[r] * alpha[r] + rs;
            m_r[r] = mnew;
        }
#pragma unroll
        for (int d = 0; d < 8; ++d)
#pragma unroll
            for (int r = 0; r < 4; ++r) o_acc[d][r] *= alpha[r];

        // P -> LDS (wave-private)
#pragma unroll
        for (int j = 0; j < 4; ++j)
#pragma unroll
            for (int r = 0; r < 4; ++r)
                p_lds[w][lg * 4 + r][j * 16 + l15] = f2bf(p[j][r]);

        // PV
        __builtin_amdgcn_s_setprio(1);
#pragma unroll
        for (int kk2 = 0; kk2 < 2; ++kk2) {
            bf16x8 a = *(const bf16x8*)&p_lds[w][l15][kk2 * 32 + lg * 8];
#pragma unroll
            for (int d = 0; d < 8; ++d) {
                bf16x8 b = *(const bf16x8*)&vts[d * 16 + l15][kk2 * 32 + lg * 8];
                o_acc[d] = __builtin_amdgcn_mfma_f32_16x16x32_bf16(a, b, o_acc[d], 0, 0, 0);
            }
        }
        __builtin_amdgcn_s_setprio(0);
    }

#pragma unroll
    for (int d = 0; d < 8; ++d)
#pragma unroll
        for (int r = 0; r < 4; ++r) {
            int srow = s0q + w * 16 + lg * 4 + r;
            float v = o_acc[d][r] / l_r[r];
            o_g[srow * 16384 + h * 128 + d * 16 + l15] = f2bf(v);
        }
}

// ---------------- host launcher ----------------
extern "C" void kernel_launch(void* const* d_in, const int* in_sizes, int n_in,
                              void* d_out, int out_size, void* d_ws, size_t ws_size,
                              hipStream_t stream) {
    const float* hs        = (const float*)d_in[0];
    const float* w_q_down  = (const float*)d_in[1];
    const float* q_norm_w  = (const float*)d_in[2];
    const float* w_q_up    = (const float*)d_in[3];
    const float* w_kv_down = (const float*)d_in[4];
    const float* kv_norm_w = (const float*)d_in[5];
    const float* w_kv_up   = (const float*)d_in[6];
    const float* w_out     = (const float*)d_in[7];
    float* out = (float*)d_out;
    char* ws = (char*)d_ws;

    const size_t SZ_KV   = (size_t)SEQ * 32768 * 2;
    const size_t SZ_QCR  = (size_t)SEQ * (NHEAD * 192) * 2;
    const size_t SZ_KR   = (size_t)SEQ * 64 * 2;
    const size_t SZ_TAB  = (size_t)SEQ * 32 * 4;
    const size_t SZ_VT   = (size_t)NHEAD * 128 * 1024 * 2;
    const size_t SZ_OG   = (size_t)SEQ * 16384 * 2;
    const size_t SZ_WOUT = (size_t)HIDN * 16384 * 2;
    const size_t SZ_WQD  = (size_t)QLRANK * HIDN * 2;
    const size_t SZ_WQU  = (size_t)24576 * QLRANK * 2;
    const size_t SZ_WKD  = (size_t)576 * HIDN * 2;
    const size_t SZ_WKU  = (size_t)32768 * KVLRANK * 2;
    const size_t SZ_PART = (size_t)4 * SEQ * QLRANK * 4;
    const size_t SZ_HS   = (size_t)SEQ * HIDN * 2;
    const size_t SZ_CQN  = (size_t)SEQ * QLRANK * 2;
    const size_t SZ_CKVN = (size_t)SEQ * KVLRANK * 2;

    size_t off = 0;
    u16* kvb     = (u16*)(ws + off); off += SZ_KV;
    u16* q_cr    = (u16*)(ws + off); off += SZ_QCR;
    u16* kr      = (u16*)(ws + off); off += SZ_KR;
    float* cos_t = (float*)(ws + off); off += SZ_TAB;
    float* sin_t = (float*)(ws + off); off += SZ_TAB;
    u16* vT      = (u16*)(ws + off); off += SZ_VT;
    u16* o_g     = (u16*)(ws + off); off += SZ_OG;
    const size_t live_end = off;
    u16* wout_bf = (u16*)(ws + live_end);
    size_t toff = live_end;
    u16* wqd_bf  = (u16*)(ws + toff); toff += SZ_WQD;
    u16* wqu_bf  = (u16*)(ws + toff); toff += SZ_WQU;
    u16* wkd_bf  = (u16*)(ws + toff); toff += SZ_WKD;
    u16* wku_bf  = (u16*)(ws + toff); toff += SZ_WKU;
    float* parts = (float*)(ws + toff); toff += SZ_PART;
    u16* hs_bf    = (u16*)(ws + toff); toff += SZ_HS;
    u16* cq_n     = (u16*)(ws + toff); toff += SZ_CQN;
    u16* ckv_n    = (u16*)(ws + toff); toff += SZ_CKVN;
    const int fuse = (live_end + SZ_WOUT) <= ws_size;
    (void)in_sizes; (void)n_in; (void)out_size;

    rope_tables<<<dim3(SEQ), dim3(32), 0, stream>>>(cos_t, sin_t);

    // one kernel converts hs + w_q_down + w_kv_down (all BW-bound)
    conv3<<<2048, 256, 0, stream>>>(hs, hs_bf, (long)SEQ * HIDN,
                                    w_q_down, wqd_bf, (long)QLRANK * HIDN,
                                    w_kv_down, wkd_bf, (long)576 * HIDN);

    // c_q = hs @ w_q_down^T   (split-K x4) + fused conversion of w_q_up
    gemm_bt<0, 1><<<dim3(QLRANK / 128, SEQ / 128, 4), 512, 0, stream>>>(
        hs_bf, wqd_bf, parts, SEQ, QLRANK, HIDN / 4, HIDN,
        w_q_up, wqu_bf, ((long)24576 * QLRANK) / 8);
    reduce_rms_cq<<<SEQ, 256, 0, stream>>>(parts, q_norm_w, cq_n);

    // q_cr = rmsnorm(c_q) @ w_q_up^T + fused conversion of w_kv_up
    gemm_bt<1, 1><<<dim3(24576 / 128, SEQ / 128), 512, 0, stream>>>(
        cq_n, wqu_bf, q_cr, SEQ, 24576, QLRANK, QLRANK,
        w_kv_up, wku_bf, ((long)32768 * KVLRANK) / 8);

    // ckv_kr = hs @ w_kv_down^T   (split-K x8; N=576 ragged)
    gemm_bt<0, 0><<<dim3(5, SEQ / 128, 8), 512, 0, stream>>>(
        hs_bf, wkd_bf, parts, SEQ, 576, HIDN / 8, HIDN, nullptr, nullptr, 0);
    reduce_rms_rope_kv<<<SEQ, 256, 0, stream>>>(parts, kv_norm_w, ckv_n, cos_t, sin_t, kr);

    // kv = rmsnorm(c_kv) @ w_kv_up^T
    gemm_bt<1, 0><<<dim3(32768 / 128, SEQ / 128), 512, 0, stream>>>(
        ckv_n, wku_bf, kvb, SEQ, 32768, KVLRANK, KVLRANK, nullptr, nullptr, 0);

    rope_q<<<dim3(SEQ, NHEAD / 2), 64, 0, stream>>>(q_cr, cos_t, sin_t);
    build_vt<<<dim3(NHEAD, SEQ / 64), 256, 0, stream>>>(kvb, vT);

    // attention; convert w_out under attention's idle BW
    if (!fuse)
        f32_to_bf16<<<4096, 256, 0, stream>>>(w_out, wout_bf, (long)HIDN * 16384);
    mla_attn<<<dim3(SEQ / 128, NHEAD), 512, 0, stream>>>(q_cr, kvb, kr, vT, o_g,
                                                         w_out, wout_bf, fuse ? 1 : 0);

    // out = o @ w_out^T
    gemm_bt<0, 0><<<dim3(HIDN / 128, SEQ / 128), 512, 0, stream>>>(
        o_g, wout_bf, out, SEQ, HIDN, 16384, 16384, nullptr, nullptr, 0);
}

// Round 21
// 866.467 us; speedup vs baseline: 1.2306x; 1.0234x over previous
//
#include <hip/hip_runtime.h>
#include <hip/hip_bf16.h>
#include <math.h>

// ---- problem constants ----
#define HIDN 7168
#define NHEAD 128
#define QLRANK 1536
#define KVLRANK 512
#define QKD 128
#define VHD 128
#define RHD 64
#define SEQ 1024
#define RMS_EPS 1.1920929e-07f

typedef unsigned short u16;
typedef __attribute__((ext_vector_type(8))) short bf16x8;
typedef __attribute__((ext_vector_type(4))) float f32x4;
typedef __attribute__((ext_vector_type(8))) unsigned short u16x8;

__device__ __forceinline__ u16 f2bf(float f) {
    unsigned int u = __float_as_uint(f);
    unsigned int r = (u + 0x7FFFu + ((u >> 16) & 1u)) >> 16;
    return (u16)r;
}
__device__ __forceinline__ float bf2f(u16 v) {
    return __uint_as_float(((unsigned int)v) << 16);
}

// async global->LDS, 16B per lane. LDS dest is wave-uniform base + lane*16.
__device__ __forceinline__ void gld_lds16(const u16* g, u16* l) {
    __builtin_amdgcn_global_load_lds(
        (const __attribute__((address_space(1))) unsigned int*)g,
        (__attribute__((address_space(3))) unsigned int*)l,
        16, 0, 0);
}

// ---------------- fused 2-way fp32 -> bf16 conversion + rope tables ----------------
__global__ __launch_bounds__(256) void conv2_tab(const float* __restrict__ s0, u16* __restrict__ d0, long n0,
                                                 const float* __restrict__ s1, u16* __restrict__ d1, long n1,
                                                 float* __restrict__ cos_t, float* __restrict__ sin_t) {
    // rope tables: blocks 0..1023, lanes 0..31
    if (blockIdx.x < SEQ && threadIdx.x < 32) {
        int s = blockIdx.x, i = threadIdx.x;
        float invf = powf(10000.0f, -((float)(2 * i) / 64.0f));
        float ang = (float)s * invf;
        cos_t[s * 32 + i] = cosf(ang);
        sin_t[s * 32 + i] = sinf(ang);
    }
    const long stride = (long)gridDim.x * blockDim.x * 8;
#pragma unroll 1
    for (int seg = 0; seg < 2; ++seg) {
        const float* s = seg == 0 ? s0 : s1;
        u16* d        = seg == 0 ? d0 : d1;
        long n        = seg == 0 ? n0 : n1;
        for (long i = ((long)blockIdx.x * blockDim.x + threadIdx.x) * 8; i < n; i += stride) {
            float4 a = *(const float4*)(s + i);
            float4 b = *(const float4*)(s + i + 4);
            u16x8 o;
            o[0] = f2bf(a.x); o[1] = f2bf(a.y); o[2] = f2bf(a.z); o[3] = f2bf(a.w);
            o[4] = f2bf(b.x); o[5] = f2bf(b.y); o[6] = f2bf(b.z); o[7] = f2bf(b.w);
            *(u16x8*)(d + i) = o;
        }
    }
}

// ---------------- single fp32 -> bf16 conversion (fallback) ----------------
__global__ __launch_bounds__(256) void f32_to_bf16(const float* __restrict__ in,
                                                   u16* __restrict__ out, long n) {
    long i = ((long)blockIdx.x * blockDim.x + threadIdx.x) * 8;
    long stride = (long)gridDim.x * blockDim.x * 8;
    for (; i < n; i += stride) {
        float4 a = *(const float4*)(in + i);
        float4 b = *(const float4*)(in + i + 4);
        u16x8 o;
        o[0] = f2bf(a.x); o[1] = f2bf(a.y); o[2] = f2bf(a.z); o[3] = f2bf(a.w);
        o[4] = f2bf(b.x); o[5] = f2bf(b.y); o[6] = f2bf(b.z); o[7] = f2bf(b.w);
        *(u16x8*)(out + i) = o;
    }
}

// ---------------- generic GEMM (r10-proven) + optional 2-segment fused conversion ----------------
// 128x128 tile, BK=64, 8 waves, 64 KiB LDS dbuf -> 2 WG/CU, 4 waves/SIMD TLP.
// One vmcnt(0)+s_barrier per K-step. FCONV: double-buffered fp32->bf16 side
// conversion (r18/r19-proven), two logical segments concatenated.
// Split-K via blockIdx.z: fp32 partials at Cv + z*M*N (OUT_BF16=0 only).
template <int OUT_BF16, int FCONV>
__global__ __launch_bounds__(512) void gemm_bt(const u16* __restrict__ A,
                                               const u16* __restrict__ B,
                                               void* __restrict__ Cv,
                                               int M, int N, int Kslice, long ldk,
                                               const float* __restrict__ cvs1,
                                               u16* __restrict__ cvd1, long cvt1,
                                               const float* __restrict__ cvs2,
                                               u16* __restrict__ cvd2, long cvt2) {
    __shared__ u16 As[2 * 128 * 64];
    __shared__ u16 Bs[2 * 128 * 64];
    const int tid = threadIdx.x;
    const int lane = tid & 63;
    const int w = tid >> 6;
    const int wr = w >> 2, wc = w & 3;
    const int l15 = lane & 15, lg = lane >> 4;
    const int n0 = blockIdx.x * 128;
    const int m0 = blockIdx.y * 128;
    const long kbase = (long)blockIdx.z * Kslice;

    const u16* asrc[2];
    const u16* bsrc[2];
    int aoff[2];
#pragma unroll
    for (int i = 0; i < 2; ++i) {
        int r = (w * 2 + i) * 8 + (lane >> 3);
        int gc = (lane & 7) ^ (r & 7);
        asrc[i] = A + (long)(m0 + r) * ldk + kbase + gc * 8;
        int br = n0 + r; if (br >= N) br = N - 1;
        bsrc[i] = B + (long)br * ldk + kbase + gc * 8;
        aoff[i] = (w * 2 + i) * 512;
    }

    long gbase = 0, gend = 0;
    int nwin = 0;
    float4 cva, cvb;
    long gprev = -1;
    if (FCONV) {
        const int nblocks = gridDim.x * gridDim.y * gridDim.z;
        const int bl = (blockIdx.z * gridDim.y + blockIdx.y) * gridDim.x + blockIdx.x;
        long total = cvt1 + cvt2;
        long share = (total + nblocks - 1) / nblocks;
        gbase = (long)bl * share;
        gend = gbase + share; if (gend > total) gend = total;
        nwin = (int)((share + 511) >> 9);
    }

    f32x4 acc[4][2];
    const f32x4 z = {0.f, 0.f, 0.f, 0.f};
#pragma unroll
    for (int i = 0; i < 4; ++i)
#pragma unroll
        for (int j = 0; j < 2; ++j) acc[i][j] = z;

    auto stage = [&](int bufi, int kofs) {
#pragma unroll
        for (int i = 0; i < 2; ++i) {
            gld_lds16(asrc[i] + kofs, As + bufi * 8192 + aoff[i]);
            gld_lds16(bsrc[i] + kofs, Bs + bufi * 8192 + aoff[i]);
        }
    };

    const int nsteps = Kslice >> 6;
    stage(0, 0);
    asm volatile("s_waitcnt vmcnt(0)" ::: "memory");
    __builtin_amdgcn_s_barrier();

    int cur = 0;
    for (int t = 0; t < nsteps; ++t) {
        if (t + 1 < nsteps) stage(cur ^ 1, (t + 1) * 64);
        if (FCONV) {
            if (gprev >= 0) {
                u16x8 o;
                o[0] = f2bf(cva.x); o[1] = f2bf(cva.y); o[2] = f2bf(cva.z); o[3] = f2bf(cva.w);
                o[4] = f2bf(cvb.x); o[5] = f2bf(cvb.y); o[6] = f2bf(cvb.z); o[7] = f2bf(cvb.w);
                if (gprev < cvt1) *(u16x8*)(cvd1 + gprev * 8) = o;
                else              *(u16x8*)(cvd2 + (gprev - cvt1) * 8) = o;
            }
            gprev = -1;
            if (t < nwin) {
                long g = gbase + (long)t * 512 + tid;
                if (g < gend) {
                    const float* src = (g < cvt1) ? (cvs1 + g * 8) : (cvs2 + (g - cvt1) * 8);
                    cva = *(const float4*)(src);
                    cvb = *(const float4*)(src + 4);
                    gprev = g;
                }
            }
        }
        const u16* Ab = As + cur * 8192;
        const u16* Bb = Bs + cur * 8192;
#pragma unroll
        for (int kk = 0; kk < 2; ++kk) {
            bf16x8 a[4], b[2];
#pragma unroll
            for (int i = 0; i < 4; ++i) {
                int row = wr * 64 + i * 16 + l15;
                a[i] = *(const bf16x8*)&Ab[row * 64 + ((kk * 4 + lg) ^ (row & 7)) * 8];
            }
#pragma unroll
            for (int j = 0; j < 2; ++j) {
                int row = wc * 32 + j * 16 + l15;
                b[j] = *(const bf16x8*)&Bb[row * 64 + ((kk * 4 + lg) ^ (row & 7)) * 8];
            }
#pragma unroll
            for (int i = 0; i < 4; ++i)
#pragma unroll
                for (int j = 0; j < 2; ++j)
                    acc[i][j] = __builtin_amdgcn_mfma_f32_16x16x32_bf16(a[i], b[j], acc[i][j], 0, 0, 0);
        }
        asm volatile("s_waitcnt vmcnt(0)" ::: "memory");
        __builtin_amdgcn_s_barrier();
        cur ^= 1;
    }
    if (FCONV && gprev >= 0) {
        u16x8 o;
        o[0] = f2bf(cva.x); o[1] = f2bf(cva.y); o[2] = f2bf(cva.z); o[3] = f2bf(cva.w);
        o[4] = f2bf(cvb.x); o[5] = f2bf(cvb.y); o[6] = f2bf(cvb.z); o[7] = f2bf(cvb.w);
        if (gprev < cvt1) *(u16x8*)(cvd1 + gprev * 8) = o;
        else              *(u16x8*)(cvd2 + (gprev - cvt1) * 8) = o;
    }

#pragma unroll
    for (int i = 0; i < 4; ++i)
#pragma unroll
        for (int j = 0; j < 2; ++j)
#pragma unroll
            for (int r = 0; r < 4; ++r) {
                int m = m0 + wr * 64 + i * 16 + lg * 4 + r;
                int n = n0 + wc * 32 + j * 16 + l15;
                if (n < N) {
                    if (OUT_BF16)
                        ((u16*)Cv)[(long)m * N + n] = f2bf(acc[i][j][r]);
                    else
                        ((float*)Cv)[(long)blockIdx.z * M * N + (long)m * N + n] = acc[i][j][r];
                }
            }
}

// ---------------- fused reduce x4 + RMSNorm (c_q chain) ----------------
__global__ __launch_bounds__(256) void reduce_rms_cq(const float* __restrict__ parts,
                                                     const float* __restrict__ wnorm,
                                                     u16* __restrict__ y) {
    const int row = blockIdx.x;
    const long mn = (long)SEQ * QLRANK;
    const float* base = parts + (long)row * QLRANK;
    float v[6];
    float ss = 0.f;
#pragma unroll
    for (int i = 0; i < 6; ++i) {
        int col = i * 256 + threadIdx.x;
        float s = base[col];
#pragma unroll
        for (int p = 1; p < 4; ++p) s += base[(long)p * mn + col];
        v[i] = s;
        ss += s * s;
    }
#pragma unroll
    for (int off = 32; off > 0; off >>= 1) ss += __shfl_down(ss, off);
    __shared__ float partial[4];
    if ((threadIdx.x & 63) == 0) partial[threadIdx.x >> 6] = ss;
    __syncthreads();
    float tot = partial[0] + partial[1] + partial[2] + partial[3];
    float rs = 1.0f / sqrtf(tot / (float)QLRANK + RMS_EPS);
    u16* yr = y + (long)row * QLRANK;
#pragma unroll
    for (int i = 0; i < 6; ++i) {
        int col = i * 256 + threadIdx.x;
        yr[col] = f2bf(v[i] * rs * wnorm[col]);
    }
}

// ---------------- fused reduce x8 + RMSNorm + RoPE-k (ckv chain) ----------------
__global__ __launch_bounds__(256) void reduce_rms_rope_kv(const float* __restrict__ parts,
                                                          const float* __restrict__ wnorm,
                                                          u16* __restrict__ y,
                                                          const float* __restrict__ cos_t,
                                                          const float* __restrict__ sin_t,
                                                          u16* __restrict__ kr) {
    const int row = blockIdx.x;
    const long mn = (long)SEQ * 576;
    const float* base = parts + (long)row * 576;
    __shared__ float rope_buf[64];
    __shared__ float partial[4];
    float v[3];
    float ss = 0.f;
#pragma unroll
    for (int i = 0; i < 3; ++i) {
        int col = i * 256 + threadIdx.x;
        if (col < 576) {
            float s = base[col];
#pragma unroll
            for (int p = 1; p < 8; ++p) s += base[(long)p * mn + col];
            v[i] = s;
            if (col < KVLRANK) ss += s * s;
            else rope_buf[col - KVLRANK] = s;
        }
    }
#pragma unroll
    for (int off = 32; off > 0; off >>= 1) ss += __shfl_down(ss, off);
    if ((threadIdx.x & 63) == 0) partial[threadIdx.x >> 6] = ss;
    __syncthreads();
    float tot = partial[0] + partial[1] + partial[2] + partial[3];
    float rs = 1.0f / sqrtf(tot / (float)KVLRANK + RMS_EPS);
    u16* yr = y + (long)row * KVLRANK;
#pragma unroll
    for (int i = 0; i < 3; ++i) {
        int col = i * 256 + threadIdx.x;
        if (col < KVLRANK) yr[col] = f2bf(v[i] * rs * wnorm[col]);
    }
    if (threadIdx.x < 32) {
        float x1 = rope_buf[threadIdx.x];
        float x2 = rope_buf[threadIdx.x + 32];
        float c = cos_t[row * 32 + threadIdx.x], sn = sin_t[row * 32 + threadIdx.x];
        kr[row * 64 + threadIdx.x]      = f2bf(x1 * c - x2 * sn);
        kr[row * 64 + threadIdx.x + 32] = f2bf(x2 * c + x1 * sn);
    }
}

// ---------------- build vT[h][dv][s] from kv[s][h*256+128+dv] ----------------
__global__ __launch_bounds__(256) void build_vt(const u16* __restrict__ kv,
                                                u16* __restrict__ vT) {
    __shared__ u16 vtile[64][136];
    const int h = blockIdx.x, sb = blockIdx.y, s0 = sb * 64;
    const int tid = threadIdx.x;
#pragma unroll
    for (int it = 0; it < 4; ++it) {
        int c = it * 256 + tid;
        int row = c >> 4;
        int off8 = (c & 15) * 8;
        *(u16x8*)&vtile[row][off8] =
            *(const u16x8*)&kv[(s0 + row) * 32768 + h * 256 + 128 + off8];
    }
    __syncthreads();
    const int sl = tid & 63;
    const int dvb = tid >> 6;
#pragma unroll
    for (int it = 0; it < 32; ++it) {
        int dv = dvb + it * 4;
        vT[(h * 128 + dv) * 1024 + s0 + sl] = vtile[sl][dv];
    }
}

// ---------------- flash attention + in-register RoPE-Q + fused w_out conversion ----------------
// RoPE on Q applied in-register after the qreg load: qreg[4][j] (col 128+i)
// pairs with qreg[5][j] (col 160+i), i = lg*8+j — exactly the reference
// (x1,x2) pair; fp32 rotate + f2bf = bit-identical to the old rope_q pass.
__global__ __launch_bounds__(512) void mla_attn(const u16* __restrict__ q_cr,
                                                const u16* __restrict__ kv,
                                                const u16* __restrict__ kr,
                                                const u16* __restrict__ vT,
                                                u16* __restrict__ o_g,
                                                const float* __restrict__ cos_t,
                                                const float* __restrict__ sin_t,
                                                const float* __restrict__ wsrc,
                                                u16* __restrict__ wdst,
                                                int do_conv) {
    __shared__ u16 ks[64][200];
    __shared__ u16 vts[128][72];
    __shared__ u16 p_lds[8][16][68];
    const int qb = blockIdx.x, h = blockIdx.y;
    const int s0q = qb * 128;
    const int tid = threadIdx.x, lane = tid & 63, w = tid >> 6;
    const int l15 = lane & 15, lg = lane >> 4;
    const float scale = 0.07216878364870323f;

    bf16x8 qreg[6];
    {
        const int qrow = s0q + w * 16 + l15;
#pragma unroll
        for (int kk = 0; kk < 6; ++kk)
            qreg[kk] = *(const bf16x8*)&q_cr[qrow * (NHEAD * 192) + h * 192 + kk * 32 + lg * 8];
        // in-register RoPE on the 64 rope dims
#pragma unroll
        for (int j = 0; j < 8; ++j) {
            int i = lg * 8 + j;
            float c = cos_t[qrow * 32 + i], sn = sin_t[qrow * 32 + i];
            float x1 = bf2f((u16)qreg[4][j]);
            float x2 = bf2f((u16)qreg[5][j]);
            qreg[4][j] = (short)f2bf(x1 * c - x2 * sn);
            qreg[5][j] = (short)f2bf(x2 * c + x1 * sn);
        }
    }

    const int krow0 = tid >> 4,           koff0 = (tid & 15) * 8;
    const int krow1 = (512 + tid) >> 4,   koff1 = ((512 + tid) & 15) * 8;
    const int rrow  = tid >> 3,           roff  = (tid & 7) * 8;
    const int vdv0  = tid >> 3,           voff0 = (tid & 7) * 8;
    const int vdv1  = (512 + tid) >> 3,   voff1 = ((512 + tid) & 7) * 8;
    const u16* kvp = kv + h * 256;
    const u16* vtp = vT + (long)(h * 128) * 1024;

    u16x8 kreg0, kreg1, krreg, vreg0, vreg1;
    auto load_tile = [&](int s0k) {
        kreg0 = *(const u16x8*)&kvp[(long)(s0k + krow0) * 32768 + koff0];
        kreg1 = *(const u16x8*)&kvp[(long)(s0k + krow1) * 32768 + koff1];
        krreg = *(const u16x8*)&kr[(s0k + rrow) * 64 + roff];
        vreg0 = *(const u16x8*)&vtp[(long)vdv0 * 1024 + s0k + voff0];
        vreg1 = *(const u16x8*)&vtp[(long)vdv1 * 1024 + s0k + voff1];
    };

    const long cbase = ((long)(h * 8 + qb)) * 16 * 896;
    float4 cva0, cvb0, cva1, cvb1;
    const int gi0 = tid;
    const int gi1 = 512 + tid;
    auto conv_load = [&](int kt) {
        long g0 = cbase + (long)kt * 896;
        long a0 = (g0 + gi0) * 8;
        cva0 = *(const float4*)(wsrc + a0);
        cvb0 = *(const float4*)(wsrc + a0 + 4);
        if (gi1 < 896) {
            long a1 = (g0 + gi1) * 8;
            cva1 = *(const float4*)(wsrc + a1);
            cvb1 = *(const float4*)(wsrc + a1 + 4);
        }
    };
    auto conv_store = [&](int kt) {
        long g0 = cbase + (long)kt * 896;
        u16x8 o;
        o[0] = f2bf(cva0.x); o[1] = f2bf(cva0.y); o[2] = f2bf(cva0.z); o[3] = f2bf(cva0.w);
        o[4] = f2bf(cvb0.x); o[5] = f2bf(cvb0.y); o[6] = f2bf(cvb0.z); o[7] = f2bf(cvb0.w);
        *(u16x8*)(wdst + (g0 + gi0) * 8) = o;
        if (gi1 < 896) {
            u16x8 o1;
            o1[0] = f2bf(cva1.x); o1[1] = f2bf(cva1.y); o1[2] = f2bf(cva1.z); o1[3] = f2bf(cva1.w);
            o1[4] = f2bf(cvb1.x); o1[5] = f2bf(cvb1.y); o1[6] = f2bf(cvb1.z); o1[7] = f2bf(cvb1.w);
            *(u16x8*)(wdst + (g0 + gi1) * 8) = o1;
        }
    };

    f32x4 o_acc[8];
    const f32x4 z = {0.f, 0.f, 0.f, 0.f};
#pragma unroll
    for (int d = 0; d < 8; ++d) o_acc[d] = z;
    float m_r[4], l_r[4];
#pragma unroll
    for (int r = 0; r < 4; ++r) { m_r[r] = -1e30f; l_r[r] = 0.f; }

    load_tile(0);
    if (do_conv) conv_load(0);

    for (int kt = 0; kt < 16; ++kt) {
        __syncthreads();
        *(u16x8*)&ks[krow0][koff0]      = kreg0;
        *(u16x8*)&ks[krow1][koff1]      = kreg1;
        *(u16x8*)&ks[rrow][128 + roff]  = krreg;
        *(u16x8*)&vts[vdv0][voff0]      = vreg0;
        *(u16x8*)&vts[vdv1][voff1]      = vreg1;
        __syncthreads();
        if (kt + 1 < 16) load_tile((kt + 1) * 64);

        if (do_conv) {
            conv_store(kt);
            if (kt + 1 < 16) conv_load(kt + 1);
        }

        // QK^T
        f32x4 sf[4];
#pragma unroll
        for (int j = 0; j < 4; ++j) sf[j] = z;
        __builtin_amdgcn_s_setprio(1);
#pragma unroll
        for (int kk = 0; kk < 6; ++kk) {
            bf16x8 a = qreg[kk];
#pragma unroll
            for (int j = 0; j < 4; ++j) {
                bf16x8 b = *(const bf16x8*)&ks[j * 16 + l15][kk * 32 + lg * 8];
                sf[j] = __builtin_amdgcn_mfma_f32_16x16x32_bf16(a, b, sf[j], 0, 0, 0);
            }
        }
        __builtin_amdgcn_s_setprio(0);

        // online softmax
        float p[4][4];
        float alpha[4];
#pragma unroll
        for (int r = 0; r < 4; ++r) {
            float mx = fmaxf(fmaxf(sf[0][r], sf[1][r]), fmaxf(sf[2][r], sf[3][r]));
#pragma unroll
            for (int off = 1; off < 16; off <<= 1) mx = fmaxf(mx, __shfl_xor(mx, off));
            mx *= scale;
            float mnew = fmaxf(m_r[r], mx);
            alpha[r] = __expf(m_r[r] - mnew);
            float rs = 0.f;
#pragma unroll
            for (int j = 0; j < 4; ++j) {
                float pv = __expf(sf[j][r] * scale - mnew);
                p[j][r] = pv;
                rs += pv;
            }
#pragma unroll
            for (int off = 1; off < 16; off <<= 1) rs += __shfl_xor(rs, off);
            l_r[r] = l_r[r] * alpha[r] + rs;
            m_r[r] = mnew;
        }
#pragma unroll
        for (int d = 0; d < 8; ++d)
#pragma unroll
            for (int r = 0; r < 4; ++r) o_acc[d][r] *= alpha[r];

        // P -> LDS (wave-private)
#pragma unroll
        for (int j = 0; j < 4; ++j)
#pragma unroll
            for (int r = 0; r < 4; ++r)
                p_lds[w][lg * 4 + r][j * 16 + l15] = f2bf(p[j][r]);

        // PV
        __builtin_amdgcn_s_setprio(1);
#pragma unroll
        for (int kk2 = 0; kk2 < 2; ++kk2) {
            bf16x8 a = *(const bf16x8*)&p_lds[w][l15][kk2 * 32 + lg * 8];
#pragma unroll
            for (int d = 0; d < 8; ++d) {
                bf16x8 b = *(const bf16x8*)&vts[d * 16 + l15][kk2 * 32 + lg * 8];
                o_acc[d] = __builtin_amdgcn_mfma_f32_16x16x32_bf16(a, b, o_acc[d], 0, 0, 0);
            }
        }
        __builtin_amdgcn_s_setprio(0);
    }

#pragma unroll
    for (int d = 0; d < 8; ++d)
#pragma unroll
        for (int r = 0; r < 4; ++r) {
            int srow = s0q + w * 16 + lg * 4 + r;
            float v = o_acc[d][r] / l_r[r];
            o_g[srow * 16384 + h * 128 + d * 16 + l15] = f2bf(v);
        }
}

// ---------------- host launcher ----------------
extern "C" void kernel_launch(void* const* d_in, const int* in_sizes, int n_in,
                              void* d_out, int out_size, void* d_ws, size_t ws_size,
                              hipStream_t stream) {
    const float* hs        = (const float*)d_in[0];
    const float* w_q_down  = (const float*)d_in[1];
    const float* q_norm_w  = (const float*)d_in[2];
    const float* w_q_up    = (const float*)d_in[3];
    const float* w_kv_down = (const float*)d_in[4];
    const float* kv_norm_w = (const float*)d_in[5];
    const float* w_kv_up   = (const float*)d_in[6];
    const float* w_out     = (const float*)d_in[7];
    float* out = (float*)d_out;
    char* ws = (char*)d_ws;

    const size_t SZ_KV   = (size_t)SEQ * 32768 * 2;
    const size_t SZ_QCR  = (size_t)SEQ * (NHEAD * 192) * 2;
    const size_t SZ_KR   = (size_t)SEQ * 64 * 2;
    const size_t SZ_TAB  = (size_t)SEQ * 32 * 4;
    const size_t SZ_VT   = (size_t)NHEAD * 128 * 1024 * 2;
    const size_t SZ_OG   = (size_t)SEQ * 16384 * 2;
    const size_t SZ_WOUT = (size_t)HIDN * 16384 * 2;
    const size_t SZ_WQD  = (size_t)QLRANK * HIDN * 2;
    const size_t SZ_WQU  = (size_t)24576 * QLRANK * 2;
    const size_t SZ_WKD  = (size_t)576 * HIDN * 2;
    const size_t SZ_WKU  = (size_t)32768 * KVLRANK * 2;
    const size_t SZ_PART = (size_t)4 * SEQ * QLRANK * 4;
    const size_t SZ_HS   = (size_t)SEQ * HIDN * 2;
    const size_t SZ_CQN  = (size_t)SEQ * QLRANK * 2;
    const size_t SZ_CKVN = (size_t)SEQ * KVLRANK * 2;

    size_t off = 0;
    u16* kvb     = (u16*)(ws + off); off += SZ_KV;
    u16* q_cr    = (u16*)(ws + off); off += SZ_QCR;
    u16* kr      = (u16*)(ws + off); off += SZ_KR;
    float* cos_t = (float*)(ws + off); off += SZ_TAB;
    float* sin_t = (float*)(ws + off); off += SZ_TAB;
    u16* vT      = (u16*)(ws + off); off += SZ_VT;
    u16* o_g     = (u16*)(ws + off); off += SZ_OG;
    const size_t live_end = off;
    u16* wout_bf = (u16*)(ws + live_end);
    size_t toff = live_end;
    u16* wqd_bf  = (u16*)(ws + toff); toff += SZ_WQD;
    u16* wqu_bf  = (u16*)(ws + toff); toff += SZ_WQU;
    u16* wkd_bf  = (u16*)(ws + toff); toff += SZ_WKD;
    u16* wku_bf  = (u16*)(ws + toff); toff += SZ_WKU;
    float* parts = (float*)(ws + toff); toff += SZ_PART;
    u16* hs_bf    = (u16*)(ws + toff); toff += SZ_HS;
    u16* cq_n     = (u16*)(ws + toff); toff += SZ_CQN;
    u16* ckv_n    = (u16*)(ws + toff); toff += SZ_CKVN;
    const int fuse = (live_end + SZ_WOUT) <= ws_size;
    (void)in_sizes; (void)n_in; (void)out_size;

    // hs + w_q_down conversion + rope tables in one kernel
    conv2_tab<<<2048, 256, 0, stream>>>(hs, hs_bf, (long)SEQ * HIDN,
                                        w_q_down, wqd_bf, (long)QLRANK * HIDN,
                                        cos_t, sin_t);

    // c_q = hs @ w_q_down^T (split-K x4) + fused conversion of w_q_up AND w_kv_down
    gemm_bt<0, 1><<<dim3(QLRANK / 128, SEQ / 128, 4), 512, 0, stream>>>(
        hs_bf, wqd_bf, parts, SEQ, QLRANK, HIDN / 4, HIDN,
        w_q_up, wqu_bf, ((long)24576 * QLRANK) / 8,
        w_kv_down, wkd_bf, ((long)576 * HIDN) / 8);
    reduce_rms_cq<<<SEQ, 256, 0, stream>>>(parts, q_norm_w, cq_n);

    // q_cr = rmsnorm(c_q) @ w_q_up^T + fused conversion of w_kv_up
    gemm_bt<1, 1><<<dim3(24576 / 128, SEQ / 128), 512, 0, stream>>>(
        cq_n, wqu_bf, q_cr, SEQ, 24576, QLRANK, QLRANK,
        w_kv_up, wku_bf, ((long)32768 * KVLRANK) / 8,
        nullptr, nullptr, 0);

    // ckv_kr = hs @ w_kv_down^T   (split-K x8; N=576 ragged)
    gemm_bt<0, 0><<<dim3(5, SEQ / 128, 8), 512, 0, stream>>>(
        hs_bf, wkd_bf, parts, SEQ, 576, HIDN / 8, HIDN,
        nullptr, nullptr, 0, nullptr, nullptr, 0);
    reduce_rms_rope_kv<<<SEQ, 256, 0, stream>>>(parts, kv_norm_w, ckv_n, cos_t, sin_t, kr);

    // kv = rmsnorm(c_kv) @ w_kv_up^T
    gemm_bt<1, 0><<<dim3(32768 / 128, SEQ / 128), 512, 0, stream>>>(
        ckv_n, wku_bf, kvb, SEQ, 32768, KVLRANK, KVLRANK,
        nullptr, nullptr, 0, nullptr, nullptr, 0);

    build_vt<<<dim3(NHEAD, SEQ / 64), 256, 0, stream>>>(kvb, vT);

    // attention (in-register RoPE-Q); convert w_out under attention's idle BW
    if (!fuse)
        f32_to_bf16<<<4096, 256, 0, stream>>>(w_out, wout_bf, (long)HIDN * 16384);
    mla_attn<<<dim3(SEQ / 128, NHEAD), 512, 0, stream>>>(q_cr, kvb, kr, vT, o_g,
                                                         cos_t, sin_t,
                                                         w_out, wout_bf, fuse ? 1 : 0);

    // out = o @ w_out^T
    gemm_bt<0, 0><<<dim3(HIDN / 128, SEQ / 128), 512, 0, stream>>>(
        o_g, wout_bf, out, SEQ, HIDN, 16384, 16384,
        nullptr, nullptr, 0, nullptr, nullptr, 0);
}

// Round 22
// 861.761 us; speedup vs baseline: 1.2374x; 1.0055x over previous
//
#include <hip/hip_runtime.h>
#include <hip/hip_bf16.h>
#include <math.h>

// ---- problem constants ----
#define HIDN 7168
#define NHEAD 128
#define QLRANK 1536
#define KVLRANK 512
#define QKD 128
#define VHD 128
#define RHD 64
#define SEQ 1024
#define RMS_EPS 1.1920929e-07f

typedef unsigned short u16;
typedef __attribute__((ext_vector_type(8))) short bf16x8;
typedef __attribute__((ext_vector_type(4))) float f32x4;
typedef __attribute__((ext_vector_type(8))) unsigned short u16x8;

__device__ __forceinline__ u16 f2bf(float f) {
    unsigned int u = __float_as_uint(f);
    unsigned int r = (u + 0x7FFFu + ((u >> 16) & 1u)) >> 16;
    return (u16)r;
}
__device__ __forceinline__ float bf2f(u16 v) {
    return __uint_as_float(((unsigned int)v) << 16);
}

// async global->LDS, 16B per lane. LDS dest is wave-uniform base + lane*16.
__device__ __forceinline__ void gld_lds16(const u16* g, u16* l) {
    __builtin_amdgcn_global_load_lds(
        (const __attribute__((address_space(1))) unsigned int*)g,
        (__attribute__((address_space(3))) unsigned int*)l,
        16, 0, 0);
}

// ---------------- fused 2-way fp32 -> bf16 conversion + rope tables ----------------
__global__ __launch_bounds__(256) void conv2_tab(const float* __restrict__ s0, u16* __restrict__ d0, long n0,
                                                 const float* __restrict__ s1, u16* __restrict__ d1, long n1,
                                                 float* __restrict__ cos_t, float* __restrict__ sin_t) {
    if (blockIdx.x < SEQ && threadIdx.x < 32) {
        int s = blockIdx.x, i = threadIdx.x;
        float invf = powf(10000.0f, -((float)(2 * i) / 64.0f));
        float ang = (float)s * invf;
        cos_t[s * 32 + i] = cosf(ang);
        sin_t[s * 32 + i] = sinf(ang);
    }
    const long stride = (long)gridDim.x * blockDim.x * 8;
#pragma unroll 1
    for (int seg = 0; seg < 2; ++seg) {
        const float* s = seg == 0 ? s0 : s1;
        u16* d        = seg == 0 ? d0 : d1;
        long n        = seg == 0 ? n0 : n1;
        for (long i = ((long)blockIdx.x * blockDim.x + threadIdx.x) * 8; i < n; i += stride) {
            float4 a = *(const float4*)(s + i);
            float4 b = *(const float4*)(s + i + 4);
            u16x8 o;
            o[0] = f2bf(a.x); o[1] = f2bf(a.y); o[2] = f2bf(a.z); o[3] = f2bf(a.w);
            o[4] = f2bf(b.x); o[5] = f2bf(b.y); o[6] = f2bf(b.z); o[7] = f2bf(b.w);
            *(u16x8*)(d + i) = o;
        }
    }
}

// ---------------- single fp32 -> bf16 conversion (fallback) ----------------
__global__ __launch_bounds__(256) void f32_to_bf16(const float* __restrict__ in,
                                                   u16* __restrict__ out, long n) {
    long i = ((long)blockIdx.x * blockDim.x + threadIdx.x) * 8;
    long stride = (long)gridDim.x * blockDim.x * 8;
    for (; i < n; i += stride) {
        float4 a = *(const float4*)(in + i);
        float4 b = *(const float4*)(in + i + 4);
        u16x8 o;
        o[0] = f2bf(a.x); o[1] = f2bf(a.y); o[2] = f2bf(a.z); o[3] = f2bf(a.w);
        o[4] = f2bf(b.x); o[5] = f2bf(b.y); o[6] = f2bf(b.z); o[7] = f2bf(b.w);
        *(u16x8*)(out + i) = o;
    }
}

// ---------------- generic GEMM (r10-proven) + fused conversion + optional vT epilogue ----------------
// 128x128 tile, BK=64, 8 waves, 64 KiB LDS dbuf -> 2 WG/CU, 4 waves/SIMD TLP.
// One vmcnt(0)+s_barrier per K-step. FCONV: double-buffered fp32->bf16 side
// conversion (r18/r19-proven), two logical segments. VT_OUT (kv_up only):
// odd blockIdx.x tiles are pure-V tiles of head bx>>1 (head stride 256,
// BN=128); their epilogue bounces acc through the dead As LDS (128x128 u16 =
// 32KB), reads transposed conflict-free (lane-consecutive dv), and stores
// vT[h*128+dv][s] in 64B/thread contiguous chunks — replaces build_vt and
// the dead kvb V-column writes. Final K-loop barrier makes the As reuse safe.
template <int OUT_BF16, int FCONV, int VT_OUT>
__global__ __launch_bounds__(512) void gemm_bt(const u16* __restrict__ A,
                                               const u16* __restrict__ B,
                                               void* __restrict__ Cv,
                                               int M, int N, int Kslice, long ldk,
                                               const float* __restrict__ cvs1,
                                               u16* __restrict__ cvd1, long cvt1,
                                               const float* __restrict__ cvs2,
                                               u16* __restrict__ cvd2, long cvt2,
                                               u16* __restrict__ vt_out) {
    __shared__ u16 As[2 * 128 * 64];
    __shared__ u16 Bs[2 * 128 * 64];
    const int tid = threadIdx.x;
    const int lane = tid & 63;
    const int w = tid >> 6;
    const int wr = w >> 2, wc = w & 3;
    const int l15 = lane & 15, lg = lane >> 4;
    const int n0 = blockIdx.x * 128;
    const int m0 = blockIdx.y * 128;
    const long kbase = (long)blockIdx.z * Kslice;

    const u16* asrc[2];
    const u16* bsrc[2];
    int aoff[2];
#pragma unroll
    for (int i = 0; i < 2; ++i) {
        int r = (w * 2 + i) * 8 + (lane >> 3);
        int gc = (lane & 7) ^ (r & 7);
        asrc[i] = A + (long)(m0 + r) * ldk + kbase + gc * 8;
        int br = n0 + r; if (br >= N) br = N - 1;
        bsrc[i] = B + (long)br * ldk + kbase + gc * 8;
        aoff[i] = (w * 2 + i) * 512;
    }

    long gbase = 0, gend = 0;
    int nwin = 0;
    float4 cva, cvb;
    long gprev = -1;
    if (FCONV) {
        const int nblocks = gridDim.x * gridDim.y * gridDim.z;
        const int bl = (blockIdx.z * gridDim.y + blockIdx.y) * gridDim.x + blockIdx.x;
        long total = cvt1 + cvt2;
        long share = (total + nblocks - 1) / nblocks;
        gbase = (long)bl * share;
        gend = gbase + share; if (gend > total) gend = total;
        nwin = (int)((share + 511) >> 9);
    }

    f32x4 acc[4][2];
    const f32x4 z = {0.f, 0.f, 0.f, 0.f};
#pragma unroll
    for (int i = 0; i < 4; ++i)
#pragma unroll
        for (int j = 0; j < 2; ++j) acc[i][j] = z;

    auto stage = [&](int bufi, int kofs) {
#pragma unroll
        for (int i = 0; i < 2; ++i) {
            gld_lds16(asrc[i] + kofs, As + bufi * 8192 + aoff[i]);
            gld_lds16(bsrc[i] + kofs, Bs + bufi * 8192 + aoff[i]);
        }
    };

    const int nsteps = Kslice >> 6;
    stage(0, 0);
    asm volatile("s_waitcnt vmcnt(0)" ::: "memory");
    __builtin_amdgcn_s_barrier();

    int cur = 0;
    for (int t = 0; t < nsteps; ++t) {
        if (t + 1 < nsteps) stage(cur ^ 1, (t + 1) * 64);
        if (FCONV) {
            if (gprev >= 0) {
                u16x8 o;
                o[0] = f2bf(cva.x); o[1] = f2bf(cva.y); o[2] = f2bf(cva.z); o[3] = f2bf(cva.w);
                o[4] = f2bf(cvb.x); o[5] = f2bf(cvb.y); o[6] = f2bf(cvb.z); o[7] = f2bf(cvb.w);
                if (gprev < cvt1) *(u16x8*)(cvd1 + gprev * 8) = o;
                else              *(u16x8*)(cvd2 + (gprev - cvt1) * 8) = o;
            }
            gprev = -1;
            if (t < nwin) {
                long g = gbase + (long)t * 512 + tid;
                if (g < gend) {
                    const float* src = (g < cvt1) ? (cvs1 + g * 8) : (cvs2 + (g - cvt1) * 8);
                    cva = *(const float4*)(src);
                    cvb = *(const float4*)(src + 4);
                    gprev = g;
                }
            }
        }
        const u16* Ab = As + cur * 8192;
        const u16* Bb = Bs + cur * 8192;
#pragma unroll
        for (int kk = 0; kk < 2; ++kk) {
            bf16x8 a[4], b[2];
#pragma unroll
            for (int i = 0; i < 4; ++i) {
                int row = wr * 64 + i * 16 + l15;
                a[i] = *(const bf16x8*)&Ab[row * 64 + ((kk * 4 + lg) ^ (row & 7)) * 8];
            }
#pragma unroll
            for (int j = 0; j < 2; ++j) {
                int row = wc * 32 + j * 16 + l15;
                b[j] = *(const bf16x8*)&Bb[row * 64 + ((kk * 4 + lg) ^ (row & 7)) * 8];
            }
#pragma unroll
            for (int i = 0; i < 4; ++i)
#pragma unroll
                for (int j = 0; j < 2; ++j)
                    acc[i][j] = __builtin_amdgcn_mfma_f32_16x16x32_bf16(a[i], b[j], acc[i][j], 0, 0, 0);
        }
        asm volatile("s_waitcnt vmcnt(0)" ::: "memory");
        __builtin_amdgcn_s_barrier();
        cur ^= 1;
    }
    if (FCONV && gprev >= 0) {
        u16x8 o;
        o[0] = f2bf(cva.x); o[1] = f2bf(cva.y); o[2] = f2bf(cva.z); o[3] = f2bf(cva.w);
        o[4] = f2bf(cvb.x); o[5] = f2bf(cvb.y); o[6] = f2bf(cvb.z); o[7] = f2bf(cvb.w);
        if (gprev < cvt1) *(u16x8*)(cvd1 + gprev * 8) = o;
        else              *(u16x8*)(cvd2 + (gprev - cvt1) * 8) = o;
    }

    if (VT_OUT && (blockIdx.x & 1)) {
        // V tile of head bx>>1: transpose via dead As (final loop barrier
        // guarantees all LDS readers done), store vT[(h*128+dv)*1024 + s].
        u16* lt = As;   // 128 s x 128 dv, stride 128 (32 KB)
#pragma unroll
        for (int i = 0; i < 4; ++i)
#pragma unroll
            for (int j = 0; j < 2; ++j)
#pragma unroll
                for (int r = 0; r < 4; ++r) {
                    int sl = wr * 64 + i * 16 + lg * 4 + r;
                    int dv = wc * 32 + j * 16 + l15;
                    lt[sl * 128 + dv] = f2bf(acc[i][j][r]);
                }
        __syncthreads();
        const int dv = tid & 127;            // lane-consecutive dv: conflict-free reads
        const int sb = (tid >> 7) << 5;      // 0,32,64,96
        const int h = blockIdx.x >> 1;
        u16* dst = vt_out + ((long)(h * 128 + dv)) * 1024 + m0 + sb;
#pragma unroll
        for (int q = 0; q < 4; ++q) {
            u16x8 o;
#pragma unroll
            for (int k = 0; k < 8; ++k) o[k] = lt[(sb + q * 8 + k) * 128 + dv];
            *(u16x8*)(dst + q * 8) = o;
        }
        return;
    }

#pragma unroll
    for (int i = 0; i < 4; ++i)
#pragma unroll
        for (int j = 0; j < 2; ++j)
#pragma unroll
            for (int r = 0; r < 4; ++r) {
                int m = m0 + wr * 64 + i * 16 + lg * 4 + r;
                int n = n0 + wc * 32 + j * 16 + l15;
                if (n < N) {
                    if (OUT_BF16)
                        ((u16*)Cv)[(long)m * N + n] = f2bf(acc[i][j][r]);
                    else
                        ((float*)Cv)[(long)blockIdx.z * M * N + (long)m * N + n] = acc[i][j][r];
                }
            }
}

// ---------------- fused reduce x4 + RMSNorm (c_q chain) ----------------
__global__ __launch_bounds__(256) void reduce_rms_cq(const float* __restrict__ parts,
                                                     const float* __restrict__ wnorm,
                                                     u16* __restrict__ y) {
    const int row = blockIdx.x;
    const long mn = (long)SEQ * QLRANK;
    const float* base = parts + (long)row * QLRANK;
    float v[6];
    float ss = 0.f;
#pragma unroll
    for (int i = 0; i < 6; ++i) {
        int col = i * 256 + threadIdx.x;
        float s = base[col];
#pragma unroll
        for (int p = 1; p < 4; ++p) s += base[(long)p * mn + col];
        v[i] = s;
        ss += s * s;
    }
#pragma unroll
    for (int off = 32; off > 0; off >>= 1) ss += __shfl_down(ss, off);
    __shared__ float partial[4];
    if ((threadIdx.x & 63) == 0) partial[threadIdx.x >> 6] = ss;
    __syncthreads();
    float tot = partial[0] + partial[1] + partial[2] + partial[3];
    float rs = 1.0f / sqrtf(tot / (float)QLRANK + RMS_EPS);
    u16* yr = y + (long)row * QLRANK;
#pragma unroll
    for (int i = 0; i < 6; ++i) {
        int col = i * 256 + threadIdx.x;
        yr[col] = f2bf(v[i] * rs * wnorm[col]);
    }
}

// ---------------- fused reduce x8 + RMSNorm + RoPE-k (ckv chain) ----------------
__global__ __launch_bounds__(256) void reduce_rms_rope_kv(const float* __restrict__ parts,
                                                          const float* __restrict__ wnorm,
                                                          u16* __restrict__ y,
                                                          const float* __restrict__ cos_t,
                                                          const float* __restrict__ sin_t,
                                                          u16* __restrict__ kr) {
    const int row = blockIdx.x;
    const long mn = (long)SEQ * 576;
    const float* base = parts + (long)row * 576;
    __shared__ float rope_buf[64];
    __shared__ float partial[4];
    float v[3];
    float ss = 0.f;
#pragma unroll
    for (int i = 0; i < 3; ++i) {
        int col = i * 256 + threadIdx.x;
        if (col < 576) {
            float s = base[col];
#pragma unroll
            for (int p = 1; p < 8; ++p) s += base[(long)p * mn + col];
            v[i] = s;
            if (col < KVLRANK) ss += s * s;
            else rope_buf[col - KVLRANK] = s;
        }
    }
#pragma unroll
    for (int off = 32; off > 0; off >>= 1) ss += __shfl_down(ss, off);
    if ((threadIdx.x & 63) == 0) partial[threadIdx.x >> 6] = ss;
    __syncthreads();
    float tot = partial[0] + partial[1] + partial[2] + partial[3];
    float rs = 1.0f / sqrtf(tot / (float)KVLRANK + RMS_EPS);
    u16* yr = y + (long)row * KVLRANK;
#pragma unroll
    for (int i = 0; i < 3; ++i) {
        int col = i * 256 + threadIdx.x;
        if (col < KVLRANK) yr[col] = f2bf(v[i] * rs * wnorm[col]);
    }
    if (threadIdx.x < 32) {
        float x1 = rope_buf[threadIdx.x];
        float x2 = rope_buf[threadIdx.x + 32];
        float c = cos_t[row * 32 + threadIdx.x], sn = sin_t[row * 32 + threadIdx.x];
        kr[row * 64 + threadIdx.x]      = f2bf(x1 * c - x2 * sn);
        kr[row * 64 + threadIdx.x + 32] = f2bf(x2 * c + x1 * sn);
    }
}

// ---------------- flash attention + in-register RoPE-Q + fused w_out conversion ----------------
__global__ __launch_bounds__(512) void mla_attn(const u16* __restrict__ q_cr,
                                                const u16* __restrict__ kv,
                                                const u16* __restrict__ kr,
                                                const u16* __restrict__ vT,
                                                u16* __restrict__ o_g,
                                                const float* __restrict__ cos_t,
                                                const float* __restrict__ sin_t,
                                                const float* __restrict__ wsrc,
                                                u16* __restrict__ wdst,
                                                int do_conv) {
    __shared__ u16 ks[64][200];
    __shared__ u16 vts[128][72];
    __shared__ u16 p_lds[8][16][68];
    const int qb = blockIdx.x, h = blockIdx.y;
    const int s0q = qb * 128;
    const int tid = threadIdx.x, lane = tid & 63, w = tid >> 6;
    const int l15 = lane & 15, lg = lane >> 4;
    const float scale = 0.07216878364870323f;

    bf16x8 qreg[6];
    {
        const int qrow = s0q + w * 16 + l15;
#pragma unroll
        for (int kk = 0; kk < 6; ++kk)
            qreg[kk] = *(const bf16x8*)&q_cr[qrow * (NHEAD * 192) + h * 192 + kk * 32 + lg * 8];
#pragma unroll
        for (int j = 0; j < 8; ++j) {
            int i = lg * 8 + j;
            float c = cos_t[qrow * 32 + i], sn = sin_t[qrow * 32 + i];
            float x1 = bf2f((u16)qreg[4][j]);
            float x2 = bf2f((u16)qreg[5][j]);
            qreg[4][j] = (short)f2bf(x1 * c - x2 * sn);
            qreg[5][j] = (short)f2bf(x2 * c + x1 * sn);
        }
    }

    const int krow0 = tid >> 4,           koff0 = (tid & 15) * 8;
    const int krow1 = (512 + tid) >> 4,   koff1 = ((512 + tid) & 15) * 8;
    const int rrow  = tid >> 3,           roff  = (tid & 7) * 8;
    const int vdv0  = tid >> 3,           voff0 = (tid & 7) * 8;
    const int vdv1  = (512 + tid) >> 3,   voff1 = ((512 + tid) & 7) * 8;
    const u16* kvp = kv + h * 256;
    const u16* vtp = vT + (long)(h * 128) * 1024;

    u16x8 kreg0, kreg1, krreg, vreg0, vreg1;
    auto load_tile = [&](int s0k) {
        kreg0 = *(const u16x8*)&kvp[(long)(s0k + krow0) * 32768 + koff0];
        kreg1 = *(const u16x8*)&kvp[(long)(s0k + krow1) * 32768 + koff1];
        krreg = *(const u16x8*)&kr[(s0k + rrow) * 64 + roff];
        vreg0 = *(const u16x8*)&vtp[(long)vdv0 * 1024 + s0k + voff0];
        vreg1 = *(const u16x8*)&vtp[(long)vdv1 * 1024 + s0k + voff1];
    };

    const long cbase = ((long)(h * 8 + qb)) * 16 * 896;
    float4 cva0, cvb0, cva1, cvb1;
    const int gi0 = tid;
    const int gi1 = 512 + tid;
    auto conv_load = [&](int kt) {
        long g0 = cbase + (long)kt * 896;
        long a0 = (g0 + gi0) * 8;
        cva0 = *(const float4*)(wsrc + a0);
        cvb0 = *(const float4*)(wsrc + a0 + 4);
        if (gi1 < 896) {
            long a1 = (g0 + gi1) * 8;
            cva1 = *(const float4*)(wsrc + a1);
            cvb1 = *(const float4*)(wsrc + a1 + 4);
        }
    };
    auto conv_store = [&](int kt) {
        long g0 = cbase + (long)kt * 896;
        u16x8 o;
        o[0] = f2bf(cva0.x); o[1] = f2bf(cva0.y); o[2] = f2bf(cva0.z); o[3] = f2bf(cva0.w);
        o[4] = f2bf(cvb0.x); o[5] = f2bf(cvb0.y); o[6] = f2bf(cvb0.z); o[7] = f2bf(cvb0.w);
        *(u16x8*)(wdst + (g0 + gi0) * 8) = o;
        if (gi1 < 896) {
            u16x8 o1;
            o1[0] = f2bf(cva1.x); o1[1] = f2bf(cva1.y); o1[2] = f2bf(cva1.z); o1[3] = f2bf(cva1.w);
            o1[4] = f2bf(cvb1.x); o1[5] = f2bf(cvb1.y); o1[6] = f2bf(cvb1.z); o1[7] = f2bf(cvb1.w);
            *(u16x8*)(wdst + (g0 + gi1) * 8) = o1;
        }
    };

    f32x4 o_acc[8];
    const f32x4 z = {0.f, 0.f, 0.f, 0.f};
#pragma unroll
    for (int d = 0; d < 8; ++d) o_acc[d] = z;
    float m_r[4], l_r[4];
#pragma unroll
    for (int r = 0; r < 4; ++r) { m_r[r] = -1e30f; l_r[r] = 0.f; }

    load_tile(0);
    if (do_conv) conv_load(0);

    for (int kt = 0; kt < 16; ++kt) {
        __syncthreads();
        *(u16x8*)&ks[krow0][koff0]      = kreg0;
        *(u16x8*)&ks[krow1][koff1]      = kreg1;
        *(u16x8*)&ks[rrow][128 + roff]  = krreg;
        *(u16x8*)&vts[vdv0][voff0]      = vreg0;
        *(u16x8*)&vts[vdv1][voff1]      = vreg1;
        __syncthreads();
        if (kt + 1 < 16) load_tile((kt + 1) * 64);

        if (do_conv) {
            conv_store(kt);
            if (kt + 1 < 16) conv_load(kt + 1);
        }

        // QK^T
        f32x4 sf[4];
#pragma unroll
        for (int j = 0; j < 4; ++j) sf[j] = z;
        __builtin_amdgcn_s_setprio(1);
#pragma unroll
        for (int kk = 0; kk < 6; ++kk) {
            bf16x8 a = qreg[kk];
#pragma unroll
            for (int j = 0; j < 4; ++j) {
                bf16x8 b = *(const bf16x8*)&ks[j * 16 + l15][kk * 32 + lg * 8];
                sf[j] = __builtin_amdgcn_mfma_f32_16x16x32_bf16(a, b, sf[j], 0, 0, 0);
            }
        }
        __builtin_amdgcn_s_setprio(0);

        // online softmax
        float p[4][4];
        float alpha[4];
#pragma unroll
        for (int r = 0; r < 4; ++r) {
            float mx = fmaxf(fmaxf(sf[0][r], sf[1][r]), fmaxf(sf[2][r], sf[3][r]));
#pragma unroll
            for (int off = 1; off < 16; off <<= 1) mx = fmaxf(mx, __shfl_xor(mx, off));
            mx *= scale;
            float mnew = fmaxf(m_r[r], mx);
            alpha[r] = __expf(m_r[r] - mnew);
            float rs = 0.f;
#pragma unroll
            for (int j = 0; j < 4; ++j) {
                float pv = __expf(sf[j][r] * scale - mnew);
                p[j][r] = pv;
                rs += pv;
            }
#pragma unroll
            for (int off = 1; off < 16; off <<= 1) rs += __shfl_xor(rs, off);
            l_r[r] = l_r[r] * alpha[r] + rs;
            m_r[r] = mnew;
        }
#pragma unroll
        for (int d = 0; d < 8; ++d)
#pragma unroll
            for (int r = 0; r < 4; ++r) o_acc[d][r] *= alpha[r];

        // P -> LDS (wave-private)
#pragma unroll
        for (int j = 0; j < 4; ++j)
#pragma unroll
            for (int r = 0; r < 4; ++r)
                p_lds[w][lg * 4 + r][j * 16 + l15] = f2bf(p[j][r]);

        // PV
        __builtin_amdgcn_s_setprio(1);
#pragma unroll
        for (int kk2 = 0; kk2 < 2; ++kk2) {
            bf16x8 a = *(const bf16x8*)&p_lds[w][l15][kk2 * 32 + lg * 8];
#pragma unroll
            for (int d = 0; d < 8; ++d) {
                bf16x8 b = *(const bf16x8*)&vts[d * 16 + l15][kk2 * 32 + lg * 8];
                o_acc[d] = __builtin_amdgcn_mfma_f32_16x16x32_bf16(a, b, o_acc[d], 0, 0, 0);
            }
        }
        __builtin_amdgcn_s_setprio(0);
    }

#pragma unroll
    for (int d = 0; d < 8; ++d)
#pragma unroll
        for (int r = 0; r < 4; ++r) {
            int srow = s0q + w * 16 + lg * 4 + r;
            float v = o_acc[d][r] / l_r[r];
            o_g[srow * 16384 + h * 128 + d * 16 + l15] = f2bf(v);
        }
}

// ---------------- host launcher ----------------
extern "C" void kernel_launch(void* const* d_in, const int* in_sizes, int n_in,
                              void* d_out, int out_size, void* d_ws, size_t ws_size,
                              hipStream_t stream) {
    const float* hs        = (const float*)d_in[0];
    const float* w_q_down  = (const float*)d_in[1];
    const float* q_norm_w  = (const float*)d_in[2];
    const float* w_q_up    = (const float*)d_in[3];
    const float* w_kv_down = (const float*)d_in[4];
    const float* kv_norm_w = (const float*)d_in[5];
    const float* w_kv_up   = (const float*)d_in[6];
    const float* w_out     = (const float*)d_in[7];
    float* out = (float*)d_out;
    char* ws = (char*)d_ws;

    const size_t SZ_KV   = (size_t)SEQ * 32768 * 2;
    const size_t SZ_QCR  = (size_t)SEQ * (NHEAD * 192) * 2;
    const size_t SZ_KR   = (size_t)SEQ * 64 * 2;
    const size_t SZ_TAB  = (size_t)SEQ * 32 * 4;
    const size_t SZ_VT   = (size_t)NHEAD * 128 * 1024 * 2;
    const size_t SZ_OG   = (size_t)SEQ * 16384 * 2;
    const size_t SZ_WOUT = (size_t)HIDN * 16384 * 2;
    const size_t SZ_WQD  = (size_t)QLRANK * HIDN * 2;
    const size_t SZ_WQU  = (size_t)24576 * QLRANK * 2;
    const size_t SZ_WKD  = (size_t)576 * HIDN * 2;
    const size_t SZ_WKU  = (size_t)32768 * KVLRANK * 2;
    const size_t SZ_PART = (size_t)4 * SEQ * QLRANK * 4;
    const size_t SZ_HS   = (size_t)SEQ * HIDN * 2;
    const size_t SZ_CQN  = (size_t)SEQ * QLRANK * 2;
    const size_t SZ_CKVN = (size_t)SEQ * KVLRANK * 2;

    size_t off = 0;
    u16* kvb     = (u16*)(ws + off); off += SZ_KV;
    u16* q_cr    = (u16*)(ws + off); off += SZ_QCR;
    u16* kr      = (u16*)(ws + off); off += SZ_KR;
    float* cos_t = (float*)(ws + off); off += SZ_TAB;
    float* sin_t = (float*)(ws + off); off += SZ_TAB;
    u16* vT      = (u16*)(ws + off); off += SZ_VT;
    u16* o_g     = (u16*)(ws + off); off += SZ_OG;
    const size_t live_end = off;
    u16* wout_bf = (u16*)(ws + live_end);
    size_t toff = live_end;
    u16* wqd_bf  = (u16*)(ws + toff); toff += SZ_WQD;
    u16* wqu_bf  = (u16*)(ws + toff); toff += SZ_WQU;
    u16* wkd_bf  = (u16*)(ws + toff); toff += SZ_WKD;
    u16* wku_bf  = (u16*)(ws + toff); toff += SZ_WKU;
    float* parts = (float*)(ws + toff); toff += SZ_PART;
    u16* hs_bf    = (u16*)(ws + toff); toff += SZ_HS;
    u16* cq_n     = (u16*)(ws + toff); toff += SZ_CQN;
    u16* ckv_n    = (u16*)(ws + toff); toff += SZ_CKVN;
    const int fuse = (live_end + SZ_WOUT) <= ws_size;
    (void)in_sizes; (void)n_in; (void)out_size;

    // hs + w_q_down conversion + rope tables in one kernel
    conv2_tab<<<2048, 256, 0, stream>>>(hs, hs_bf, (long)SEQ * HIDN,
                                        w_q_down, wqd_bf, (long)QLRANK * HIDN,
                                        cos_t, sin_t);

    // c_q = hs @ w_q_down^T (split-K x4) + fused conversion of w_q_up AND w_kv_down
    gemm_bt<0, 1, 0><<<dim3(QLRANK / 128, SEQ / 128, 4), 512, 0, stream>>>(
        hs_bf, wqd_bf, parts, SEQ, QLRANK, HIDN / 4, HIDN,
        w_q_up, wqu_bf, ((long)24576 * QLRANK) / 8,
        w_kv_down, wkd_bf, ((long)576 * HIDN) / 8, nullptr);
    reduce_rms_cq<<<SEQ, 256, 0, stream>>>(parts, q_norm_w, cq_n);

    // q_cr = rmsnorm(c_q) @ w_q_up^T + fused conversion of w_kv_up
    gemm_bt<1, 1, 0><<<dim3(24576 / 128, SEQ / 128), 512, 0, stream>>>(
        cq_n, wqu_bf, q_cr, SEQ, 24576, QLRANK, QLRANK,
        w_kv_up, wku_bf, ((long)32768 * KVLRANK) / 8,
        nullptr, nullptr, 0, nullptr);

    // ckv_kr = hs @ w_kv_down^T   (split-K x8; N=576 ragged)
    gemm_bt<0, 0, 0><<<dim3(5, SEQ / 128, 8), 512, 0, stream>>>(
        hs_bf, wkd_bf, parts, SEQ, 576, HIDN / 8, HIDN,
        nullptr, nullptr, 0, nullptr, nullptr, 0, nullptr);
    reduce_rms_rope_kv<<<SEQ, 256, 0, stream>>>(parts, kv_norm_w, ckv_n, cos_t, sin_t, kr);

    // kv = rmsnorm(c_kv) @ w_kv_up^T; odd-x blocks (pure V tiles) write vT
    // directly via the LDS transpose epilogue (build_vt eliminated)
    gemm_bt<1, 0, 1><<<dim3(32768 / 128, SEQ / 128), 512, 0, stream>>>(
        ckv_n, wku_bf, kvb, SEQ, 32768, KVLRANK, KVLRANK,
        nullptr, nullptr, 0, nullptr, nullptr, 0, vT);

    // attention (in-register RoPE-Q); convert w_out under attention's idle BW
    if (!fuse)
        f32_to_bf16<<<4096, 256, 0, stream>>>(w_out, wout_bf, (long)HIDN * 16384);
    mla_attn<<<dim3(SEQ / 128, NHEAD), 512, 0, stream>>>(q_cr, kvb, kr, vT, o_g,
                                                         cos_t, sin_t,
                                                         w_out, wout_bf, fuse ? 1 : 0);

    // out = o @ w_out^T
    gemm_bt<0, 0, 0><<<dim3(HIDN / 128, SEQ / 128), 512, 0, stream>>>(
        o_g, wout_bf, out, SEQ, HIDN, 16384, 16384,
        nullptr, nullptr, 0, nullptr, nullptr, 0, nullptr);
}